// Round 11
// baseline (690.036 us; speedup 1.0000x reference)
//
#include <hip/hip_runtime.h>
#include <hip/hip_bf16.h>
#include <math.h>

#define NB 16
#define CIN1 512
#define COUT 256
#define GD 256
#define TD 256
#define LL 32
#define P1 1024
#define P2 4096
#define CONDC 512

typedef __attribute__((ext_vector_type(8))) short bf16x8;
typedef __attribute__((ext_vector_type(4))) float f32x4;
typedef unsigned short u16;

__device__ __forceinline__ u16 f2b(float f) {
  __hip_bfloat16 h = __float2bfloat16(f);
  return *(u16*)&h;
}

// ---------------- BN stats: mean + rsqrt(var+eps) per channel ----------------
__global__ void bn_stats_kernel(const float* __restrict__ x, float* __restrict__ mean,
                                float* __restrict__ rstd, int C, int HW) {
  int c = blockIdx.x, t = threadIdx.x;
  float s = 0.f, sq = 0.f;
  for (int b = 0; b < NB; ++b) {
    const float* p = x + ((size_t)b * C + c) * HW;
    for (int i = t; i < HW; i += 256) { float v = p[i]; s += v; sq += v * v; }
  }
  __shared__ float ss[256], sq2[256];
  ss[t] = s; sq2[t] = sq; __syncthreads();
  for (int o = 128; o > 0; o >>= 1) {
    if (t < o) { ss[t] += ss[t + o]; sq2[t] += sq2[t + o]; }
    __syncthreads();
  }
  if (t == 0) {
    float n = (float)NB * (float)HW;
    float m = ss[0] / n;
    float v = sq2[0] / n - m * m;
    mean[c] = m;
    rstd[c] = rsqrtf(v + 1e-5f);
  }
}

// ---------------- normalize words_embs over channel dim per (b,l) ----------------
__global__ void wdn_kernel(const float* __restrict__ we, float* __restrict__ wdn) {
  int b = blockIdx.x >> 5, l = blockIdx.x & 31;
  int t = threadIdx.x; // 64
  const float* base = we + (size_t)b * TD * LL + l;
  float v[4]; float sq = 0.f;
#pragma unroll
  for (int k = 0; k < 4; ++k) { v[k] = base[(size_t)(t * 4 + k) * LL]; sq += v[k] * v[k]; }
#pragma unroll
  for (int o = 32; o > 0; o >>= 1) sq += __shfl_xor(sq, o);
  float r = 1.f / fmaxf(sqrtf(sq), 1e-12f);
  float* ob = wdn + (size_t)b * TD * LL + l;
#pragma unroll
  for (int k = 0; k < 4; ++k) ob[(size_t)(t * 4 + k) * LL] = v[k] * r;
}

// ---------------- gvec[b,o] = bias[o] + sum_{c<GD} W[o,c]*gc[b,c] ----------------
__global__ void gvec_kernel(const float* __restrict__ Wg, const float* __restrict__ bias,
                            const float* __restrict__ gc, float* __restrict__ outv, int O) {
  int o = blockIdx.x * 64 + threadIdx.x;
  int b = blockIdx.y;
  if (o >= O) return;
  const float* wr = Wg + (size_t)o * CONDC;
  const float* g = gc + (size_t)b * GD;
  float s = 0.f;
  for (int c = 0; c < GD; ++c) s += wr[c] * g[c];
  outv[(size_t)b * O + o] = s + bias[o];
}

// ---------------- fused attention: l2norm -> sim (MFMA) -> softmax -> ctx (MFMA) ----------------
__global__ __launch_bounds__(256) void attnctx_kernel(
    const float* __restrict__ img, const float* __restrict__ wdn,
    const int* __restrict__ mask, float* __restrict__ ctx, int P) {
  __shared__ u16 imgT[64 * 72];
  __shared__ u16 wdnT[32 * 264];
  __shared__ u16 wdnC[256 * 40];
  __shared__ u16 attnB[64 * 40];
  __shared__ float sqP[4][64];
  __shared__ float rnL[64];
  const int b = blockIdx.y, p0 = blockIdx.x * 64;
  const int tid = threadIdx.x;
  const int w = tid >> 6, lane = tid & 63;
  const int l15 = lane & 15, lg = lane >> 4;
  const float* ib = img + (size_t)b * TD * P;
  const float* wb = wdn + (size_t)b * TD * LL;

  for (int i = tid; i < TD * LL; i += 256) {
    int t = i >> 5, l = i & 31;
    u16 v = f2b(wb[i]);
    wdnT[l * 264 + t] = v;
    wdnC[t * 40 + l] = v;
  }

  f32x4 s0 = {}, s1 = {};
  float ssq = 0.f;
  for (int q = 0; q < 4; ++q) {
#pragma unroll
    for (int i = 0; i < 16; i += 2) {
      int t = q * 64 + w * 16 + i;
      float v0 = ib[(size_t)t * P + p0 + lane];
      float v1 = ib[(size_t)(t + 1) * P + p0 + lane];
      ssq += v0 * v0 + v1 * v1;
      unsigned pk = (unsigned)f2b(v0) | ((unsigned)f2b(v1) << 16);
      *(unsigned*)(imgT + lane * 72 + w * 16 + i) = pk;
    }
    __syncthreads();
#pragma unroll
    for (int ks = 0; ks < 2; ++ks) {
      bf16x8 a = *(const bf16x8*)(imgT + (w * 16 + l15) * 72 + ks * 32 + lg * 8);
      bf16x8 b0 = *(const bf16x8*)(wdnT + l15 * 264 + q * 64 + ks * 32 + lg * 8);
      bf16x8 b1 = *(const bf16x8*)(wdnT + (16 + l15) * 264 + q * 64 + ks * 32 + lg * 8);
      s0 = __builtin_amdgcn_mfma_f32_16x16x32_bf16(a, b0, s0, 0, 0, 0);
      s1 = __builtin_amdgcn_mfma_f32_16x16x32_bf16(a, b1, s1, 0, 0, 0);
    }
    __syncthreads();
  }
  sqP[w][lane] = ssq;
  __syncthreads();
  if (tid < 64) {
    float s = sqP[0][tid] + sqP[1][tid] + sqP[2][tid] + sqP[3][tid];
    rnL[tid] = 1.f / fmaxf(sqrtf(s), 1e-12f);
  }
  __syncthreads();
  const bool m0 = mask[b * LL + l15] != 0;
  const bool m1 = mask[b * LL + 16 + l15] != 0;
#pragma unroll
  for (int k = 0; k < 4; ++k) {
    float rn = rnL[w * 16 + lg * 4 + k];
    float v0 = m0 ? -INFINITY : s0[k] * rn;
    float v1 = m1 ? -INFINITY : s1[k] * rn;
    float mx = fmaxf(v0, v1);
#pragma unroll
    for (int o = 1; o < 16; o <<= 1) mx = fmaxf(mx, __shfl_xor(mx, o));
    float e0 = expf(v0 - mx), e1 = expf(v1 - mx);
    float sm = e0 + e1;
#pragma unroll
    for (int o = 1; o < 16; o <<= 1) sm += __shfl_xor(sm, o);
    float inv = 1.f / sm;
    int px = w * 16 + lg * 4 + k;
    attnB[px * 40 + l15] = f2b(e0 * inv);
    attnB[px * 40 + 16 + l15] = f2b(e1 * inv);
  }
  __syncthreads();
  f32x4 acc[4][4] = {};
  bf16x8 bfr[4];
#pragma unroll
  for (int pt = 0; pt < 4; ++pt)
    bfr[pt] = *(const bf16x8*)(attnB + (pt * 16 + l15) * 40 + lg * 8);
#pragma unroll
  for (int cc = 0; cc < 4; ++cc) {
    bf16x8 a = *(const bf16x8*)(wdnC + ((w * 4 + cc) * 16 + l15) * 40 + lg * 8);
#pragma unroll
    for (int pt = 0; pt < 4; ++pt)
      acc[cc][pt] = __builtin_amdgcn_mfma_f32_16x16x32_bf16(a, bfr[pt], acc[cc][pt], 0, 0, 0);
  }
#pragma unroll
  for (int cc = 0; cc < 4; ++cc) {
#pragma unroll
    for (int pt = 0; pt < 4; ++pt) {
#pragma unroll
      for (int k = 0; k < 4; ++k) {
        int c = (w * 4 + cc) * 16 + lg * 4 + k;
        ctx[((size_t)b * TD + c) * P + p0 + pt * 16 + l15] = acc[cc][pt][k];
      }
    }
  }
}

// ---------------- bf16 MFMA GEMM (img1/img2/shortcut): Y = W x X ----------------
__global__ __launch_bounds__(256) void gemm_mfma_kernel(
    const float* __restrict__ W, int ldw, int c_off,
    const float* __restrict__ X, const float* __restrict__ vec,
    float* __restrict__ Y, int T, int C, int P) {
  __shared__ u16 Wl[128 * 44];
  __shared__ u16 Xl[128 * 40];
  const int b = blockIdx.z;
  const int t0 = blockIdx.y * 128, p0 = blockIdx.x * 128;
  const int tid = threadIdx.x;
  const int w = tid >> 6, lane = tid & 63;
  const int wo = w >> 1, wq = w & 1;
  const int l15 = lane & 15, lg = lane >> 4;
  const float* Xb = X + (size_t)b * C * P;
  const int wr = tid >> 1, wcH = tid & 1;
  const int xr = tid >> 3, xcG = tid & 7;
  const int csw = xr ^ ((xcG & 3) << 3);
  f32x4 acc[4][4] = {};

  for (int c0 = 0; c0 < C; c0 += 32) {
    {
      const float* src = W + (size_t)(t0 + wr) * ldw + c_off + c0 + wcH * 16;
      u16* dst = Wl + wr * 44 + wcH * 16;
#pragma unroll
      for (int j = 0; j < 4; ++j) {
        float4 v = *(const float4*)(src + j * 4);
        ushort4 pk = make_ushort4(f2b(v.x), f2b(v.y), f2b(v.z), f2b(v.w));
        *(ushort4*)(dst + j * 4) = pk;
      }
    }
    {
      const float* src = Xb + (size_t)(c0 + xr) * P + p0 + xcG * 16;
#pragma unroll
      for (int j = 0; j < 4; ++j) {
        float4 v = *(const float4*)(src + j * 4);
        int px = xcG * 16 + j * 4;
        Xl[(px + 0) * 40 + csw] = f2b(v.x);
        Xl[(px + 1) * 40 + csw] = f2b(v.y);
        Xl[(px + 2) * 40 + csw] = f2b(v.z);
        Xl[(px + 3) * 40 + csw] = f2b(v.w);
      }
    }
    __syncthreads();
    bf16x8 a[4], bb[4];
#pragma unroll
    for (int rr = 0; rr < 4; ++rr)
      a[rr] = *(const bf16x8*)(Wl + (wo * 64 + rr * 16 + l15) * 44 + lg * 8);
#pragma unroll
    for (int ss = 0; ss < 4; ++ss)
      bb[ss] = *(const bf16x8*)(Xl + (wq * 64 + ss * 16 + l15) * 40 + ((lg ^ ss) << 3));
#pragma unroll
    for (int rr = 0; rr < 4; ++rr)
#pragma unroll
      for (int ss = 0; ss < 4; ++ss)
        acc[rr][ss] = __builtin_amdgcn_mfma_f32_16x16x32_bf16(a[rr], bb[ss], acc[rr][ss], 0, 0, 0);
    __syncthreads();
  }
#pragma unroll
  for (int rr = 0; rr < 4; ++rr) {
    int tb = t0 + wo * 64 + rr * 16 + lg * 4;
#pragma unroll
    for (int ss = 0; ss < 4; ++ss) {
      int p = p0 + wq * 64 + ss * 16 + l15;
#pragma unroll
      for (int k = 0; k < 4; ++k) {
        int t = tb + k;
        float val = acc[rr][ss][k];
        if (vec) val += vec[(size_t)b * T + t];
        Y[((size_t)b * T + t) * P + p] = val;
      }
    }
  }
}

// ---------------- fused gamma/beta GEMM + BN + ReLU + NHWC bf16 pack ----------------
__global__ __launch_bounds__(256, 1) void gbact_kernel(
    const float* __restrict__ Wg, const float* __restrict__ Wb,
    const float* __restrict__ ctx, const float* __restrict__ gvec,
    const float* __restrict__ bvec, const float* __restrict__ xin,
    const float* __restrict__ mean, const float* __restrict__ rstd,
    const float* __restrict__ bnw, const float* __restrict__ bnb,
    u16* __restrict__ outb, int C, int P) {
  __shared__ u16 shmem[17408];
  u16* Wgl = shmem;
  u16* Wbl = shmem + 5632;
  u16* Xl  = shmem + 11264;
  const int b = blockIdx.z, t0 = blockIdx.y * 128, p0 = blockIdx.x * 128;
  const int tid = threadIdx.x;
  const int w = tid >> 6, lane = tid & 63;
  const int wo = w >> 1, wq = w & 1;
  const int l15 = lane & 15, lg = lane >> 4;
  const float* Xb = ctx + (size_t)b * TD * P;
  const int wr = tid >> 1, wcH = tid & 1;
  const int xr = tid >> 3, xcG = tid & 7;
  const int csw = xr ^ ((xcG & 3) << 3);
  f32x4 accg[4][4] = {}, accb[4][4] = {};

  for (int c0 = 0; c0 < TD; c0 += 32) {
    {
      const float* sg = Wg + (size_t)(t0 + wr) * CONDC + GD + c0 + wcH * 16;
      const float* sb = Wb + (size_t)(t0 + wr) * CONDC + GD + c0 + wcH * 16;
      u16* dg = Wgl + wr * 44 + wcH * 16;
      u16* db = Wbl + wr * 44 + wcH * 16;
#pragma unroll
      for (int j = 0; j < 4; ++j) {
        float4 v = *(const float4*)(sg + j * 4);
        *(ushort4*)(dg + j * 4) = make_ushort4(f2b(v.x), f2b(v.y), f2b(v.z), f2b(v.w));
        float4 u = *(const float4*)(sb + j * 4);
        *(ushort4*)(db + j * 4) = make_ushort4(f2b(u.x), f2b(u.y), f2b(u.z), f2b(u.w));
      }
    }
    {
      const float* src = Xb + (size_t)(c0 + xr) * P + p0 + xcG * 16;
#pragma unroll
      for (int j = 0; j < 4; ++j) {
        float4 v = *(const float4*)(src + j * 4);
        int px = xcG * 16 + j * 4;
        Xl[(px + 0) * 40 + csw] = f2b(v.x);
        Xl[(px + 1) * 40 + csw] = f2b(v.y);
        Xl[(px + 2) * 40 + csw] = f2b(v.z);
        Xl[(px + 3) * 40 + csw] = f2b(v.w);
      }
    }
    __syncthreads();
    bf16x8 ag[4], ab[4], bb[4];
#pragma unroll
    for (int rr = 0; rr < 4; ++rr) {
      ag[rr] = *(const bf16x8*)(Wgl + (wo * 64 + rr * 16 + l15) * 44 + lg * 8);
      ab[rr] = *(const bf16x8*)(Wbl + (wo * 64 + rr * 16 + l15) * 44 + lg * 8);
    }
#pragma unroll
    for (int ss = 0; ss < 4; ++ss)
      bb[ss] = *(const bf16x8*)(Xl + (wq * 64 + ss * 16 + l15) * 40 + ((lg ^ ss) << 3));
#pragma unroll
    for (int rr = 0; rr < 4; ++rr)
#pragma unroll
      for (int ss = 0; ss < 4; ++ss) {
        accg[rr][ss] = __builtin_amdgcn_mfma_f32_16x16x32_bf16(ag[rr], bb[ss], accg[rr][ss], 0, 0, 0);
        accb[rr][ss] = __builtin_amdgcn_mfma_f32_16x16x32_bf16(ab[rr], bb[ss], accb[rr][ss], 0, 0, 0);
      }
    __syncthreads();
  }
#pragma unroll
  for (int rr = 0; rr < 4; ++rr) {
    float gv[4], bv[4], mm[4], rs[4], bB[4];
#pragma unroll
    for (int k = 0; k < 4; ++k) {
      int c = t0 + wo * 64 + rr * 16 + lg * 4 + k;
      gv[k] = gvec[(size_t)b * C + c];
      bv[k] = bvec[(size_t)b * C + c];
      mm[k] = mean[c]; rs[k] = rstd[c] * bnw[c]; bB[k] = bnb[c];
    }
#pragma unroll
    for (int ss = 0; ss < 4; ++ss) {
#pragma unroll
      for (int k = 0; k < 4; ++k) {
        int cl = wo * 64 + rr * 16 + lg * 4 + k;
        int pl = wq * 64 + ss * 16 + l15;
        float xv = xin[((size_t)b * C + t0 + cl) * P + p0 + pl];
        float g = accg[rr][ss][k] + gv[k];
        float be = accb[rr][ss][k] + bv[k];
        float val = fmaxf(g * ((xv - mm[k]) * rs[k] + bB[k]) + be, 0.f);
        shmem[pl * 136 + cl] = f2b(val);
      }
    }
  }
  __syncthreads();
  const int pr = tid >> 1, h = tid & 1;
#pragma unroll
  for (int j = 0; j < 8; ++j) {
    uint4 v = *(uint4*)(shmem + pr * 136 + h * 64 + j * 8);
    *(uint4*)(outb + ((size_t)b * P + p0 + pr) * C + t0 + h * 64 + j * 8) = v;
  }
}

// ---------------- pack conv weights: fragment-linear bf16 ----------------
__global__ void pack_w_kernel(const float* __restrict__ w, u16* __restrict__ wp, int O, int CIN) {
  int lin = blockIdx.x * 256 + threadIdx.x;
  if (lin >= O * CIN) return;
  int o = lin / CIN, c = lin - o * CIN;
  int c0blk = c >> 5, lg = (c >> 3) & 3, cc = c & 7;
  int ot = o >> 4, l15 = o & 15;
  int lane = lg * 16 + l15;
  size_t base = (((size_t)c0blk * (O >> 4) + ot) * 64 + lane) * 8 + cc;
  size_t posStride = (size_t)(CIN >> 5) * (O >> 4) * 512;
  const float* src = w + (size_t)lin * 9;
#pragma unroll
  for (int pos = 0; pos < 9; ++pos)
    wp[pos * posStride + base] = f2b(src[pos]);
}

// ---------------- bf16 MFMA implicit-GEMM 3x3 conv ----------------
// Block: 4 waves = 256o x 128px; wave tile 128o x 64px (8rr x 4ss) -> LDS bytes/FLOP under budget.
// B-fragments: single ds_read_b128 (stride 40 u16 = 80B, 16B-aligned).
template <int CIN, bool UP>
__global__ __launch_bounds__(256, 2) void conv_mfma_kernel(
    const u16* __restrict__ Wp, const u16* __restrict__ Xt,
    const float* __restrict__ scs, const float* __restrict__ scb,
    float* __restrict__ Y) {
  constexpr int S = UP ? 32 : 64;
  constexpr int NC0 = CIN >> 5;
  __shared__ u16 Xs[2][4 * 66 * 40];  // double buffer, 21120 B each
  const int b = blockIdx.z, pxT = blockIdx.x;
  const int tid = threadIdx.x;
  const int w = tid >> 6, lane = tid & 63;
  const int wo = w >> 1, wp_ = w & 1;
  const int l15 = lane & 15, lg = lane >> 4;
  const int Y0 = pxT * 2;
  const u16* Xb = Xt + (size_t)b * S * S * CIN;
  const size_t posStride = (size_t)NC0 * 16 * 512;
  f32x4 acc[8][4] = {};
  uint2 st[9];

  // prologue: load + write tile 0
#pragma unroll
  for (int j = 0; j < 9; ++j) {
    int i = tid + j * 256;
    if (i < 2112) {
      int r = i / 528, rem = i - r * 528, col = rem >> 3, ch = rem & 7;
      int uy = Y0 - 1 + r, ux = col - 1;
      uint2 v = make_uint2(0u, 0u);
      if (uy >= 0 && uy < 64 && ux >= 0 && ux < 64) {
        int sy = UP ? (uy >> 1) : uy, sx = UP ? (ux >> 1) : ux;
        v = *(const uint2*)(Xb + ((size_t)sy * S + sx) * CIN + ch * 4);
      }
      st[j] = v;
    }
  }
#pragma unroll
  for (int j = 0; j < 9; ++j) {
    int i = tid + j * 256;
    if (i < 2112) {
      int r = i / 528, rem = i - r * 528, col = rem >> 3, ch = rem & 7;
      *(uint2*)(&Xs[0][(r * 66 + col) * 40 + ch * 4]) = st[j];
    }
  }
  __syncthreads();

  for (int c0b = 0; c0b < NC0; ++c0b) {
    const int cur = c0b & 1;
    // early-issue loads for next tile (land during compute)
    if (c0b + 1 < NC0) {
      const int c0n = (c0b + 1) << 5;
#pragma unroll
      for (int j = 0; j < 9; ++j) {
        int i = tid + j * 256;
        if (i < 2112) {
          int r = i / 528, rem = i - r * 528, col = rem >> 3, ch = rem & 7;
          int uy = Y0 - 1 + r, ux = col - 1;
          uint2 v = make_uint2(0u, 0u);
          if (uy >= 0 && uy < 64 && ux >= 0 && ux < 64) {
            int sy = UP ? (uy >> 1) : uy, sx = UP ? (ux >> 1) : ux;
            v = *(const uint2*)(Xb + ((size_t)sy * S + sx) * CIN + c0n + ch * 4);
          }
          st[j] = v;
        }
      }
    }
    // compute: A-fragments (8 rr = 128 o) software-pipelined across pos
    {
      const u16* wbB = Wp + ((size_t)c0b * 16 + wo * 8) * 512 + lane * 8;
      bf16x8 aC[8], aN[8];
#pragma unroll
      for (int rr = 0; rr < 8; ++rr)
        aC[rr] = *(const bf16x8*)(wbB + rr * 512);
#pragma unroll
      for (int pos = 0; pos < 9; ++pos) {
        const int ky = pos / 3, kx = pos - ky * 3;
        if (pos < 8) {
          const u16* wbn = wbB + (size_t)(pos + 1) * posStride;
#pragma unroll
          for (int rr = 0; rr < 8; ++rr)
            aN[rr] = *(const bf16x8*)(wbn + rr * 512);
        }
        const int rowb = ((wp_ + ky) * 66 + kx) * 40 + lg * 8;
#pragma unroll
        for (int ss = 0; ss < 4; ++ss) {
          bf16x8 bfr = *(const bf16x8*)(&Xs[cur][rowb + (ss * 16 + l15) * 40]);
#pragma unroll
          for (int rr = 0; rr < 8; ++rr)
            acc[rr][ss] = __builtin_amdgcn_mfma_f32_16x16x32_bf16(aC[rr], bfr, acc[rr][ss], 0, 0, 0);
        }
#pragma unroll
        for (int rr = 0; rr < 8; ++rr) aC[rr] = aN[rr];
      }
    }
    // write next tile into the other buffer; single barrier per iter
    if (c0b + 1 < NC0) {
#pragma unroll
      for (int j = 0; j < 9; ++j) {
        int i = tid + j * 256;
        if (i < 2112) {
          int r = i / 528, rem = i - r * 528, col = rem >> 3, ch = rem & 7;
          *(uint2*)(&Xs[cur ^ 1][(r * 66 + col) * 40 + ch * 4]) = st[j];
        }
      }
      __syncthreads();
    }
  }
  const int oBase = wo * 128 + lg * 4;
  const int pxBase = pxT * 128 + wp_ * 64 + l15;
#pragma unroll
  for (int rr = 0; rr < 8; ++rr) {
#pragma unroll
    for (int ss = 0; ss < 4; ++ss) {
      int px = pxBase + ss * 16;
#pragma unroll
      for (int k = 0; k < 4; ++k) {
        int o = oBase + rr * 16 + k;
        float val = acc[rr][ss][k];
        if (scs) {
          int gx = px & 63;
          val += scs[((size_t)b * COUT + o) * P1 + pxT * 32 + (gx >> 1)] + scb[o];
        }
        Y[((size_t)b * COUT + o) * 4096 + px] = val;
      }
    }
  }
}

extern "C" void kernel_launch(void* const* d_in, const int* in_sizes, int n_in,
                              void* d_out, int out_size, void* d_ws, size_t ws_size,
                              hipStream_t stream) {
  const float* x      = (const float*)d_in[0];
  const float* gcond  = (const float*)d_in[1];
  const float* wemb   = (const float*)d_in[2];
  const int*   mask   = (const int*)d_in[3];
  const float* w_img1 = (const float*)d_in[4];
  const float* w_img2 = (const float*)d_in[5];
  const float* w_c1   = (const float*)d_in[6];
  const float* w_c2   = (const float*)d_in[7];
  const float* bn1_w  = (const float*)d_in[8];
  const float* bn1_b  = (const float*)d_in[9];
  const float* bn2_w  = (const float*)d_in[10];
  const float* bn2_b  = (const float*)d_in[11];
  const float* w_g1   = (const float*)d_in[12];
  const float* b_g1   = (const float*)d_in[13];
  const float* w_b1   = (const float*)d_in[14];
  const float* b_b1   = (const float*)d_in[15];
  const float* w_g2   = (const float*)d_in[16];
  const float* b_g2   = (const float*)d_in[17];
  const float* w_b2   = (const float*)d_in[18];
  const float* b_b2   = (const float*)d_in[19];
  const float* w_sc   = (const float*)d_in[20];
  const float* b_sc   = (const float*)d_in[21];
  float* out = (float*)d_out;
  float* ws = (float*)d_ws;

  const size_t MF = 16777216;  // floats per 64MB region
  float* A  = ws;
  float* Br = ws + MF;
  float* Cr = ws + 2 * MF;
  float* SM = ws + 3 * MF;
  float* wdn   = SM;                     // 131072
  float* mean1 = SM + 131072;
  float* rstd1 = mean1 + 512;
  float* mean2 = rstd1 + 512;
  float* rstd2 = mean2 + 256;
  float* gvec1 = rstd2 + 256;            // 8192
  float* bvec1 = gvec1 + 8192;
  float* gvec2 = bvec1 + 8192;           // 4096
  float* bvec2 = gvec2 + 4096;
  float* wsp   = bvec2 + 4096;
  u16* Wp1 = (u16*)wsp;                  // 9*256*512 ushorts
  u16* Wp2 = (u16*)(wsp + 655360);       // 9*256*256 ushorts

  float* img1   = A;                     // 4M floats
  float* ctx1   = A + 4194304;           // 4M floats
  u16*   Xt1    = (u16*)(A + 8388608);   // 8.4M u16 NHWC bf16
  float* conv1o = Cr;                    // 16M floats
  float* img2   = Br;                    // 16M floats
  float* ctx2   = A;                     // reuse (all of A dead after conv1)
  u16*   Xt2    = (u16*)Br;              // reuse (img2 dead after attnctx2)
  float* scs    = Cr;                    // reuse (conv1o dead after gbact2)

  // ---- stage 1 ----
  bn_stats_kernel<<<dim3(CIN1), dim3(256), 0, stream>>>(x, mean1, rstd1, CIN1, P1);
  wdn_kernel<<<dim3(NB * LL), dim3(64), 0, stream>>>(wemb, wdn);
  pack_w_kernel<<<dim3(COUT * CIN1 / 256), dim3(256), 0, stream>>>(w_c1, Wp1, COUT, CIN1);
  pack_w_kernel<<<dim3(COUT * COUT / 256), dim3(256), 0, stream>>>(w_c2, Wp2, COUT, COUT);
  gemm_mfma_kernel<<<dim3(P1 / 128, TD / 128, NB), dim3(256), 0, stream>>>(
      w_img1, CIN1, 0, x, nullptr, img1, TD, CIN1, P1);
  attnctx_kernel<<<dim3(P1 / 64, NB), dim3(256), 0, stream>>>(img1, wdn, mask, ctx1, P1);
  gvec_kernel<<<dim3(CIN1 / 64, NB), dim3(64), 0, stream>>>(w_g1, b_g1, gcond, gvec1, CIN1);
  gvec_kernel<<<dim3(CIN1 / 64, NB), dim3(64), 0, stream>>>(w_b1, b_b1, gcond, bvec1, CIN1);
  gbact_kernel<<<dim3(P1 / 128, CIN1 / 128, NB), dim3(256), 0, stream>>>(
      w_g1, w_b1, ctx1, gvec1, bvec1, x, mean1, rstd1, bn1_w, bn1_b, Xt1, CIN1, P1);
  conv_mfma_kernel<CIN1, true><<<dim3(32, 1, NB), dim3(256), 0, stream>>>(
      Wp1, Xt1, nullptr, nullptr, conv1o);

  // ---- stage 2 ----
  bn_stats_kernel<<<dim3(COUT), dim3(256), 0, stream>>>(conv1o, mean2, rstd2, COUT, P2);
  gemm_mfma_kernel<<<dim3(P2 / 128, TD / 128, NB), dim3(256), 0, stream>>>(
      w_img2, COUT, 0, conv1o, nullptr, img2, TD, COUT, P2);
  attnctx_kernel<<<dim3(P2 / 64, NB), dim3(256), 0, stream>>>(img2, wdn, mask, ctx2, P2);
  gvec_kernel<<<dim3(COUT / 64, NB), dim3(64), 0, stream>>>(w_g2, b_g2, gcond, gvec2, COUT);
  gvec_kernel<<<dim3(COUT / 64, NB), dim3(64), 0, stream>>>(w_b2, b_b2, gcond, bvec2, COUT);
  gbact_kernel<<<dim3(P2 / 128, COUT / 128, NB), dim3(256), 0, stream>>>(
      w_g2, w_b2, ctx2, gvec2, bvec2, conv1o, mean2, rstd2, bn2_w, bn2_b, Xt2, COUT, P2);
  gemm_mfma_kernel<<<dim3(P1 / 128, COUT / 128, NB), dim3(256), 0, stream>>>(
      w_sc, CIN1, 0, x, nullptr, scs, COUT, CIN1, P1);
  conv_mfma_kernel<COUT, false><<<dim3(32, 1, NB), dim3(256), 0, stream>>>(
      Wp2, Xt2, scs, b_sc, out);
}

// Round 12
// 633.040 us; speedup vs baseline: 1.0900x; 1.0900x over previous
//
#include <hip/hip_runtime.h>
#include <hip/hip_bf16.h>
#include <math.h>

#define NB 16
#define CIN1 512
#define COUT 256
#define GD 256
#define TD 256
#define LL 32
#define P1 1024
#define P2 4096
#define CONDC 512

typedef __attribute__((ext_vector_type(8))) short bf16x8;
typedef __attribute__((ext_vector_type(4))) float f32x4;
typedef unsigned short u16;

__device__ __forceinline__ u16 f2b(float f) {
  __hip_bfloat16 h = __float2bfloat16(f);
  return *(u16*)&h;
}

// ---------------- BN stats: mean + rsqrt(var+eps) per channel ----------------
__global__ void bn_stats_kernel(const float* __restrict__ x, float* __restrict__ mean,
                                float* __restrict__ rstd, int C, int HW) {
  int c = blockIdx.x, t = threadIdx.x;
  float s = 0.f, sq = 0.f;
  for (int b = 0; b < NB; ++b) {
    const float* p = x + ((size_t)b * C + c) * HW;
    for (int i = t; i < HW; i += 256) { float v = p[i]; s += v; sq += v * v; }
  }
  __shared__ float ss[256], sq2[256];
  ss[t] = s; sq2[t] = sq; __syncthreads();
  for (int o = 128; o > 0; o >>= 1) {
    if (t < o) { ss[t] += ss[t + o]; sq2[t] += sq2[t + o]; }
    __syncthreads();
  }
  if (t == 0) {
    float n = (float)NB * (float)HW;
    float m = ss[0] / n;
    float v = sq2[0] / n - m * m;
    mean[c] = m;
    rstd[c] = rsqrtf(v + 1e-5f);
  }
}

// ---------------- normalize words_embs over channel dim per (b,l) ----------------
__global__ void wdn_kernel(const float* __restrict__ we, float* __restrict__ wdn) {
  int b = blockIdx.x >> 5, l = blockIdx.x & 31;
  int t = threadIdx.x; // 64
  const float* base = we + (size_t)b * TD * LL + l;
  float v[4]; float sq = 0.f;
#pragma unroll
  for (int k = 0; k < 4; ++k) { v[k] = base[(size_t)(t * 4 + k) * LL]; sq += v[k] * v[k]; }
#pragma unroll
  for (int o = 32; o > 0; o >>= 1) sq += __shfl_xor(sq, o);
  float r = 1.f / fmaxf(sqrtf(sq), 1e-12f);
  float* ob = wdn + (size_t)b * TD * LL + l;
#pragma unroll
  for (int k = 0; k < 4; ++k) ob[(size_t)(t * 4 + k) * LL] = v[k] * r;
}

// ---------------- gvec[b,o] = bias[o] + sum_{c<GD} W[o,c]*gc[b,c] ----------------
__global__ void gvec_kernel(const float* __restrict__ Wg, const float* __restrict__ bias,
                            const float* __restrict__ gc, float* __restrict__ outv, int O) {
  int o = blockIdx.x * 64 + threadIdx.x;
  int b = blockIdx.y;
  if (o >= O) return;
  const float* wr = Wg + (size_t)o * CONDC;
  const float* g = gc + (size_t)b * GD;
  float s = 0.f;
  for (int c = 0; c < GD; ++c) s += wr[c] * g[c];
  outv[(size_t)b * O + o] = s + bias[o];
}

// ---------------- fused attention: l2norm -> sim (MFMA) -> softmax -> ctx (MFMA) ----------------
__global__ __launch_bounds__(256) void attnctx_kernel(
    const float* __restrict__ img, const float* __restrict__ wdn,
    const int* __restrict__ mask, float* __restrict__ ctx, int P) {
  __shared__ u16 imgT[64 * 72];
  __shared__ u16 wdnT[32 * 264];
  __shared__ u16 wdnC[256 * 40];
  __shared__ u16 attnB[64 * 40];
  __shared__ float sqP[4][64];
  __shared__ float rnL[64];
  const int b = blockIdx.y, p0 = blockIdx.x * 64;
  const int tid = threadIdx.x;
  const int w = tid >> 6, lane = tid & 63;
  const int l15 = lane & 15, lg = lane >> 4;
  const float* ib = img + (size_t)b * TD * P;
  const float* wb = wdn + (size_t)b * TD * LL;

  for (int i = tid; i < TD * LL; i += 256) {
    int t = i >> 5, l = i & 31;
    u16 v = f2b(wb[i]);
    wdnT[l * 264 + t] = v;
    wdnC[t * 40 + l] = v;
  }

  f32x4 s0 = {}, s1 = {};
  float ssq = 0.f;
  for (int q = 0; q < 4; ++q) {
#pragma unroll
    for (int i = 0; i < 16; i += 2) {
      int t = q * 64 + w * 16 + i;
      float v0 = ib[(size_t)t * P + p0 + lane];
      float v1 = ib[(size_t)(t + 1) * P + p0 + lane];
      ssq += v0 * v0 + v1 * v1;
      unsigned pk = (unsigned)f2b(v0) | ((unsigned)f2b(v1) << 16);
      *(unsigned*)(imgT + lane * 72 + w * 16 + i) = pk;
    }
    __syncthreads();
#pragma unroll
    for (int ks = 0; ks < 2; ++ks) {
      bf16x8 a = *(const bf16x8*)(imgT + (w * 16 + l15) * 72 + ks * 32 + lg * 8);
      bf16x8 b0 = *(const bf16x8*)(wdnT + l15 * 264 + q * 64 + ks * 32 + lg * 8);
      bf16x8 b1 = *(const bf16x8*)(wdnT + (16 + l15) * 264 + q * 64 + ks * 32 + lg * 8);
      s0 = __builtin_amdgcn_mfma_f32_16x16x32_bf16(a, b0, s0, 0, 0, 0);
      s1 = __builtin_amdgcn_mfma_f32_16x16x32_bf16(a, b1, s1, 0, 0, 0);
    }
    __syncthreads();
  }
  sqP[w][lane] = ssq;
  __syncthreads();
  if (tid < 64) {
    float s = sqP[0][tid] + sqP[1][tid] + sqP[2][tid] + sqP[3][tid];
    rnL[tid] = 1.f / fmaxf(sqrtf(s), 1e-12f);
  }
  __syncthreads();
  const bool m0 = mask[b * LL + l15] != 0;
  const bool m1 = mask[b * LL + 16 + l15] != 0;
#pragma unroll
  for (int k = 0; k < 4; ++k) {
    float rn = rnL[w * 16 + lg * 4 + k];
    float v0 = m0 ? -INFINITY : s0[k] * rn;
    float v1 = m1 ? -INFINITY : s1[k] * rn;
    float mx = fmaxf(v0, v1);
#pragma unroll
    for (int o = 1; o < 16; o <<= 1) mx = fmaxf(mx, __shfl_xor(mx, o));
    float e0 = expf(v0 - mx), e1 = expf(v1 - mx);
    float sm = e0 + e1;
#pragma unroll
    for (int o = 1; o < 16; o <<= 1) sm += __shfl_xor(sm, o);
    float inv = 1.f / sm;
    int px = w * 16 + lg * 4 + k;
    attnB[px * 40 + l15] = f2b(e0 * inv);
    attnB[px * 40 + 16 + l15] = f2b(e1 * inv);
  }
  __syncthreads();
  f32x4 acc[4][4] = {};
  bf16x8 bfr[4];
#pragma unroll
  for (int pt = 0; pt < 4; ++pt)
    bfr[pt] = *(const bf16x8*)(attnB + (pt * 16 + l15) * 40 + lg * 8);
#pragma unroll
  for (int cc = 0; cc < 4; ++cc) {
    bf16x8 a = *(const bf16x8*)(wdnC + ((w * 4 + cc) * 16 + l15) * 40 + lg * 8);
#pragma unroll
    for (int pt = 0; pt < 4; ++pt)
      acc[cc][pt] = __builtin_amdgcn_mfma_f32_16x16x32_bf16(a, bfr[pt], acc[cc][pt], 0, 0, 0);
  }
#pragma unroll
  for (int cc = 0; cc < 4; ++cc) {
#pragma unroll
    for (int pt = 0; pt < 4; ++pt) {
#pragma unroll
      for (int k = 0; k < 4; ++k) {
        int c = (w * 4 + cc) * 16 + lg * 4 + k;
        ctx[((size_t)b * TD + c) * P + p0 + pt * 16 + l15] = acc[cc][pt][k];
      }
    }
  }
}

// ---------------- bf16 MFMA GEMM (img1/img2/shortcut): Y = W x X ----------------
__global__ __launch_bounds__(256) void gemm_mfma_kernel(
    const float* __restrict__ W, int ldw, int c_off,
    const float* __restrict__ X, const float* __restrict__ vec,
    float* __restrict__ Y, int T, int C, int P) {
  __shared__ u16 Wl[128 * 44];
  __shared__ u16 Xl[128 * 40];
  const int b = blockIdx.z;
  const int t0 = blockIdx.y * 128, p0 = blockIdx.x * 128;
  const int tid = threadIdx.x;
  const int w = tid >> 6, lane = tid & 63;
  const int wo = w >> 1, wq = w & 1;
  const int l15 = lane & 15, lg = lane >> 4;
  const float* Xb = X + (size_t)b * C * P;
  const int wr = tid >> 1, wcH = tid & 1;
  const int xr = tid >> 3, xcG = tid & 7;
  const int csw = xr ^ ((xcG & 3) << 3);
  f32x4 acc[4][4] = {};

  for (int c0 = 0; c0 < C; c0 += 32) {
    {
      const float* src = W + (size_t)(t0 + wr) * ldw + c_off + c0 + wcH * 16;
      u16* dst = Wl + wr * 44 + wcH * 16;
#pragma unroll
      for (int j = 0; j < 4; ++j) {
        float4 v = *(const float4*)(src + j * 4);
        ushort4 pk = make_ushort4(f2b(v.x), f2b(v.y), f2b(v.z), f2b(v.w));
        *(ushort4*)(dst + j * 4) = pk;
      }
    }
    {
      const float* src = Xb + (size_t)(c0 + xr) * P + p0 + xcG * 16;
#pragma unroll
      for (int j = 0; j < 4; ++j) {
        float4 v = *(const float4*)(src + j * 4);
        int px = xcG * 16 + j * 4;
        Xl[(px + 0) * 40 + csw] = f2b(v.x);
        Xl[(px + 1) * 40 + csw] = f2b(v.y);
        Xl[(px + 2) * 40 + csw] = f2b(v.z);
        Xl[(px + 3) * 40 + csw] = f2b(v.w);
      }
    }
    __syncthreads();
    bf16x8 a[4], bb[4];
#pragma unroll
    for (int rr = 0; rr < 4; ++rr)
      a[rr] = *(const bf16x8*)(Wl + (wo * 64 + rr * 16 + l15) * 44 + lg * 8);
#pragma unroll
    for (int ss = 0; ss < 4; ++ss)
      bb[ss] = *(const bf16x8*)(Xl + (wq * 64 + ss * 16 + l15) * 40 + ((lg ^ ss) << 3));
#pragma unroll
    for (int rr = 0; rr < 4; ++rr)
#pragma unroll
      for (int ss = 0; ss < 4; ++ss)
        acc[rr][ss] = __builtin_amdgcn_mfma_f32_16x16x32_bf16(a[rr], bb[ss], acc[rr][ss], 0, 0, 0);
    __syncthreads();
  }
#pragma unroll
  for (int rr = 0; rr < 4; ++rr) {
    int tb = t0 + wo * 64 + rr * 16 + lg * 4;
#pragma unroll
    for (int ss = 0; ss < 4; ++ss) {
      int p = p0 + wq * 64 + ss * 16 + l15;
#pragma unroll
      for (int k = 0; k < 4; ++k) {
        int t = tb + k;
        float val = acc[rr][ss][k];
        if (vec) val += vec[(size_t)b * T + t];
        Y[((size_t)b * T + t) * P + p] = val;
      }
    }
  }
}

// ---------------- fused gamma/beta GEMM + BN + ReLU + NHWC bf16 pack ----------------
__global__ __launch_bounds__(256, 1) void gbact_kernel(
    const float* __restrict__ Wg, const float* __restrict__ Wb,
    const float* __restrict__ ctx, const float* __restrict__ gvec,
    const float* __restrict__ bvec, const float* __restrict__ xin,
    const float* __restrict__ mean, const float* __restrict__ rstd,
    const float* __restrict__ bnw, const float* __restrict__ bnb,
    u16* __restrict__ outb, int C, int P) {
  __shared__ u16 shmem[17408];
  u16* Wgl = shmem;
  u16* Wbl = shmem + 5632;
  u16* Xl  = shmem + 11264;
  const int b = blockIdx.z, t0 = blockIdx.y * 128, p0 = blockIdx.x * 128;
  const int tid = threadIdx.x;
  const int w = tid >> 6, lane = tid & 63;
  const int wo = w >> 1, wq = w & 1;
  const int l15 = lane & 15, lg = lane >> 4;
  const float* Xb = ctx + (size_t)b * TD * P;
  const int wr = tid >> 1, wcH = tid & 1;
  const int xr = tid >> 3, xcG = tid & 7;
  const int csw = xr ^ ((xcG & 3) << 3);
  f32x4 accg[4][4] = {}, accb[4][4] = {};

  for (int c0 = 0; c0 < TD; c0 += 32) {
    {
      const float* sg = Wg + (size_t)(t0 + wr) * CONDC + GD + c0 + wcH * 16;
      const float* sb = Wb + (size_t)(t0 + wr) * CONDC + GD + c0 + wcH * 16;
      u16* dg = Wgl + wr * 44 + wcH * 16;
      u16* db = Wbl + wr * 44 + wcH * 16;
#pragma unroll
      for (int j = 0; j < 4; ++j) {
        float4 v = *(const float4*)(sg + j * 4);
        *(ushort4*)(dg + j * 4) = make_ushort4(f2b(v.x), f2b(v.y), f2b(v.z), f2b(v.w));
        float4 u = *(const float4*)(sb + j * 4);
        *(ushort4*)(db + j * 4) = make_ushort4(f2b(u.x), f2b(u.y), f2b(u.z), f2b(u.w));
      }
    }
    {
      const float* src = Xb + (size_t)(c0 + xr) * P + p0 + xcG * 16;
#pragma unroll
      for (int j = 0; j < 4; ++j) {
        float4 v = *(const float4*)(src + j * 4);
        int px = xcG * 16 + j * 4;
        Xl[(px + 0) * 40 + csw] = f2b(v.x);
        Xl[(px + 1) * 40 + csw] = f2b(v.y);
        Xl[(px + 2) * 40 + csw] = f2b(v.z);
        Xl[(px + 3) * 40 + csw] = f2b(v.w);
      }
    }
    __syncthreads();
    bf16x8 ag[4], ab[4], bb[4];
#pragma unroll
    for (int rr = 0; rr < 4; ++rr) {
      ag[rr] = *(const bf16x8*)(Wgl + (wo * 64 + rr * 16 + l15) * 44 + lg * 8);
      ab[rr] = *(const bf16x8*)(Wbl + (wo * 64 + rr * 16 + l15) * 44 + lg * 8);
    }
#pragma unroll
    for (int ss = 0; ss < 4; ++ss)
      bb[ss] = *(const bf16x8*)(Xl + (wq * 64 + ss * 16 + l15) * 40 + ((lg ^ ss) << 3));
#pragma unroll
    for (int rr = 0; rr < 4; ++rr)
#pragma unroll
      for (int ss = 0; ss < 4; ++ss) {
        accg[rr][ss] = __builtin_amdgcn_mfma_f32_16x16x32_bf16(ag[rr], bb[ss], accg[rr][ss], 0, 0, 0);
        accb[rr][ss] = __builtin_amdgcn_mfma_f32_16x16x32_bf16(ab[rr], bb[ss], accb[rr][ss], 0, 0, 0);
      }
    __syncthreads();
  }
#pragma unroll
  for (int rr = 0; rr < 4; ++rr) {
    float gv[4], bv[4], mm[4], rs[4], bB[4];
#pragma unroll
    for (int k = 0; k < 4; ++k) {
      int c = t0 + wo * 64 + rr * 16 + lg * 4 + k;
      gv[k] = gvec[(size_t)b * C + c];
      bv[k] = bvec[(size_t)b * C + c];
      mm[k] = mean[c]; rs[k] = rstd[c] * bnw[c]; bB[k] = bnb[c];
    }
#pragma unroll
    for (int ss = 0; ss < 4; ++ss) {
#pragma unroll
      for (int k = 0; k < 4; ++k) {
        int cl = wo * 64 + rr * 16 + lg * 4 + k;
        int pl = wq * 64 + ss * 16 + l15;
        float xv = xin[((size_t)b * C + t0 + cl) * P + p0 + pl];
        float g = accg[rr][ss][k] + gv[k];
        float be = accb[rr][ss][k] + bv[k];
        float val = fmaxf(g * ((xv - mm[k]) * rs[k] + bB[k]) + be, 0.f);
        shmem[pl * 136 + cl] = f2b(val);
      }
    }
  }
  __syncthreads();
  const int pr = tid >> 1, h = tid & 1;
#pragma unroll
  for (int j = 0; j < 8; ++j) {
    uint4 v = *(uint4*)(shmem + pr * 136 + h * 64 + j * 8);
    *(uint4*)(outb + ((size_t)b * P + p0 + pr) * C + t0 + h * 64 + j * 8) = v;
  }
}

// ---------------- pack conv weights: fragment-linear bf16 ----------------
__global__ void pack_w_kernel(const float* __restrict__ w, u16* __restrict__ wp, int O, int CIN) {
  int lin = blockIdx.x * 256 + threadIdx.x;
  if (lin >= O * CIN) return;
  int o = lin / CIN, c = lin - o * CIN;
  int c0blk = c >> 5, lg = (c >> 3) & 3, cc = c & 7;
  int ot = o >> 4, l15 = o & 15;
  int lane = lg * 16 + l15;
  size_t base = (((size_t)c0blk * (O >> 4) + ot) * 64 + lane) * 8 + cc;
  size_t posStride = (size_t)(CIN >> 5) * (O >> 4) * 512;
  const float* src = w + (size_t)lin * 9;
#pragma unroll
  for (int pos = 0; pos < 9; ++pos)
    wp[pos * posStride + base] = f2b(src[pos]);
}

// ---------------- bf16 MFMA implicit-GEMM 3x3 conv ----------------
// Block: 4 waves = 256o x 128px; wave tile 128o x 64px (8rr x 4ss).
// Xs stride 36 u16 (72B): word-stride 18, conflict-free b64 reads (round-10 layout).
template <int CIN, bool UP>
__global__ __launch_bounds__(256, 2) void conv_mfma_kernel(
    const u16* __restrict__ Wp, const u16* __restrict__ Xt,
    const float* __restrict__ scs, const float* __restrict__ scb,
    float* __restrict__ Y) {
  constexpr int S = UP ? 32 : 64;
  constexpr int NC0 = CIN >> 5;
  __shared__ u16 Xs[2][4 * 66 * 36];  // double buffer, 19008 B each
  const int b = blockIdx.z, pxT = blockIdx.x;
  const int tid = threadIdx.x;
  const int w = tid >> 6, lane = tid & 63;
  const int wo = w >> 1, wp_ = w & 1;
  const int l15 = lane & 15, lg = lane >> 4;
  const int Y0 = pxT * 2;
  const u16* Xb = Xt + (size_t)b * S * S * CIN;
  const size_t posStride = (size_t)NC0 * 16 * 512;
  f32x4 acc[8][4] = {};
  uint2 st[9];

  // prologue: load + write tile 0
#pragma unroll
  for (int j = 0; j < 9; ++j) {
    int i = tid + j * 256;
    if (i < 2112) {
      int r = i / 528, rem = i - r * 528, col = rem >> 3, ch = rem & 7;
      int uy = Y0 - 1 + r, ux = col - 1;
      uint2 v = make_uint2(0u, 0u);
      if (uy >= 0 && uy < 64 && ux >= 0 && ux < 64) {
        int sy = UP ? (uy >> 1) : uy, sx = UP ? (ux >> 1) : ux;
        v = *(const uint2*)(Xb + ((size_t)sy * S + sx) * CIN + ch * 4);
      }
      st[j] = v;
    }
  }
#pragma unroll
  for (int j = 0; j < 9; ++j) {
    int i = tid + j * 256;
    if (i < 2112) {
      int r = i / 528, rem = i - r * 528, col = rem >> 3, ch = rem & 7;
      *(uint2*)(&Xs[0][(r * 66 + col) * 36 + ch * 4]) = st[j];
    }
  }
  __syncthreads();

  for (int c0b = 0; c0b < NC0; ++c0b) {
    const int cur = c0b & 1;
    // early-issue loads for next tile (land during compute)
    if (c0b + 1 < NC0) {
      const int c0n = (c0b + 1) << 5;
#pragma unroll
      for (int j = 0; j < 9; ++j) {
        int i = tid + j * 256;
        if (i < 2112) {
          int r = i / 528, rem = i - r * 528, col = rem >> 3, ch = rem & 7;
          int uy = Y0 - 1 + r, ux = col - 1;
          uint2 v = make_uint2(0u, 0u);
          if (uy >= 0 && uy < 64 && ux >= 0 && ux < 64) {
            int sy = UP ? (uy >> 1) : uy, sx = UP ? (ux >> 1) : ux;
            v = *(const uint2*)(Xb + ((size_t)sy * S + sx) * CIN + c0n + ch * 4);
          }
          st[j] = v;
        }
      }
    }
    // compute: A-fragments (8 rr = 128 o) software-pipelined across pos
    {
      const u16* wbB = Wp + ((size_t)c0b * 16 + wo * 8) * 512 + lane * 8;
      bf16x8 aC[8], aN[8];
#pragma unroll
      for (int rr = 0; rr < 8; ++rr)
        aC[rr] = *(const bf16x8*)(wbB + rr * 512);
#pragma unroll
      for (int pos = 0; pos < 9; ++pos) {
        const int ky = pos / 3, kx = pos - ky * 3;
        if (pos < 8) {
          const u16* wbn = wbB + (size_t)(pos + 1) * posStride;
#pragma unroll
          for (int rr = 0; rr < 8; ++rr)
            aN[rr] = *(const bf16x8*)(wbn + rr * 512);
        }
        const int rowb = ((wp_ + ky) * 66 + kx) * 36 + lg * 8;
#pragma unroll
        for (int ss = 0; ss < 4; ++ss) {
          int idx = rowb + (ss * 16 + l15) * 36;
          union { uint2 q[2]; bf16x8 v; } u;
          u.q[0] = *(const uint2*)(&Xs[cur][idx]);
          u.q[1] = *(const uint2*)(&Xs[cur][idx + 4]);
#pragma unroll
          for (int rr = 0; rr < 8; ++rr)
            acc[rr][ss] = __builtin_amdgcn_mfma_f32_16x16x32_bf16(aC[rr], u.v, acc[rr][ss], 0, 0, 0);
        }
#pragma unroll
        for (int rr = 0; rr < 8; ++rr) aC[rr] = aN[rr];
      }
    }
    // write next tile into the other buffer; single barrier per iter
    if (c0b + 1 < NC0) {
#pragma unroll
      for (int j = 0; j < 9; ++j) {
        int i = tid + j * 256;
        if (i < 2112) {
          int r = i / 528, rem = i - r * 528, col = rem >> 3, ch = rem & 7;
          *(uint2*)(&Xs[cur ^ 1][(r * 66 + col) * 36 + ch * 4]) = st[j];
        }
      }
      __syncthreads();
    }
  }
  const int oBase = wo * 128 + lg * 4;
  const int pxBase = pxT * 128 + wp_ * 64 + l15;
#pragma unroll
  for (int rr = 0; rr < 8; ++rr) {
#pragma unroll
    for (int ss = 0; ss < 4; ++ss) {
      int px = pxBase + ss * 16;
#pragma unroll
      for (int k = 0; k < 4; ++k) {
        int o = oBase + rr * 16 + k;
        float val = acc[rr][ss][k];
        if (scs) {
          int gx = px & 63;
          val += scs[((size_t)b * COUT + o) * P1 + pxT * 32 + (gx >> 1)] + scb[o];
        }
        Y[((size_t)b * COUT + o) * 4096 + px] = val;
      }
    }
  }
}

extern "C" void kernel_launch(void* const* d_in, const int* in_sizes, int n_in,
                              void* d_out, int out_size, void* d_ws, size_t ws_size,
                              hipStream_t stream) {
  const float* x      = (const float*)d_in[0];
  const float* gcond  = (const float*)d_in[1];
  const float* wemb   = (const float*)d_in[2];
  const int*   mask   = (const int*)d_in[3];
  const float* w_img1 = (const float*)d_in[4];
  const float* w_img2 = (const float*)d_in[5];
  const float* w_c1   = (const float*)d_in[6];
  const float* w_c2   = (const float*)d_in[7];
  const float* bn1_w  = (const float*)d_in[8];
  const float* bn1_b  = (const float*)d_in[9];
  const float* bn2_w  = (const float*)d_in[10];
  const float* bn2_b  = (const float*)d_in[11];
  const float* w_g1   = (const float*)d_in[12];
  const float* b_g1   = (const float*)d_in[13];
  const float* w_b1   = (const float*)d_in[14];
  const float* b_b1   = (const float*)d_in[15];
  const float* w_g2   = (const float*)d_in[16];
  const float* b_g2   = (const float*)d_in[17];
  const float* w_b2   = (const float*)d_in[18];
  const float* b_b2   = (const float*)d_in[19];
  const float* w_sc   = (const float*)d_in[20];
  const float* b_sc   = (const float*)d_in[21];
  float* out = (float*)d_out;
  float* ws = (float*)d_ws;

  const size_t MF = 16777216;  // floats per 64MB region
  float* A  = ws;
  float* Br = ws + MF;
  float* Cr = ws + 2 * MF;
  float* SM = ws + 3 * MF;
  float* wdn   = SM;                     // 131072
  float* mean1 = SM + 131072;
  float* rstd1 = mean1 + 512;
  float* mean2 = rstd1 + 512;
  float* rstd2 = mean2 + 256;
  float* gvec1 = rstd2 + 256;            // 8192
  float* bvec1 = gvec1 + 8192;
  float* gvec2 = bvec1 + 8192;           // 4096
  float* bvec2 = gvec2 + 4096;
  float* wsp   = bvec2 + 4096;
  u16* Wp1 = (u16*)wsp;                  // 9*256*512 ushorts
  u16* Wp2 = (u16*)(wsp + 655360);       // 9*256*256 ushorts

  float* img1   = A;                     // 4M floats
  float* ctx1   = A + 4194304;           // 4M floats
  u16*   Xt1    = (u16*)(A + 8388608);   // 8.4M u16 NHWC bf16
  float* conv1o = Cr;                    // 16M floats
  float* img2   = Br;                    // 16M floats
  float* ctx2   = A;                     // reuse (all of A dead after conv1)
  u16*   Xt2    = (u16*)Br;              // reuse (img2 dead after attnctx2)
  float* scs    = Cr;                    // reuse (conv1o dead after gbact2)

  // ---- stage 1 ----
  bn_stats_kernel<<<dim3(CIN1), dim3(256), 0, stream>>>(x, mean1, rstd1, CIN1, P1);
  wdn_kernel<<<dim3(NB * LL), dim3(64), 0, stream>>>(wemb, wdn);
  pack_w_kernel<<<dim3(COUT * CIN1 / 256), dim3(256), 0, stream>>>(w_c1, Wp1, COUT, CIN1);
  pack_w_kernel<<<dim3(COUT * COUT / 256), dim3(256), 0, stream>>>(w_c2, Wp2, COUT, COUT);
  gemm_mfma_kernel<<<dim3(P1 / 128, TD / 128, NB), dim3(256), 0, stream>>>(
      w_img1, CIN1, 0, x, nullptr, img1, TD, CIN1, P1);
  attnctx_kernel<<<dim3(P1 / 64, NB), dim3(256), 0, stream>>>(img1, wdn, mask, ctx1, P1);
  gvec_kernel<<<dim3(CIN1 / 64, NB), dim3(64), 0, stream>>>(w_g1, b_g1, gcond, gvec1, CIN1);
  gvec_kernel<<<dim3(CIN1 / 64, NB), dim3(64), 0, stream>>>(w_b1, b_b1, gcond, bvec1, CIN1);
  gbact_kernel<<<dim3(P1 / 128, CIN1 / 128, NB), dim3(256), 0, stream>>>(
      w_g1, w_b1, ctx1, gvec1, bvec1, x, mean1, rstd1, bn1_w, bn1_b, Xt1, CIN1, P1);
  conv_mfma_kernel<CIN1, true><<<dim3(32, 1, NB), dim3(256), 0, stream>>>(
      Wp1, Xt1, nullptr, nullptr, conv1o);

  // ---- stage 2 ----
  bn_stats_kernel<<<dim3(COUT), dim3(256), 0, stream>>>(conv1o, mean2, rstd2, COUT, P2);
  gemm_mfma_kernel<<<dim3(P2 / 128, TD / 128, NB), dim3(256), 0, stream>>>(
      w_img2, COUT, 0, conv1o, nullptr, img2, TD, COUT, P2);
  attnctx_kernel<<<dim3(P2 / 64, NB), dim3(256), 0, stream>>>(img2, wdn, mask, ctx2, P2);
  gvec_kernel<<<dim3(COUT / 64, NB), dim3(64), 0, stream>>>(w_g2, b_g2, gcond, gvec2, COUT);
  gvec_kernel<<<dim3(COUT / 64, NB), dim3(64), 0, stream>>>(w_b2, b_b2, gcond, bvec2, COUT);
  gbact_kernel<<<dim3(P2 / 128, COUT / 128, NB), dim3(256), 0, stream>>>(
      w_g2, w_b2, ctx2, gvec2, bvec2, conv1o, mean2, rstd2, bn2_w, bn2_b, Xt2, COUT, P2);
  gemm_mfma_kernel<<<dim3(P1 / 128, COUT / 128, NB), dim3(256), 0, stream>>>(
      w_sc, CIN1, 0, x, nullptr, scs, COUT, CIN1, P1);
  conv_mfma_kernel<COUT, false><<<dim3(32, 1, NB), dim3(256), 0, stream>>>(
      Wp2, Xt2, scs, b_sc, out);
}

// Round 13
// 546.364 us; speedup vs baseline: 1.2630x; 1.1586x over previous
//
#include <hip/hip_runtime.h>
#include <hip/hip_bf16.h>
#include <math.h>

#define NB 16
#define CIN1 512
#define COUT 256
#define GD 256
#define TD 256
#define LL 32
#define P1 1024
#define P2 4096
#define CONDC 512

typedef __attribute__((ext_vector_type(8))) short bf16x8;
typedef __attribute__((ext_vector_type(4))) float f32x4;
typedef unsigned short u16;

__device__ __forceinline__ u16 f2b(float f) {
  __hip_bfloat16 h = __float2bfloat16(f);
  return *(u16*)&h;
}

// ---------------- BN stats: mean + rsqrt(var+eps) per channel ----------------
__global__ void bn_stats_kernel(const float* __restrict__ x, float* __restrict__ mean,
                                float* __restrict__ rstd, int C, int HW) {
  int c = blockIdx.x, t = threadIdx.x;
  float s = 0.f, sq = 0.f;
  for (int b = 0; b < NB; ++b) {
    const float* p = x + ((size_t)b * C + c) * HW;
    for (int i = t; i < HW; i += 256) { float v = p[i]; s += v; sq += v * v; }
  }
  __shared__ float ss[256], sq2[256];
  ss[t] = s; sq2[t] = sq; __syncthreads();
  for (int o = 128; o > 0; o >>= 1) {
    if (t < o) { ss[t] += ss[t + o]; sq2[t] += sq2[t + o]; }
    __syncthreads();
  }
  if (t == 0) {
    float n = (float)NB * (float)HW;
    float m = ss[0] / n;
    float v = sq2[0] / n - m * m;
    mean[c] = m;
    rstd[c] = rsqrtf(v + 1e-5f);
  }
}

// ---------------- normalize words_embs over channel dim per (b,l) ----------------
__global__ void wdn_kernel(const float* __restrict__ we, float* __restrict__ wdn) {
  int b = blockIdx.x >> 5, l = blockIdx.x & 31;
  int t = threadIdx.x; // 64
  const float* base = we + (size_t)b * TD * LL + l;
  float v[4]; float sq = 0.f;
#pragma unroll
  for (int k = 0; k < 4; ++k) { v[k] = base[(size_t)(t * 4 + k) * LL]; sq += v[k] * v[k]; }
#pragma unroll
  for (int o = 32; o > 0; o >>= 1) sq += __shfl_xor(sq, o);
  float r = 1.f / fmaxf(sqrtf(sq), 1e-12f);
  float* ob = wdn + (size_t)b * TD * LL + l;
#pragma unroll
  for (int k = 0; k < 4; ++k) ob[(size_t)(t * 4 + k) * LL] = v[k] * r;
}

// ---------------- gvec[b,o] = bias[o] + sum_{c<GD} W[o,c]*gc[b,c] ----------------
__global__ void gvec_kernel(const float* __restrict__ Wg, const float* __restrict__ bias,
                            const float* __restrict__ gc, float* __restrict__ outv, int O) {
  int o = blockIdx.x * 64 + threadIdx.x;
  int b = blockIdx.y;
  if (o >= O) return;
  const float* wr = Wg + (size_t)o * CONDC;
  const float* g = gc + (size_t)b * GD;
  float s = 0.f;
  for (int c = 0; c < GD; ++c) s += wr[c] * g[c];
  outv[(size_t)b * O + o] = s + bias[o];
}

// ---------------- fused attention: l2norm -> sim (MFMA) -> softmax -> ctx (MFMA) ----------------
__global__ __launch_bounds__(256) void attnctx_kernel(
    const float* __restrict__ img, const float* __restrict__ wdn,
    const int* __restrict__ mask, float* __restrict__ ctx, int P) {
  __shared__ u16 imgT[64 * 72];
  __shared__ u16 wdnT[32 * 264];
  __shared__ u16 wdnC[256 * 40];
  __shared__ u16 attnB[64 * 40];
  __shared__ float sqP[4][64];
  __shared__ float rnL[64];
  const int b = blockIdx.y, p0 = blockIdx.x * 64;
  const int tid = threadIdx.x;
  const int w = tid >> 6, lane = tid & 63;
  const int l15 = lane & 15, lg = lane >> 4;
  const float* ib = img + (size_t)b * TD * P;
  const float* wb = wdn + (size_t)b * TD * LL;

  for (int i = tid; i < TD * LL; i += 256) {
    int t = i >> 5, l = i & 31;
    u16 v = f2b(wb[i]);
    wdnT[l * 264 + t] = v;
    wdnC[t * 40 + l] = v;
  }

  f32x4 s0 = {}, s1 = {};
  float ssq = 0.f;
  for (int q = 0; q < 4; ++q) {
#pragma unroll
    for (int i = 0; i < 16; i += 2) {
      int t = q * 64 + w * 16 + i;
      float v0 = ib[(size_t)t * P + p0 + lane];
      float v1 = ib[(size_t)(t + 1) * P + p0 + lane];
      ssq += v0 * v0 + v1 * v1;
      unsigned pk = (unsigned)f2b(v0) | ((unsigned)f2b(v1) << 16);
      *(unsigned*)(imgT + lane * 72 + w * 16 + i) = pk;
    }
    __syncthreads();
#pragma unroll
    for (int ks = 0; ks < 2; ++ks) {
      bf16x8 a = *(const bf16x8*)(imgT + (w * 16 + l15) * 72 + ks * 32 + lg * 8);
      bf16x8 b0 = *(const bf16x8*)(wdnT + l15 * 264 + q * 64 + ks * 32 + lg * 8);
      bf16x8 b1 = *(const bf16x8*)(wdnT + (16 + l15) * 264 + q * 64 + ks * 32 + lg * 8);
      s0 = __builtin_amdgcn_mfma_f32_16x16x32_bf16(a, b0, s0, 0, 0, 0);
      s1 = __builtin_amdgcn_mfma_f32_16x16x32_bf16(a, b1, s1, 0, 0, 0);
    }
    __syncthreads();
  }
  sqP[w][lane] = ssq;
  __syncthreads();
  if (tid < 64) {
    float s = sqP[0][tid] + sqP[1][tid] + sqP[2][tid] + sqP[3][tid];
    rnL[tid] = 1.f / fmaxf(sqrtf(s), 1e-12f);
  }
  __syncthreads();
  const bool m0 = mask[b * LL + l15] != 0;
  const bool m1 = mask[b * LL + 16 + l15] != 0;
#pragma unroll
  for (int k = 0; k < 4; ++k) {
    float rn = rnL[w * 16 + lg * 4 + k];
    float v0 = m0 ? -INFINITY : s0[k] * rn;
    float v1 = m1 ? -INFINITY : s1[k] * rn;
    float mx = fmaxf(v0, v1);
#pragma unroll
    for (int o = 1; o < 16; o <<= 1) mx = fmaxf(mx, __shfl_xor(mx, o));
    float e0 = expf(v0 - mx), e1 = expf(v1 - mx);
    float sm = e0 + e1;
#pragma unroll
    for (int o = 1; o < 16; o <<= 1) sm += __shfl_xor(sm, o);
    float inv = 1.f / sm;
    int px = w * 16 + lg * 4 + k;
    attnB[px * 40 + l15] = f2b(e0 * inv);
    attnB[px * 40 + 16 + l15] = f2b(e1 * inv);
  }
  __syncthreads();
  f32x4 acc[4][4] = {};
  bf16x8 bfr[4];
#pragma unroll
  for (int pt = 0; pt < 4; ++pt)
    bfr[pt] = *(const bf16x8*)(attnB + (pt * 16 + l15) * 40 + lg * 8);
#pragma unroll
  for (int cc = 0; cc < 4; ++cc) {
    bf16x8 a = *(const bf16x8*)(wdnC + ((w * 4 + cc) * 16 + l15) * 40 + lg * 8);
#pragma unroll
    for (int pt = 0; pt < 4; ++pt)
      acc[cc][pt] = __builtin_amdgcn_mfma_f32_16x16x32_bf16(a, bfr[pt], acc[cc][pt], 0, 0, 0);
  }
#pragma unroll
  for (int cc = 0; cc < 4; ++cc) {
#pragma unroll
    for (int pt = 0; pt < 4; ++pt) {
#pragma unroll
      for (int k = 0; k < 4; ++k) {
        int c = (w * 4 + cc) * 16 + lg * 4 + k;
        ctx[((size_t)b * TD + c) * P + p0 + pt * 16 + l15] = acc[cc][pt][k];
      }
    }
  }
}

// ---------------- bf16 MFMA GEMM (img1/img2/shortcut): double-buffered reg-staged ----------------
__global__ __launch_bounds__(256, 2) void gemm_mfma_kernel(
    const float* __restrict__ W, int ldw, int c_off,
    const float* __restrict__ X, const float* __restrict__ vec,
    float* __restrict__ Y, int T, int C, int P) {
  __shared__ u16 Wl[2][128 * 44];
  __shared__ u16 Xl[2][128 * 40];
  const int b = blockIdx.z;
  const int t0 = blockIdx.y * 128, p0 = blockIdx.x * 128;
  const int tid = threadIdx.x;
  const int w = tid >> 6, lane = tid & 63;
  const int wo = w >> 1, wq = w & 1;
  const int l15 = lane & 15, lg = lane >> 4;
  const float* Xb = X + (size_t)b * C * P;
  const int wr = tid >> 1, wcH = tid & 1;
  const int xr = tid >> 3, xcG = tid & 7;
  const int csw = xr ^ ((xcG & 3) << 3);
  const float* wsrc = W + (size_t)(t0 + wr) * ldw + c_off + wcH * 16;
  const float* xsrc = Xb + (size_t)xr * P + p0 + xcG * 16;
  const int NK = C / 32;
  f32x4 acc[4][4] = {};
  float4 wreg[4], xreg[4];

  // prologue: tile 0 -> buf 0
#pragma unroll
  for (int j = 0; j < 4; ++j) {
    wreg[j] = *(const float4*)(wsrc + j * 4);
    xreg[j] = *(const float4*)(xsrc + j * 4);
  }
  {
    u16* dst = Wl[0] + wr * 44 + wcH * 16;
#pragma unroll
    for (int j = 0; j < 4; ++j) {
      *(ushort4*)(dst + j * 4) = make_ushort4(f2b(wreg[j].x), f2b(wreg[j].y), f2b(wreg[j].z), f2b(wreg[j].w));
      int px = xcG * 16 + j * 4;
      Xl[0][(px + 0) * 40 + csw] = f2b(xreg[j].x);
      Xl[0][(px + 1) * 40 + csw] = f2b(xreg[j].y);
      Xl[0][(px + 2) * 40 + csw] = f2b(xreg[j].z);
      Xl[0][(px + 3) * 40 + csw] = f2b(xreg[j].w);
    }
  }
  __syncthreads();

  for (int kb = 0; kb < NK; ++kb) {
    const int cur = kb & 1;
    if (kb + 1 < NK) {
      const int c0n = (kb + 1) * 32;
#pragma unroll
      for (int j = 0; j < 4; ++j) {
        wreg[j] = *(const float4*)(wsrc + c0n + j * 4);
        xreg[j] = *(const float4*)(xsrc + (size_t)c0n * P + j * 4);
      }
    }
    bf16x8 a[4], bb[4];
#pragma unroll
    for (int rr = 0; rr < 4; ++rr)
      a[rr] = *(const bf16x8*)(Wl[cur] + (wo * 64 + rr * 16 + l15) * 44 + lg * 8);
#pragma unroll
    for (int ss = 0; ss < 4; ++ss)
      bb[ss] = *(const bf16x8*)(Xl[cur] + (wq * 64 + ss * 16 + l15) * 40 + ((lg ^ ss) << 3));
#pragma unroll
    for (int rr = 0; rr < 4; ++rr)
#pragma unroll
      for (int ss = 0; ss < 4; ++ss)
        acc[rr][ss] = __builtin_amdgcn_mfma_f32_16x16x32_bf16(a[rr], bb[ss], acc[rr][ss], 0, 0, 0);
    if (kb + 1 < NK) {
      const int nxt = cur ^ 1;
      u16* dst = Wl[nxt] + wr * 44 + wcH * 16;
#pragma unroll
      for (int j = 0; j < 4; ++j) {
        *(ushort4*)(dst + j * 4) = make_ushort4(f2b(wreg[j].x), f2b(wreg[j].y), f2b(wreg[j].z), f2b(wreg[j].w));
        int px = xcG * 16 + j * 4;
        Xl[nxt][(px + 0) * 40 + csw] = f2b(xreg[j].x);
        Xl[nxt][(px + 1) * 40 + csw] = f2b(xreg[j].y);
        Xl[nxt][(px + 2) * 40 + csw] = f2b(xreg[j].z);
        Xl[nxt][(px + 3) * 40 + csw] = f2b(xreg[j].w);
      }
      __syncthreads();
    }
  }
#pragma unroll
  for (int rr = 0; rr < 4; ++rr) {
    int tb = t0 + wo * 64 + rr * 16 + lg * 4;
#pragma unroll
    for (int ss = 0; ss < 4; ++ss) {
      int p = p0 + wq * 64 + ss * 16 + l15;
#pragma unroll
      for (int k = 0; k < 4; ++k) {
        int t = tb + k;
        float val = acc[rr][ss][k];
        if (vec) val += vec[(size_t)b * T + t];
        Y[((size_t)b * T + t) * P + p] = val;
      }
    }
  }
}

// ---------------- fused gamma/beta GEMM + BN + ReLU + NHWC pack (dbuf reg-staged) ----------------
__global__ __launch_bounds__(256, 2) void gbact_kernel(
    const float* __restrict__ Wg, const float* __restrict__ Wb,
    const float* __restrict__ ctx, const float* __restrict__ gvec,
    const float* __restrict__ bvec, const float* __restrict__ xin,
    const float* __restrict__ mean, const float* __restrict__ rstd,
    const float* __restrict__ bnw, const float* __restrict__ bnb,
    u16* __restrict__ outb, int C, int P) {
  __shared__ u16 shmem[2][16384];  // per buf: Wgl 5632 | Wbl 5632 | Xl 5120; flat for transpose
  const int b = blockIdx.z, t0 = blockIdx.y * 128, p0 = blockIdx.x * 128;
  const int tid = threadIdx.x;
  const int w = tid >> 6, lane = tid & 63;
  const int wo = w >> 1, wq = w & 1;
  const int l15 = lane & 15, lg = lane >> 4;
  const float* Xb = ctx + (size_t)b * TD * P;
  const int wr = tid >> 1, wcH = tid & 1;
  const int xr = tid >> 3, xcG = tid & 7;
  const int csw = xr ^ ((xcG & 3) << 3);
  const float* gsrc = Wg + (size_t)(t0 + wr) * CONDC + GD + wcH * 16;
  const float* bsrc = Wb + (size_t)(t0 + wr) * CONDC + GD + wcH * 16;
  const float* xsrc = Xb + (size_t)xr * P + p0 + xcG * 16;
  const int NK = TD / 32;
  f32x4 accg[4][4] = {}, accb[4][4] = {};
  float4 greg[4], breg[4], xreg[4];

#pragma unroll
  for (int j = 0; j < 4; ++j) {
    greg[j] = *(const float4*)(gsrc + j * 4);
    breg[j] = *(const float4*)(bsrc + j * 4);
    xreg[j] = *(const float4*)(xsrc + j * 4);
  }
  {
    u16* dg = shmem[0] + wr * 44 + wcH * 16;
    u16* db = shmem[0] + 5632 + wr * 44 + wcH * 16;
    u16* xl = shmem[0] + 11264;
#pragma unroll
    for (int j = 0; j < 4; ++j) {
      *(ushort4*)(dg + j * 4) = make_ushort4(f2b(greg[j].x), f2b(greg[j].y), f2b(greg[j].z), f2b(greg[j].w));
      *(ushort4*)(db + j * 4) = make_ushort4(f2b(breg[j].x), f2b(breg[j].y), f2b(breg[j].z), f2b(breg[j].w));
      int px = xcG * 16 + j * 4;
      xl[(px + 0) * 40 + csw] = f2b(xreg[j].x);
      xl[(px + 1) * 40 + csw] = f2b(xreg[j].y);
      xl[(px + 2) * 40 + csw] = f2b(xreg[j].z);
      xl[(px + 3) * 40 + csw] = f2b(xreg[j].w);
    }
  }
  __syncthreads();

  for (int kb = 0; kb < NK; ++kb) {
    const int cur = kb & 1;
    if (kb + 1 < NK) {
      const int c0n = (kb + 1) * 32;
#pragma unroll
      for (int j = 0; j < 4; ++j) {
        greg[j] = *(const float4*)(gsrc + c0n + j * 4);
        breg[j] = *(const float4*)(bsrc + c0n + j * 4);
        xreg[j] = *(const float4*)(xsrc + (size_t)c0n * P + j * 4);
      }
    }
    bf16x8 ag[4], ab[4], bb[4];
#pragma unroll
    for (int rr = 0; rr < 4; ++rr) {
      ag[rr] = *(const bf16x8*)(shmem[cur] + (wo * 64 + rr * 16 + l15) * 44 + lg * 8);
      ab[rr] = *(const bf16x8*)(shmem[cur] + 5632 + (wo * 64 + rr * 16 + l15) * 44 + lg * 8);
    }
#pragma unroll
    for (int ss = 0; ss < 4; ++ss)
      bb[ss] = *(const bf16x8*)(shmem[cur] + 11264 + (wq * 64 + ss * 16 + l15) * 40 + ((lg ^ ss) << 3));
#pragma unroll
    for (int rr = 0; rr < 4; ++rr)
#pragma unroll
      for (int ss = 0; ss < 4; ++ss) {
        accg[rr][ss] = __builtin_amdgcn_mfma_f32_16x16x32_bf16(ag[rr], bb[ss], accg[rr][ss], 0, 0, 0);
        accb[rr][ss] = __builtin_amdgcn_mfma_f32_16x16x32_bf16(ab[rr], bb[ss], accb[rr][ss], 0, 0, 0);
      }
    if (kb + 1 < NK) {
      const int nxt = cur ^ 1;
      u16* dg = shmem[nxt] + wr * 44 + wcH * 16;
      u16* db = shmem[nxt] + 5632 + wr * 44 + wcH * 16;
      u16* xl = shmem[nxt] + 11264;
#pragma unroll
      for (int j = 0; j < 4; ++j) {
        *(ushort4*)(dg + j * 4) = make_ushort4(f2b(greg[j].x), f2b(greg[j].y), f2b(greg[j].z), f2b(greg[j].w));
        *(ushort4*)(db + j * 4) = make_ushort4(f2b(breg[j].x), f2b(breg[j].y), f2b(breg[j].z), f2b(breg[j].w));
        int px = xcG * 16 + j * 4;
        xl[(px + 0) * 40 + csw] = f2b(xreg[j].x);
        xl[(px + 1) * 40 + csw] = f2b(xreg[j].y);
        xl[(px + 2) * 40 + csw] = f2b(xreg[j].z);
        xl[(px + 3) * 40 + csw] = f2b(xreg[j].w);
      }
      __syncthreads();
    }
  }
  __syncthreads();  // all waves done reading LDS before transpose reuse
  u16* tbuf = &shmem[0][0];
#pragma unroll
  for (int rr = 0; rr < 4; ++rr) {
    float gv[4], bv[4], mm[4], rs[4], bB[4];
#pragma unroll
    for (int k = 0; k < 4; ++k) {
      int c = t0 + wo * 64 + rr * 16 + lg * 4 + k;
      gv[k] = gvec[(size_t)b * C + c];
      bv[k] = bvec[(size_t)b * C + c];
      mm[k] = mean[c]; rs[k] = rstd[c] * bnw[c]; bB[k] = bnb[c];
    }
#pragma unroll
    for (int ss = 0; ss < 4; ++ss) {
#pragma unroll
      for (int k = 0; k < 4; ++k) {
        int cl = wo * 64 + rr * 16 + lg * 4 + k;
        int pl = wq * 64 + ss * 16 + l15;
        float xv = xin[((size_t)b * C + t0 + cl) * P + p0 + pl];
        float g = accg[rr][ss][k] + gv[k];
        float be = accb[rr][ss][k] + bv[k];
        float val = fmaxf(g * ((xv - mm[k]) * rs[k] + bB[k]) + be, 0.f);
        tbuf[pl * 136 + cl] = f2b(val);
      }
    }
  }
  __syncthreads();
  const int pr = tid >> 1, h = tid & 1;
#pragma unroll
  for (int j = 0; j < 8; ++j) {
    uint4 v = *(uint4*)(tbuf + pr * 136 + h * 64 + j * 8);
    *(uint4*)(outb + ((size_t)b * P + p0 + pr) * C + t0 + h * 64 + j * 8) = v;
  }
}

// ---------------- pack conv weights: fragment-linear bf16 ----------------
__global__ void pack_w_kernel(const float* __restrict__ w, u16* __restrict__ wp, int O, int CIN) {
  int lin = blockIdx.x * 256 + threadIdx.x;
  if (lin >= O * CIN) return;
  int o = lin / CIN, c = lin - o * CIN;
  int c0blk = c >> 5, lg = (c >> 3) & 3, cc = c & 7;
  int ot = o >> 4, l15 = o & 15;
  int lane = lg * 16 + l15;
  size_t base = (((size_t)c0blk * (O >> 4) + ot) * 64 + lane) * 8 + cc;
  size_t posStride = (size_t)(CIN >> 5) * (O >> 4) * 512;
  const float* src = w + (size_t)lin * 9;
#pragma unroll
  for (int pos = 0; pos < 9; ++pos)
    wp[pos * posStride + base] = f2b(src[pos]);
}

// ---------------- bf16 MFMA implicit-GEMM 3x3 conv ----------------
// Block: 4 waves = 256o x 128px; wave tile 128o x 64px (8rr x 4ss).
// Xs stride 36 u16 (72B): word-stride 18, conflict-free b64 reads.
template <int CIN, bool UP>
__global__ __launch_bounds__(256, 2) void conv_mfma_kernel(
    const u16* __restrict__ Wp, const u16* __restrict__ Xt,
    const float* __restrict__ scs, const float* __restrict__ scb,
    float* __restrict__ Y) {
  constexpr int S = UP ? 32 : 64;
  constexpr int NC0 = CIN >> 5;
  __shared__ u16 Xs[2][4 * 66 * 36];  // double buffer, 19008 B each
  const int b = blockIdx.z, pxT = blockIdx.x;
  const int tid = threadIdx.x;
  const int w = tid >> 6, lane = tid & 63;
  const int wo = w >> 1, wp_ = w & 1;
  const int l15 = lane & 15, lg = lane >> 4;
  const int Y0 = pxT * 2;
  const u16* Xb = Xt + (size_t)b * S * S * CIN;
  const size_t posStride = (size_t)NC0 * 16 * 512;
  f32x4 acc[8][4] = {};
  uint2 st[9];

  // prologue: load + write tile 0
#pragma unroll
  for (int j = 0; j < 9; ++j) {
    int i = tid + j * 256;
    if (i < 2112) {
      int r = i / 528, rem = i - r * 528, col = rem >> 3, ch = rem & 7;
      int uy = Y0 - 1 + r, ux = col - 1;
      uint2 v = make_uint2(0u, 0u);
      if (uy >= 0 && uy < 64 && ux >= 0 && ux < 64) {
        int sy = UP ? (uy >> 1) : uy, sx = UP ? (ux >> 1) : ux;
        v = *(const uint2*)(Xb + ((size_t)sy * S + sx) * CIN + ch * 4);
      }
      st[j] = v;
    }
  }
#pragma unroll
  for (int j = 0; j < 9; ++j) {
    int i = tid + j * 256;
    if (i < 2112) {
      int r = i / 528, rem = i - r * 528, col = rem >> 3, ch = rem & 7;
      *(uint2*)(&Xs[0][(r * 66 + col) * 36 + ch * 4]) = st[j];
    }
  }
  __syncthreads();

  for (int c0b = 0; c0b < NC0; ++c0b) {
    const int cur = c0b & 1;
    // early-issue loads for next tile (land during compute)
    if (c0b + 1 < NC0) {
      const int c0n = (c0b + 1) << 5;
#pragma unroll
      for (int j = 0; j < 9; ++j) {
        int i = tid + j * 256;
        if (i < 2112) {
          int r = i / 528, rem = i - r * 528, col = rem >> 3, ch = rem & 7;
          int uy = Y0 - 1 + r, ux = col - 1;
          uint2 v = make_uint2(0u, 0u);
          if (uy >= 0 && uy < 64 && ux >= 0 && ux < 64) {
            int sy = UP ? (uy >> 1) : uy, sx = UP ? (ux >> 1) : ux;
            v = *(const uint2*)(Xb + ((size_t)sy * S + sx) * CIN + c0n + ch * 4);
          }
          st[j] = v;
        }
      }
    }
    // compute: A-fragments (8 rr = 128 o) software-pipelined across pos
    {
      const u16* wbB = Wp + ((size_t)c0b * 16 + wo * 8) * 512 + lane * 8;
      bf16x8 aC[8], aN[8];
#pragma unroll
      for (int rr = 0; rr < 8; ++rr)
        aC[rr] = *(const bf16x8*)(wbB + rr * 512);
#pragma unroll
      for (int pos = 0; pos < 9; ++pos) {
        const int ky = pos / 3, kx = pos - ky * 3;
        if (pos < 8) {
          const u16* wbn = wbB + (size_t)(pos + 1) * posStride;
#pragma unroll
          for (int rr = 0; rr < 8; ++rr)
            aN[rr] = *(const bf16x8*)(wbn + rr * 512);
        }
        const int rowb = ((wp_ + ky) * 66 + kx) * 36 + lg * 8;
#pragma unroll
        for (int ss = 0; ss < 4; ++ss) {
          int idx = rowb + (ss * 16 + l15) * 36;
          union { uint2 q[2]; bf16x8 v; } u;
          u.q[0] = *(const uint2*)(&Xs[cur][idx]);
          u.q[1] = *(const uint2*)(&Xs[cur][idx + 4]);
#pragma unroll
          for (int rr = 0; rr < 8; ++rr)
            acc[rr][ss] = __builtin_amdgcn_mfma_f32_16x16x32_bf16(aC[rr], u.v, acc[rr][ss], 0, 0, 0);
        }
#pragma unroll
        for (int rr = 0; rr < 8; ++rr) aC[rr] = aN[rr];
      }
    }
    // write next tile into the other buffer; single barrier per iter
    if (c0b + 1 < NC0) {
#pragma unroll
      for (int j = 0; j < 9; ++j) {
        int i = tid + j * 256;
        if (i < 2112) {
          int r = i / 528, rem = i - r * 528, col = rem >> 3, ch = rem & 7;
          *(uint2*)(&Xs[cur ^ 1][(r * 66 + col) * 36 + ch * 4]) = st[j];
        }
      }
      __syncthreads();
    }
  }
  const int oBase = wo * 128 + lg * 4;
  const int pxBase = pxT * 128 + wp_ * 64 + l15;
#pragma unroll
  for (int rr = 0; rr < 8; ++rr) {
#pragma unroll
    for (int ss = 0; ss < 4; ++ss) {
      int px = pxBase + ss * 16;
#pragma unroll
      for (int k = 0; k < 4; ++k) {
        int o = oBase + rr * 16 + k;
        float val = acc[rr][ss][k];
        if (scs) {
          int gx = px & 63;
          val += scs[((size_t)b * COUT + o) * P1 + pxT * 32 + (gx >> 1)] + scb[o];
        }
        Y[((size_t)b * COUT + o) * 4096 + px] = val;
      }
    }
  }
}

extern "C" void kernel_launch(void* const* d_in, const int* in_sizes, int n_in,
                              void* d_out, int out_size, void* d_ws, size_t ws_size,
                              hipStream_t stream) {
  const float* x      = (const float*)d_in[0];
  const float* gcond  = (const float*)d_in[1];
  const float* wemb   = (const float*)d_in[2];
  const int*   mask   = (const int*)d_in[3];
  const float* w_img1 = (const float*)d_in[4];
  const float* w_img2 = (const float*)d_in[5];
  const float* w_c1   = (const float*)d_in[6];
  const float* w_c2   = (const float*)d_in[7];
  const float* bn1_w  = (const float*)d_in[8];
  const float* bn1_b  = (const float*)d_in[9];
  const float* bn2_w  = (const float*)d_in[10];
  const float* bn2_b  = (const float*)d_in[11];
  const float* w_g1   = (const float*)d_in[12];
  const float* b_g1   = (const float*)d_in[13];
  const float* w_b1   = (const float*)d_in[14];
  const float* b_b1   = (const float*)d_in[15];
  const float* w_g2   = (const float*)d_in[16];
  const float* b_g2   = (const float*)d_in[17];
  const float* w_b2   = (const float*)d_in[18];
  const float* b_b2   = (const float*)d_in[19];
  const float* w_sc   = (const float*)d_in[20];
  const float* b_sc   = (const float*)d_in[21];
  float* out = (float*)d_out;
  float* ws = (float*)d_ws;

  const size_t MF = 16777216;  // floats per 64MB region
  float* A  = ws;
  float* Br = ws + MF;
  float* Cr = ws + 2 * MF;
  float* SM = ws + 3 * MF;
  float* wdn   = SM;                     // 131072
  float* mean1 = SM + 131072;
  float* rstd1 = mean1 + 512;
  float* mean2 = rstd1 + 512;
  float* rstd2 = mean2 + 256;
  float* gvec1 = rstd2 + 256;            // 8192
  float* bvec1 = gvec1 + 8192;
  float* gvec2 = bvec1 + 8192;           // 4096
  float* bvec2 = gvec2 + 4096;
  float* wsp   = bvec2 + 4096;
  u16* Wp1 = (u16*)wsp;                  // 9*256*512 ushorts
  u16* Wp2 = (u16*)(wsp + 655360);       // 9*256*256 ushorts

  float* img1   = A;                     // 4M floats
  float* ctx1   = A + 4194304;           // 4M floats
  u16*   Xt1    = (u16*)(A + 8388608);   // 8.4M u16 NHWC bf16
  float* conv1o = Cr;                    // 16M floats
  float* img2   = Br;                    // 16M floats
  float* ctx2   = A;                     // reuse (all of A dead after conv1)
  u16*   Xt2    = (u16*)Br;              // reuse (img2 dead after attnctx2)
  float* scs    = Cr;                    // reuse (conv1o dead after gbact2)

  // ---- stage 1 ----
  bn_stats_kernel<<<dim3(CIN1), dim3(256), 0, stream>>>(x, mean1, rstd1, CIN1, P1);
  wdn_kernel<<<dim3(NB * LL), dim3(64), 0, stream>>>(wemb, wdn);
  pack_w_kernel<<<dim3(COUT * CIN1 / 256), dim3(256), 0, stream>>>(w_c1, Wp1, COUT, CIN1);
  pack_w_kernel<<<dim3(COUT * COUT / 256), dim3(256), 0, stream>>>(w_c2, Wp2, COUT, COUT);
  gemm_mfma_kernel<<<dim3(P1 / 128, TD / 128, NB), dim3(256), 0, stream>>>(
      w_img1, CIN1, 0, x, nullptr, img1, TD, CIN1, P1);
  attnctx_kernel<<<dim3(P1 / 64, NB), dim3(256), 0, stream>>>(img1, wdn, mask, ctx1, P1);
  gvec_kernel<<<dim3(CIN1 / 64, NB), dim3(64), 0, stream>>>(w_g1, b_g1, gcond, gvec1, CIN1);
  gvec_kernel<<<dim3(CIN1 / 64, NB), dim3(64), 0, stream>>>(w_b1, b_b1, gcond, bvec1, CIN1);
  gbact_kernel<<<dim3(P1 / 128, CIN1 / 128, NB), dim3(256), 0, stream>>>(
      w_g1, w_b1, ctx1, gvec1, bvec1, x, mean1, rstd1, bn1_w, bn1_b, Xt1, CIN1, P1);
  conv_mfma_kernel<CIN1, true><<<dim3(32, 1, NB), dim3(256), 0, stream>>>(
      Wp1, Xt1, nullptr, nullptr, conv1o);

  // ---- stage 2 ----
  bn_stats_kernel<<<dim3(COUT), dim3(256), 0, stream>>>(conv1o, mean2, rstd2, COUT, P2);
  gemm_mfma_kernel<<<dim3(P2 / 128, TD / 128, NB), dim3(256), 0, stream>>>(
      w_img2, COUT, 0, conv1o, nullptr, img2, TD, COUT, P2);
  attnctx_kernel<<<dim3(P2 / 64, NB), dim3(256), 0, stream>>>(img2, wdn, mask, ctx2, P2);
  gvec_kernel<<<dim3(COUT / 64, NB), dim3(64), 0, stream>>>(w_g2, b_g2, gcond, gvec2, COUT);
  gvec_kernel<<<dim3(COUT / 64, NB), dim3(64), 0, stream>>>(w_b2, b_b2, gcond, bvec2, COUT);
  gbact_kernel<<<dim3(P2 / 128, COUT / 128, NB), dim3(256), 0, stream>>>(
      w_g2, w_b2, ctx2, gvec2, bvec2, conv1o, mean2, rstd2, bn2_w, bn2_b, Xt2, COUT, P2);
  gemm_mfma_kernel<<<dim3(P1 / 128, COUT / 128, NB), dim3(256), 0, stream>>>(
      w_sc, CIN1, 0, x, nullptr, scs, COUT, CIN1, P1);
  conv_mfma_kernel<COUT, false><<<dim3(32, 1, NB), dim3(256), 0, stream>>>(
      Wp2, Xt2, scs, b_sc, out);
}

// Round 14
// 501.961 us; speedup vs baseline: 1.3747x; 1.0885x over previous
//
#include <hip/hip_runtime.h>
#include <hip/hip_bf16.h>
#include <math.h>

#define NB 16
#define CIN1 512
#define COUT 256
#define GD 256
#define TD 256
#define LL 32
#define P1 1024
#define P2 4096
#define CONDC 512

typedef __attribute__((ext_vector_type(8))) short bf16x8;
typedef __attribute__((ext_vector_type(4))) float f32x4;
typedef unsigned short u16;

__device__ __forceinline__ u16 f2b(float f) {
  __hip_bfloat16 h = __float2bfloat16(f);
  return *(u16*)&h;
}
__device__ __forceinline__ float b2f(u16 v) {
  unsigned u = ((unsigned)v) << 16;
  float f;
  __builtin_memcpy(&f, &u, 4);
  return f;
}

// ---------------- BN stats: mean + rsqrt(var+eps) per channel ----------------
template <bool BF>
__global__ void bn_stats_kernel(const void* xv, float* __restrict__ mean,
                                float* __restrict__ rstd, int C, int HW) {
  int c = blockIdx.x, t = threadIdx.x;
  float s = 0.f, sq = 0.f;
  for (int b = 0; b < NB; ++b) {
    size_t base = ((size_t)b * C + c) * HW;
    for (int i = t; i < HW; i += 256) {
      float v = BF ? b2f(((const u16*)xv)[base + i]) : ((const float*)xv)[base + i];
      s += v; sq += v * v;
    }
  }
  __shared__ float ss[256], sq2[256];
  ss[t] = s; sq2[t] = sq; __syncthreads();
  for (int o = 128; o > 0; o >>= 1) {
    if (t < o) { ss[t] += ss[t + o]; sq2[t] += sq2[t + o]; }
    __syncthreads();
  }
  if (t == 0) {
    float n = (float)NB * (float)HW;
    float m = ss[0] / n;
    float v = sq2[0] / n - m * m;
    mean[c] = m;
    rstd[c] = rsqrtf(v + 1e-5f);
  }
}

// ---------------- normalize words_embs over channel dim per (b,l) ----------------
__global__ void wdn_kernel(const float* __restrict__ we, float* __restrict__ wdn) {
  int b = blockIdx.x >> 5, l = blockIdx.x & 31;
  int t = threadIdx.x; // 64
  const float* base = we + (size_t)b * TD * LL + l;
  float v[4]; float sq = 0.f;
#pragma unroll
  for (int k = 0; k < 4; ++k) { v[k] = base[(size_t)(t * 4 + k) * LL]; sq += v[k] * v[k]; }
#pragma unroll
  for (int o = 32; o > 0; o >>= 1) sq += __shfl_xor(sq, o);
  float r = 1.f / fmaxf(sqrtf(sq), 1e-12f);
  float* ob = wdn + (size_t)b * TD * LL + l;
#pragma unroll
  for (int k = 0; k < 4; ++k) ob[(size_t)(t * 4 + k) * LL] = v[k] * r;
}

// ---------------- gvec[b,o] = bias[o] + sum_{c<GD} W[o,c]*gc[b,c] ----------------
__global__ void gvec_kernel(const float* __restrict__ Wg, const float* __restrict__ bias,
                            const float* __restrict__ gc, float* __restrict__ outv, int O) {
  int o = blockIdx.x * 64 + threadIdx.x;
  int b = blockIdx.y;
  if (o >= O) return;
  const float* wr = Wg + (size_t)o * CONDC;
  const float* g = gc + (size_t)b * GD;
  float s = 0.f;
  for (int c = 0; c < GD; ++c) s += wr[c] * g[c];
  outv[(size_t)b * O + o] = s + bias[o];
}

// ---------------- fused attention (bf16 img in, bf16 ctx out) ----------------
__global__ __launch_bounds__(256) void attnctx_kernel(
    const u16* __restrict__ img, const float* __restrict__ wdn,
    const int* __restrict__ mask, u16* __restrict__ ctx, int P) {
  __shared__ u16 imgT[64 * 72];
  __shared__ u16 wdnT[32 * 264];
  __shared__ u16 wdnC[256 * 40];
  __shared__ u16 attnB[64 * 40];
  __shared__ float sqP[4][64];
  __shared__ float rnL[64];
  const int b = blockIdx.y, p0 = blockIdx.x * 64;
  const int tid = threadIdx.x;
  const int w = tid >> 6, lane = tid & 63;
  const int l15 = lane & 15, lg = lane >> 4;
  const u16* ib = img + (size_t)b * TD * P;
  const float* wb = wdn + (size_t)b * TD * LL;

  for (int i = tid; i < TD * LL; i += 256) {
    int t = i >> 5, l = i & 31;
    u16 v = f2b(wb[i]);
    wdnT[l * 264 + t] = v;
    wdnC[t * 40 + l] = v;
  }

  f32x4 s0 = {}, s1 = {};
  float ssq = 0.f;
  for (int q = 0; q < 4; ++q) {
#pragma unroll
    for (int i = 0; i < 16; i += 2) {
      int t = q * 64 + w * 16 + i;
      u16 h0 = ib[(size_t)t * P + p0 + lane];
      u16 h1 = ib[(size_t)(t + 1) * P + p0 + lane];
      float v0 = b2f(h0), v1 = b2f(h1);
      ssq += v0 * v0 + v1 * v1;
      unsigned pk = (unsigned)h0 | ((unsigned)h1 << 16);
      *(unsigned*)(imgT + lane * 72 + w * 16 + i) = pk;
    }
    __syncthreads();
#pragma unroll
    for (int ks = 0; ks < 2; ++ks) {
      bf16x8 a = *(const bf16x8*)(imgT + (w * 16 + l15) * 72 + ks * 32 + lg * 8);
      bf16x8 b0 = *(const bf16x8*)(wdnT + l15 * 264 + q * 64 + ks * 32 + lg * 8);
      bf16x8 b1 = *(const bf16x8*)(wdnT + (16 + l15) * 264 + q * 64 + ks * 32 + lg * 8);
      s0 = __builtin_amdgcn_mfma_f32_16x16x32_bf16(a, b0, s0, 0, 0, 0);
      s1 = __builtin_amdgcn_mfma_f32_16x16x32_bf16(a, b1, s1, 0, 0, 0);
    }
    __syncthreads();
  }
  sqP[w][lane] = ssq;
  __syncthreads();
  if (tid < 64) {
    float s = sqP[0][tid] + sqP[1][tid] + sqP[2][tid] + sqP[3][tid];
    rnL[tid] = 1.f / fmaxf(sqrtf(s), 1e-12f);
  }
  __syncthreads();
  const bool m0 = mask[b * LL + l15] != 0;
  const bool m1 = mask[b * LL + 16 + l15] != 0;
#pragma unroll
  for (int k = 0; k < 4; ++k) {
    float rn = rnL[w * 16 + lg * 4 + k];
    float v0 = m0 ? -INFINITY : s0[k] * rn;
    float v1 = m1 ? -INFINITY : s1[k] * rn;
    float mx = fmaxf(v0, v1);
#pragma unroll
    for (int o = 1; o < 16; o <<= 1) mx = fmaxf(mx, __shfl_xor(mx, o));
    float e0 = expf(v0 - mx), e1 = expf(v1 - mx);
    float sm = e0 + e1;
#pragma unroll
    for (int o = 1; o < 16; o <<= 1) sm += __shfl_xor(sm, o);
    float inv = 1.f / sm;
    int px = w * 16 + lg * 4 + k;
    attnB[px * 40 + l15] = f2b(e0 * inv);
    attnB[px * 40 + 16 + l15] = f2b(e1 * inv);
  }
  __syncthreads();
  f32x4 acc[4][4] = {};
  bf16x8 bfr[4];
#pragma unroll
  for (int pt = 0; pt < 4; ++pt)
    bfr[pt] = *(const bf16x8*)(attnB + (pt * 16 + l15) * 40 + lg * 8);
#pragma unroll
  for (int cc = 0; cc < 4; ++cc) {
    bf16x8 a = *(const bf16x8*)(wdnC + ((w * 4 + cc) * 16 + l15) * 40 + lg * 8);
#pragma unroll
    for (int pt = 0; pt < 4; ++pt)
      acc[cc][pt] = __builtin_amdgcn_mfma_f32_16x16x32_bf16(a, bfr[pt], acc[cc][pt], 0, 0, 0);
  }
#pragma unroll
  for (int cc = 0; cc < 4; ++cc) {
#pragma unroll
    for (int pt = 0; pt < 4; ++pt) {
#pragma unroll
      for (int k = 0; k < 4; ++k) {
        int c = (w * 4 + cc) * 16 + lg * 4 + k;
        ctx[((size_t)b * TD + c) * P + p0 + pt * 16 + l15] = f2b(acc[cc][pt][k]);
      }
    }
  }
}

// ---------------- bf16 MFMA GEMM, dbuf reg-staged; X fp32/bf16, Y fp32/bf16 ----------------
template <bool XB, bool YB>
__global__ __launch_bounds__(256, 2) void gemm_mfma_kernel(
    const float* __restrict__ W, int ldw, int c_off,
    const void* __restrict__ Xv, const float* __restrict__ vec,
    void* __restrict__ Yv, int T, int C, int P) {
  __shared__ u16 Wl[2][128 * 44];
  __shared__ u16 Xl[2][128 * 40];
  const int b = blockIdx.z;
  const int t0 = blockIdx.y * 128, p0 = blockIdx.x * 128;
  const int tid = threadIdx.x;
  const int w = tid >> 6, lane = tid & 63;
  const int wo = w >> 1, wq = w & 1;
  const int l15 = lane & 15, lg = lane >> 4;
  const int wr = tid >> 1, wcH = tid & 1;
  const int xr = tid >> 3, xcG = tid & 7;
  const int csw = xr ^ ((xcG & 3) << 3);
  const float* wsrc = W + (size_t)(t0 + wr) * ldw + c_off + wcH * 16;
  const float* xsrc32 = XB ? nullptr : (const float*)Xv + (size_t)b * C * P + (size_t)xr * P + p0 + xcG * 16;
  const u16* xsrc16 = XB ? (const u16*)Xv + (size_t)b * C * P + (size_t)xr * P + p0 + xcG * 16 : nullptr;
  const int NK = C / 32;
  f32x4 acc[4][4] = {};
  float4 wreg[4];
  u16 xst[16];

  // prologue
#pragma unroll
  for (int j = 0; j < 4; ++j) wreg[j] = *(const float4*)(wsrc + j * 4);
  if (XB) {
    union { u16 u[16]; uint4 q[2]; } xu;
    xu.q[0] = *(const uint4*)(xsrc16);
    xu.q[1] = *(const uint4*)(xsrc16 + 8);
#pragma unroll
    for (int i = 0; i < 16; ++i) xst[i] = xu.u[i];
  } else {
#pragma unroll
    for (int j = 0; j < 4; ++j) {
      float4 v = *(const float4*)(xsrc32 + j * 4);
      xst[j * 4 + 0] = f2b(v.x); xst[j * 4 + 1] = f2b(v.y);
      xst[j * 4 + 2] = f2b(v.z); xst[j * 4 + 3] = f2b(v.w);
    }
  }
  {
    u16* dst = Wl[0] + wr * 44 + wcH * 16;
#pragma unroll
    for (int j = 0; j < 4; ++j)
      *(ushort4*)(dst + j * 4) = make_ushort4(f2b(wreg[j].x), f2b(wreg[j].y), f2b(wreg[j].z), f2b(wreg[j].w));
#pragma unroll
    for (int i = 0; i < 16; ++i)
      Xl[0][(xcG * 16 + i) * 40 + csw] = xst[i];
  }
  __syncthreads();

  for (int kb = 0; kb < NK; ++kb) {
    const int cur = kb & 1;
    if (kb + 1 < NK) {
      const int c0n = (kb + 1) * 32;
#pragma unroll
      for (int j = 0; j < 4; ++j) wreg[j] = *(const float4*)(wsrc + c0n + j * 4);
      if (XB) {
        union { u16 u[16]; uint4 q[2]; } xu;
        xu.q[0] = *(const uint4*)(xsrc16 + (size_t)c0n * P);
        xu.q[1] = *(const uint4*)(xsrc16 + (size_t)c0n * P + 8);
#pragma unroll
        for (int i = 0; i < 16; ++i) xst[i] = xu.u[i];
      } else {
#pragma unroll
        for (int j = 0; j < 4; ++j) {
          float4 v = *(const float4*)(xsrc32 + (size_t)c0n * P + j * 4);
          xst[j * 4 + 0] = f2b(v.x); xst[j * 4 + 1] = f2b(v.y);
          xst[j * 4 + 2] = f2b(v.z); xst[j * 4 + 3] = f2b(v.w);
        }
      }
    }
    bf16x8 a[4], bb[4];
#pragma unroll
    for (int rr = 0; rr < 4; ++rr)
      a[rr] = *(const bf16x8*)(Wl[cur] + (wo * 64 + rr * 16 + l15) * 44 + lg * 8);
#pragma unroll
    for (int ss = 0; ss < 4; ++ss)
      bb[ss] = *(const bf16x8*)(Xl[cur] + (wq * 64 + ss * 16 + l15) * 40 + ((lg ^ ss) << 3));
#pragma unroll
    for (int rr = 0; rr < 4; ++rr)
#pragma unroll
      for (int ss = 0; ss < 4; ++ss)
        acc[rr][ss] = __builtin_amdgcn_mfma_f32_16x16x32_bf16(a[rr], bb[ss], acc[rr][ss], 0, 0, 0);
    if (kb + 1 < NK) {
      const int nxt = cur ^ 1;
      u16* dst = Wl[nxt] + wr * 44 + wcH * 16;
#pragma unroll
      for (int j = 0; j < 4; ++j)
        *(ushort4*)(dst + j * 4) = make_ushort4(f2b(wreg[j].x), f2b(wreg[j].y), f2b(wreg[j].z), f2b(wreg[j].w));
#pragma unroll
      for (int i = 0; i < 16; ++i)
        Xl[nxt][(xcG * 16 + i) * 40 + csw] = xst[i];
      __syncthreads();
    }
  }
#pragma unroll
  for (int rr = 0; rr < 4; ++rr) {
    int tb = t0 + wo * 64 + rr * 16 + lg * 4;
#pragma unroll
    for (int ss = 0; ss < 4; ++ss) {
      int p = p0 + wq * 64 + ss * 16 + l15;
#pragma unroll
      for (int k = 0; k < 4; ++k) {
        int t = tb + k;
        float val = acc[rr][ss][k];
        if (vec) val += vec[(size_t)b * T + t];
        if (YB) ((u16*)Yv)[((size_t)b * T + t) * P + p] = f2b(val);
        else    ((float*)Yv)[((size_t)b * T + t) * P + p] = val;
      }
    }
  }
}

// ---------------- fused gamma/beta GEMM + BN + ReLU + NHWC pack (bf16 ctx in) ----------------
template <bool XINB>
__global__ __launch_bounds__(256, 2) void gbact_kernel(
    const float* __restrict__ Wg, const float* __restrict__ Wb,
    const u16* __restrict__ ctx, const float* __restrict__ gvec,
    const float* __restrict__ bvec, const void* __restrict__ xinv,
    const float* __restrict__ mean, const float* __restrict__ rstd,
    const float* __restrict__ bnw, const float* __restrict__ bnb,
    u16* __restrict__ outb, int C, int P) {
  __shared__ u16 shmem[2][16384];
  const int b = blockIdx.z, t0 = blockIdx.y * 128, p0 = blockIdx.x * 128;
  const int tid = threadIdx.x;
  const int w = tid >> 6, lane = tid & 63;
  const int wo = w >> 1, wq = w & 1;
  const int l15 = lane & 15, lg = lane >> 4;
  const int wr = tid >> 1, wcH = tid & 1;
  const int xr = tid >> 3, xcG = tid & 7;
  const int csw = xr ^ ((xcG & 3) << 3);
  const float* gsrc = Wg + (size_t)(t0 + wr) * CONDC + GD + wcH * 16;
  const float* bsrc = Wb + (size_t)(t0 + wr) * CONDC + GD + wcH * 16;
  const u16* xsrc = ctx + (size_t)b * TD * P + (size_t)xr * P + p0 + xcG * 16;
  const int NK = TD / 32;
  f32x4 accg[4][4] = {}, accb[4][4] = {};
  float4 greg[4], breg[4];
  u16 xst[16];

#pragma unroll
  for (int j = 0; j < 4; ++j) {
    greg[j] = *(const float4*)(gsrc + j * 4);
    breg[j] = *(const float4*)(bsrc + j * 4);
  }
  {
    union { u16 u[16]; uint4 q[2]; } xu;
    xu.q[0] = *(const uint4*)(xsrc);
    xu.q[1] = *(const uint4*)(xsrc + 8);
#pragma unroll
    for (int i = 0; i < 16; ++i) xst[i] = xu.u[i];
  }
  {
    u16* dg = shmem[0] + wr * 44 + wcH * 16;
    u16* db = shmem[0] + 5632 + wr * 44 + wcH * 16;
    u16* xl = shmem[0] + 11264;
#pragma unroll
    for (int j = 0; j < 4; ++j) {
      *(ushort4*)(dg + j * 4) = make_ushort4(f2b(greg[j].x), f2b(greg[j].y), f2b(greg[j].z), f2b(greg[j].w));
      *(ushort4*)(db + j * 4) = make_ushort4(f2b(breg[j].x), f2b(breg[j].y), f2b(breg[j].z), f2b(breg[j].w));
    }
#pragma unroll
    for (int i = 0; i < 16; ++i)
      xl[(xcG * 16 + i) * 40 + csw] = xst[i];
  }
  __syncthreads();

  for (int kb = 0; kb < NK; ++kb) {
    const int cur = kb & 1;
    if (kb + 1 < NK) {
      const int c0n = (kb + 1) * 32;
#pragma unroll
      for (int j = 0; j < 4; ++j) {
        greg[j] = *(const float4*)(gsrc + c0n + j * 4);
        breg[j] = *(const float4*)(bsrc + c0n + j * 4);
      }
      union { u16 u[16]; uint4 q[2]; } xu;
      xu.q[0] = *(const uint4*)(xsrc + (size_t)c0n * P);
      xu.q[1] = *(const uint4*)(xsrc + (size_t)c0n * P + 8);
#pragma unroll
      for (int i = 0; i < 16; ++i) xst[i] = xu.u[i];
    }
    bf16x8 ag[4], ab[4], bb[4];
#pragma unroll
    for (int rr = 0; rr < 4; ++rr) {
      ag[rr] = *(const bf16x8*)(shmem[cur] + (wo * 64 + rr * 16 + l15) * 44 + lg * 8);
      ab[rr] = *(const bf16x8*)(shmem[cur] + 5632 + (wo * 64 + rr * 16 + l15) * 44 + lg * 8);
    }
#pragma unroll
    for (int ss = 0; ss < 4; ++ss)
      bb[ss] = *(const bf16x8*)(shmem[cur] + 11264 + (wq * 64 + ss * 16 + l15) * 40 + ((lg ^ ss) << 3));
#pragma unroll
    for (int rr = 0; rr < 4; ++rr)
#pragma unroll
      for (int ss = 0; ss < 4; ++ss) {
        accg[rr][ss] = __builtin_amdgcn_mfma_f32_16x16x32_bf16(ag[rr], bb[ss], accg[rr][ss], 0, 0, 0);
        accb[rr][ss] = __builtin_amdgcn_mfma_f32_16x16x32_bf16(ab[rr], bb[ss], accb[rr][ss], 0, 0, 0);
      }
    if (kb + 1 < NK) {
      const int nxt = cur ^ 1;
      u16* dg = shmem[nxt] + wr * 44 + wcH * 16;
      u16* db = shmem[nxt] + 5632 + wr * 44 + wcH * 16;
      u16* xl = shmem[nxt] + 11264;
#pragma unroll
      for (int j = 0; j < 4; ++j) {
        *(ushort4*)(dg + j * 4) = make_ushort4(f2b(greg[j].x), f2b(greg[j].y), f2b(greg[j].z), f2b(greg[j].w));
        *(ushort4*)(db + j * 4) = make_ushort4(f2b(breg[j].x), f2b(breg[j].y), f2b(breg[j].z), f2b(breg[j].w));
      }
#pragma unroll
      for (int i = 0; i < 16; ++i)
        xl[(xcG * 16 + i) * 40 + csw] = xst[i];
      __syncthreads();
    }
  }
  __syncthreads();
  u16* tbuf = &shmem[0][0];
#pragma unroll
  for (int rr = 0; rr < 4; ++rr) {
    float gv[4], bv[4], mm[4], rs[4], bB[4];
#pragma unroll
    for (int k = 0; k < 4; ++k) {
      int c = t0 + wo * 64 + rr * 16 + lg * 4 + k;
      gv[k] = gvec[(size_t)b * C + c];
      bv[k] = bvec[(size_t)b * C + c];
      mm[k] = mean[c]; rs[k] = rstd[c] * bnw[c]; bB[k] = bnb[c];
    }
#pragma unroll
    for (int ss = 0; ss < 4; ++ss) {
#pragma unroll
      for (int k = 0; k < 4; ++k) {
        int cl = wo * 64 + rr * 16 + lg * 4 + k;
        int pl = wq * 64 + ss * 16 + l15;
        size_t xidx = ((size_t)b * C + t0 + cl) * P + p0 + pl;
        float xv = XINB ? b2f(((const u16*)xinv)[xidx]) : ((const float*)xinv)[xidx];
        float g = accg[rr][ss][k] + gv[k];
        float be = accb[rr][ss][k] + bv[k];
        float val = fmaxf(g * ((xv - mm[k]) * rs[k] + bB[k]) + be, 0.f);
        tbuf[pl * 136 + cl] = f2b(val);
      }
    }
  }
  __syncthreads();
  const int pr = tid >> 1, h = tid & 1;
#pragma unroll
  for (int j = 0; j < 8; ++j) {
    uint4 v = *(uint4*)(tbuf + pr * 136 + h * 64 + j * 8);
    *(uint4*)(outb + ((size_t)b * P + p0 + pr) * C + t0 + h * 64 + j * 8) = v;
  }
}

// ---------------- pack conv weights: fragment-linear bf16 ----------------
__global__ void pack_w_kernel(const float* __restrict__ w, u16* __restrict__ wp, int O, int CIN) {
  int lin = blockIdx.x * 256 + threadIdx.x;
  if (lin >= O * CIN) return;
  int o = lin / CIN, c = lin - o * CIN;
  int c0blk = c >> 5, lg = (c >> 3) & 3, cc = c & 7;
  int ot = o >> 4, l15 = o & 15;
  int lane = lg * 16 + l15;
  size_t base = (((size_t)c0blk * (O >> 4) + ot) * 64 + lane) * 8 + cc;
  size_t posStride = (size_t)(CIN >> 5) * (O >> 4) * 512;
  const float* src = w + (size_t)lin * 9;
#pragma unroll
  for (int pos = 0; pos < 9; ++pos)
    wp[pos * posStride + base] = f2b(src[pos]);
}

// ---------------- bf16 MFMA implicit-GEMM 3x3 conv ----------------
template <int CIN, bool UP, bool OUTB>
__global__ __launch_bounds__(256, 2) void conv_mfma_kernel(
    const u16* __restrict__ Wp, const u16* __restrict__ Xt,
    const float* __restrict__ scs, const float* __restrict__ scb,
    void* __restrict__ Yv) {
  constexpr int S = UP ? 32 : 64;
  constexpr int NC0 = CIN >> 5;
  __shared__ u16 Xs[2][4 * 66 * 36];
  const int b = blockIdx.z, pxT = blockIdx.x;
  const int tid = threadIdx.x;
  const int w = tid >> 6, lane = tid & 63;
  const int wo = w >> 1, wp_ = w & 1;
  const int l15 = lane & 15, lg = lane >> 4;
  const int Y0 = pxT * 2;
  const u16* Xb = Xt + (size_t)b * S * S * CIN;
  const size_t posStride = (size_t)NC0 * 16 * 512;
  f32x4 acc[8][4] = {};
  uint2 st[9];

#pragma unroll
  for (int j = 0; j < 9; ++j) {
    int i = tid + j * 256;
    if (i < 2112) {
      int r = i / 528, rem = i - r * 528, col = rem >> 3, ch = rem & 7;
      int uy = Y0 - 1 + r, ux = col - 1;
      uint2 v = make_uint2(0u, 0u);
      if (uy >= 0 && uy < 64 && ux >= 0 && ux < 64) {
        int sy = UP ? (uy >> 1) : uy, sx = UP ? (ux >> 1) : ux;
        v = *(const uint2*)(Xb + ((size_t)sy * S + sx) * CIN + ch * 4);
      }
      st[j] = v;
    }
  }
#pragma unroll
  for (int j = 0; j < 9; ++j) {
    int i = tid + j * 256;
    if (i < 2112) {
      int r = i / 528, rem = i - r * 528, col = rem >> 3, ch = rem & 7;
      *(uint2*)(&Xs[0][(r * 66 + col) * 36 + ch * 4]) = st[j];
    }
  }
  __syncthreads();

  for (int c0b = 0; c0b < NC0; ++c0b) {
    const int cur = c0b & 1;
    if (c0b + 1 < NC0) {
      const int c0n = (c0b + 1) << 5;
#pragma unroll
      for (int j = 0; j < 9; ++j) {
        int i = tid + j * 256;
        if (i < 2112) {
          int r = i / 528, rem = i - r * 528, col = rem >> 3, ch = rem & 7;
          int uy = Y0 - 1 + r, ux = col - 1;
          uint2 v = make_uint2(0u, 0u);
          if (uy >= 0 && uy < 64 && ux >= 0 && ux < 64) {
            int sy = UP ? (uy >> 1) : uy, sx = UP ? (ux >> 1) : ux;
            v = *(const uint2*)(Xb + ((size_t)sy * S + sx) * CIN + c0n + ch * 4);
          }
          st[j] = v;
        }
      }
    }
    {
      const u16* wbB = Wp + ((size_t)c0b * 16 + wo * 8) * 512 + lane * 8;
      bf16x8 aC[8], aN[8];
#pragma unroll
      for (int rr = 0; rr < 8; ++rr)
        aC[rr] = *(const bf16x8*)(wbB + rr * 512);
#pragma unroll
      for (int pos = 0; pos < 9; ++pos) {
        const int ky = pos / 3, kx = pos - ky * 3;
        if (pos < 8) {
          const u16* wbn = wbB + (size_t)(pos + 1) * posStride;
#pragma unroll
          for (int rr = 0; rr < 8; ++rr)
            aN[rr] = *(const bf16x8*)(wbn + rr * 512);
        }
        const int rowb = ((wp_ + ky) * 66 + kx) * 36 + lg * 8;
#pragma unroll
        for (int ss = 0; ss < 4; ++ss) {
          int idx = rowb + (ss * 16 + l15) * 36;
          union { uint2 q[2]; bf16x8 v; } u;
          u.q[0] = *(const uint2*)(&Xs[cur][idx]);
          u.q[1] = *(const uint2*)(&Xs[cur][idx + 4]);
#pragma unroll
          for (int rr = 0; rr < 8; ++rr)
            acc[rr][ss] = __builtin_amdgcn_mfma_f32_16x16x32_bf16(aC[rr], u.v, acc[rr][ss], 0, 0, 0);
        }
#pragma unroll
        for (int rr = 0; rr < 8; ++rr) aC[rr] = aN[rr];
      }
    }
    if (c0b + 1 < NC0) {
#pragma unroll
      for (int j = 0; j < 9; ++j) {
        int i = tid + j * 256;
        if (i < 2112) {
          int r = i / 528, rem = i - r * 528, col = rem >> 3, ch = rem & 7;
          *(uint2*)(&Xs[cur ^ 1][(r * 66 + col) * 36 + ch * 4]) = st[j];
        }
      }
      __syncthreads();
    }
  }
  const int oBase = wo * 128 + lg * 4;
  const int pxBase = pxT * 128 + wp_ * 64 + l15;
#pragma unroll
  for (int rr = 0; rr < 8; ++rr) {
#pragma unroll
    for (int ss = 0; ss < 4; ++ss) {
      int px = pxBase + ss * 16;
#pragma unroll
      for (int k = 0; k < 4; ++k) {
        int o = oBase + rr * 16 + k;
        float val = acc[rr][ss][k];
        if (scs) {
          int gx = px & 63;
          val += scs[((size_t)b * COUT + o) * P1 + pxT * 32 + (gx >> 1)] + scb[o];
        }
        if (OUTB) ((u16*)Yv)[((size_t)b * COUT + o) * 4096 + px] = f2b(val);
        else      ((float*)Yv)[((size_t)b * COUT + o) * 4096 + px] = val;
      }
    }
  }
}

extern "C" void kernel_launch(void* const* d_in, const int* in_sizes, int n_in,
                              void* d_out, int out_size, void* d_ws, size_t ws_size,
                              hipStream_t stream) {
  const float* x      = (const float*)d_in[0];
  const float* gcond  = (const float*)d_in[1];
  const float* wemb   = (const float*)d_in[2];
  const int*   mask   = (const int*)d_in[3];
  const float* w_img1 = (const float*)d_in[4];
  const float* w_img2 = (const float*)d_in[5];
  const float* w_c1   = (const float*)d_in[6];
  const float* w_c2   = (const float*)d_in[7];
  const float* bn1_w  = (const float*)d_in[8];
  const float* bn1_b  = (const float*)d_in[9];
  const float* bn2_w  = (const float*)d_in[10];
  const float* bn2_b  = (const float*)d_in[11];
  const float* w_g1   = (const float*)d_in[12];
  const float* b_g1   = (const float*)d_in[13];
  const float* w_b1   = (const float*)d_in[14];
  const float* b_b1   = (const float*)d_in[15];
  const float* w_g2   = (const float*)d_in[16];
  const float* b_g2   = (const float*)d_in[17];
  const float* w_b2   = (const float*)d_in[18];
  const float* b_b2   = (const float*)d_in[19];
  const float* w_sc   = (const float*)d_in[20];
  const float* b_sc   = (const float*)d_in[21];
  float* out = (float*)d_out;
  float* ws = (float*)d_ws;

  const size_t MF = 16777216;  // floats per 64MB region
  float* A  = ws;
  float* Br = ws + MF;
  float* Cr = ws + 2 * MF;
  float* SM = ws + 3 * MF;
  float* wdn   = SM;                     // 131072
  float* mean1 = SM + 131072;
  float* rstd1 = mean1 + 512;
  float* mean2 = rstd1 + 512;
  float* rstd2 = mean2 + 256;
  float* gvec1 = rstd2 + 256;            // 8192
  float* bvec1 = gvec1 + 8192;
  float* gvec2 = bvec1 + 8192;           // 4096
  float* bvec2 = gvec2 + 4096;
  float* wsp   = bvec2 + 4096;
  u16* Wp1 = (u16*)wsp;                  // 9*256*512 ushorts
  u16* Wp2 = (u16*)(wsp + 655360);       // 9*256*256 ushorts

  u16* img1   = (u16*)A;                 // 4.2M u16
  u16* ctx1   = (u16*)A + 4194304;       // 4.2M u16
  u16* Xt1    = (u16*)A + 8388608;       // 8.4M u16 NHWC bf16
  u16* conv1o = (u16*)Cr;                // 16.8M u16 NCHW bf16
  u16* img2   = (u16*)Br;                // 16.8M u16
  u16* ctx2   = (u16*)A;                 // reuse (A dead after conv1)
  u16* Xt2    = (u16*)Br;                // reuse (img2 dead after attnctx2)
  float* scs  = Cr;                      // reuse (conv1o dead after gbact2)

  // ---- stage 1 ----
  bn_stats_kernel<false><<<dim3(CIN1), dim3(256), 0, stream>>>(x, mean1, rstd1, CIN1, P1);
  wdn_kernel<<<dim3(NB * LL), dim3(64), 0, stream>>>(wemb, wdn);
  pack_w_kernel<<<dim3(COUT * CIN1 / 256), dim3(256), 0, stream>>>(w_c1, Wp1, COUT, CIN1);
  pack_w_kernel<<<dim3(COUT * COUT / 256), dim3(256), 0, stream>>>(w_c2, Wp2, COUT, COUT);
  gemm_mfma_kernel<false, true><<<dim3(P1 / 128, TD / 128, NB), dim3(256), 0, stream>>>(
      w_img1, CIN1, 0, x, nullptr, img1, TD, CIN1, P1);
  attnctx_kernel<<<dim3(P1 / 64, NB), dim3(256), 0, stream>>>(img1, wdn, mask, ctx1, P1);
  gvec_kernel<<<dim3(CIN1 / 64, NB), dim3(64), 0, stream>>>(w_g1, b_g1, gcond, gvec1, CIN1);
  gvec_kernel<<<dim3(CIN1 / 64, NB), dim3(64), 0, stream>>>(w_b1, b_b1, gcond, bvec1, CIN1);
  gbact_kernel<false><<<dim3(P1 / 128, CIN1 / 128, NB), dim3(256), 0, stream>>>(
      w_g1, w_b1, ctx1, gvec1, bvec1, x, mean1, rstd1, bn1_w, bn1_b, Xt1, CIN1, P1);
  conv_mfma_kernel<CIN1, true, true><<<dim3(32, 1, NB), dim3(256), 0, stream>>>(
      Wp1, Xt1, nullptr, nullptr, conv1o);

  // ---- stage 2 ----
  bn_stats_kernel<true><<<dim3(COUT), dim3(256), 0, stream>>>(conv1o, mean2, rstd2, COUT, P2);
  gemm_mfma_kernel<true, true><<<dim3(P2 / 128, TD / 128, NB), dim3(256), 0, stream>>>(
      w_img2, COUT, 0, conv1o, nullptr, img2, TD, COUT, P2);
  attnctx_kernel<<<dim3(P2 / 64, NB), dim3(256), 0, stream>>>(img2, wdn, mask, ctx2, P2);
  gvec_kernel<<<dim3(COUT / 64, NB), dim3(64), 0, stream>>>(w_g2, b_g2, gcond, gvec2, COUT);
  gvec_kernel<<<dim3(COUT / 64, NB), dim3(64), 0, stream>>>(w_b2, b_b2, gcond, bvec2, COUT);
  gbact_kernel<true><<<dim3(P2 / 128, COUT / 128, NB), dim3(256), 0, stream>>>(
      w_g2, w_b2, ctx2, gvec2, bvec2, conv1o, mean2, rstd2, bn2_w, bn2_b, Xt2, COUT, P2);
  gemm_mfma_kernel<false, false><<<dim3(P1 / 128, COUT / 128, NB), dim3(256), 0, stream>>>(
      w_sc, CIN1, 0, x, nullptr, scs, COUT, CIN1, P1);
  conv_mfma_kernel<COUT, false, false><<<dim3(32, 1, NB), dim3(256), 0, stream>>>(
      Wp2, Xt2, scs, b_sc, out);
}

// Round 15
// 495.148 us; speedup vs baseline: 1.3936x; 1.0138x over previous
//
#include <hip/hip_runtime.h>
#include <hip/hip_bf16.h>
#include <math.h>

#define NB 16
#define CIN1 512
#define COUT 256
#define GD 256
#define TD 256
#define LL 32
#define P1 1024
#define P2 4096
#define CONDC 512

typedef __attribute__((ext_vector_type(8))) short bf16x8;
typedef __attribute__((ext_vector_type(4))) float f32x4;
typedef unsigned short u16;

__device__ __forceinline__ u16 f2b(float f) {
  __hip_bfloat16 h = __float2bfloat16(f);
  return *(u16*)&h;
}
__device__ __forceinline__ float b2f(u16 v) {
  unsigned u = ((unsigned)v) << 16;
  float f;
  __builtin_memcpy(&f, &u, 4);
  return f;
}

// ---------------- BN stats: mean + rsqrt(var+eps) per channel ----------------
template <bool BF>
__global__ void bn_stats_kernel(const void* xv, float* __restrict__ mean,
                                float* __restrict__ rstd, int C, int HW) {
  int c = blockIdx.x, t = threadIdx.x;
  float s = 0.f, sq = 0.f;
  for (int b = 0; b < NB; ++b) {
    size_t base = ((size_t)b * C + c) * HW;
    for (int i = t; i < HW; i += 256) {
      float v = BF ? b2f(((const u16*)xv)[base + i]) : ((const float*)xv)[base + i];
      s += v; sq += v * v;
    }
  }
  __shared__ float ss[256], sq2[256];
  ss[t] = s; sq2[t] = sq; __syncthreads();
  for (int o = 128; o > 0; o >>= 1) {
    if (t < o) { ss[t] += ss[t + o]; sq2[t] += sq2[t + o]; }
    __syncthreads();
  }
  if (t == 0) {
    float n = (float)NB * (float)HW;
    float m = ss[0] / n;
    float v = sq2[0] / n - m * m;
    mean[c] = m;
    rstd[c] = rsqrtf(v + 1e-5f);
  }
}

// ---------------- normalize words_embs over channel dim per (b,l) ----------------
__global__ void wdn_kernel(const float* __restrict__ we, float* __restrict__ wdn) {
  int b = blockIdx.x >> 5, l = blockIdx.x & 31;
  int t = threadIdx.x; // 64
  const float* base = we + (size_t)b * TD * LL + l;
  float v[4]; float sq = 0.f;
#pragma unroll
  for (int k = 0; k < 4; ++k) { v[k] = base[(size_t)(t * 4 + k) * LL]; sq += v[k] * v[k]; }
#pragma unroll
  for (int o = 32; o > 0; o >>= 1) sq += __shfl_xor(sq, o);
  float r = 1.f / fmaxf(sqrtf(sq), 1e-12f);
  float* ob = wdn + (size_t)b * TD * LL + l;
#pragma unroll
  for (int k = 0; k < 4; ++k) ob[(size_t)(t * 4 + k) * LL] = v[k] * r;
}

// ---------------- gvec[b,o] = bias[o] + sum_{c<GD} W[o,c]*gc[b,c] ----------------
__global__ void gvec_kernel(const float* __restrict__ Wg, const float* __restrict__ bias,
                            const float* __restrict__ gc, float* __restrict__ outv, int O) {
  int o = blockIdx.x * 64 + threadIdx.x;
  int b = blockIdx.y;
  if (o >= O) return;
  const float* wr = Wg + (size_t)o * CONDC;
  const float* g = gc + (size_t)b * GD;
  float s = 0.f;
  for (int c = 0; c < GD; ++c) s += wr[c] * g[c];
  outv[(size_t)b * O + o] = s + bias[o];
}

// ---------------- fused attention (bf16 img in, bf16 ctx out) ----------------
__global__ __launch_bounds__(256) void attnctx_kernel(
    const u16* __restrict__ img, const float* __restrict__ wdn,
    const int* __restrict__ mask, u16* __restrict__ ctx, int P) {
  __shared__ u16 imgT[64 * 72];
  __shared__ u16 wdnT[32 * 264];
  __shared__ u16 wdnC[256 * 40];
  __shared__ u16 attnB[64 * 40];
  __shared__ float sqP[4][64];
  __shared__ float rnL[64];
  const int b = blockIdx.y, p0 = blockIdx.x * 64;
  const int tid = threadIdx.x;
  const int w = tid >> 6, lane = tid & 63;
  const int l15 = lane & 15, lg = lane >> 4;
  const u16* ib = img + (size_t)b * TD * P;
  const float* wb = wdn + (size_t)b * TD * LL;

  for (int i = tid; i < TD * LL; i += 256) {
    int t = i >> 5, l = i & 31;
    u16 v = f2b(wb[i]);
    wdnT[l * 264 + t] = v;
    wdnC[t * 40 + l] = v;
  }

  f32x4 s0 = {}, s1 = {};
  float ssq = 0.f;
  for (int q = 0; q < 4; ++q) {
#pragma unroll
    for (int i = 0; i < 16; i += 2) {
      int t = q * 64 + w * 16 + i;
      u16 h0 = ib[(size_t)t * P + p0 + lane];
      u16 h1 = ib[(size_t)(t + 1) * P + p0 + lane];
      float v0 = b2f(h0), v1 = b2f(h1);
      ssq += v0 * v0 + v1 * v1;
      unsigned pk = (unsigned)h0 | ((unsigned)h1 << 16);
      *(unsigned*)(imgT + lane * 72 + w * 16 + i) = pk;
    }
    __syncthreads();
#pragma unroll
    for (int ks = 0; ks < 2; ++ks) {
      bf16x8 a = *(const bf16x8*)(imgT + (w * 16 + l15) * 72 + ks * 32 + lg * 8);
      bf16x8 b0 = *(const bf16x8*)(wdnT + l15 * 264 + q * 64 + ks * 32 + lg * 8);
      bf16x8 b1 = *(const bf16x8*)(wdnT + (16 + l15) * 264 + q * 64 + ks * 32 + lg * 8);
      s0 = __builtin_amdgcn_mfma_f32_16x16x32_bf16(a, b0, s0, 0, 0, 0);
      s1 = __builtin_amdgcn_mfma_f32_16x16x32_bf16(a, b1, s1, 0, 0, 0);
    }
    __syncthreads();
  }
  sqP[w][lane] = ssq;
  __syncthreads();
  if (tid < 64) {
    float s = sqP[0][tid] + sqP[1][tid] + sqP[2][tid] + sqP[3][tid];
    rnL[tid] = 1.f / fmaxf(sqrtf(s), 1e-12f);
  }
  __syncthreads();
  const bool m0 = mask[b * LL + l15] != 0;
  const bool m1 = mask[b * LL + 16 + l15] != 0;
#pragma unroll
  for (int k = 0; k < 4; ++k) {
    float rn = rnL[w * 16 + lg * 4 + k];
    float v0 = m0 ? -INFINITY : s0[k] * rn;
    float v1 = m1 ? -INFINITY : s1[k] * rn;
    float mx = fmaxf(v0, v1);
#pragma unroll
    for (int o = 1; o < 16; o <<= 1) mx = fmaxf(mx, __shfl_xor(mx, o));
    float e0 = expf(v0 - mx), e1 = expf(v1 - mx);
    float sm = e0 + e1;
#pragma unroll
    for (int o = 1; o < 16; o <<= 1) sm += __shfl_xor(sm, o);
    float inv = 1.f / sm;
    int px = w * 16 + lg * 4 + k;
    attnB[px * 40 + l15] = f2b(e0 * inv);
    attnB[px * 40 + 16 + l15] = f2b(e1 * inv);
  }
  __syncthreads();
  f32x4 acc[4][4] = {};
  bf16x8 bfr[4];
#pragma unroll
  for (int pt = 0; pt < 4; ++pt)
    bfr[pt] = *(const bf16x8*)(attnB + (pt * 16 + l15) * 40 + lg * 8);
#pragma unroll
  for (int cc = 0; cc < 4; ++cc) {
    bf16x8 a = *(const bf16x8*)(wdnC + ((w * 4 + cc) * 16 + l15) * 40 + lg * 8);
#pragma unroll
    for (int pt = 0; pt < 4; ++pt)
      acc[cc][pt] = __builtin_amdgcn_mfma_f32_16x16x32_bf16(a, bfr[pt], acc[cc][pt], 0, 0, 0);
  }
#pragma unroll
  for (int cc = 0; cc < 4; ++cc) {
#pragma unroll
    for (int pt = 0; pt < 4; ++pt) {
#pragma unroll
      for (int k = 0; k < 4; ++k) {
        int c = (w * 4 + cc) * 16 + lg * 4 + k;
        ctx[((size_t)b * TD + c) * P + p0 + pt * 16 + l15] = f2b(acc[cc][pt][k]);
      }
    }
  }
}

// ---------------- bf16 MFMA GEMM, dbuf reg-staged; X fp32/bf16, Y fp32/bf16 ----------------
template <bool XB, bool YB>
__global__ __launch_bounds__(256, 2) void gemm_mfma_kernel(
    const float* __restrict__ W, int ldw, int c_off,
    const void* __restrict__ Xv, const float* __restrict__ vec,
    void* __restrict__ Yv, int T, int C, int P) {
  __shared__ u16 Wl[2][128 * 44];
  __shared__ u16 Xl[2][128 * 40];
  const int b = blockIdx.z;
  const int t0 = blockIdx.y * 128, p0 = blockIdx.x * 128;
  const int tid = threadIdx.x;
  const int w = tid >> 6, lane = tid & 63;
  const int wo = w >> 1, wq = w & 1;
  const int l15 = lane & 15, lg = lane >> 4;
  const int wr = tid >> 1, wcH = tid & 1;
  const int xr = tid >> 3, xcG = tid & 7;
  const int csw = xr ^ ((xcG & 3) << 3);
  const float* wsrc = W + (size_t)(t0 + wr) * ldw + c_off + wcH * 16;
  const float* xsrc32 = XB ? nullptr : (const float*)Xv + (size_t)b * C * P + (size_t)xr * P + p0 + xcG * 16;
  const u16* xsrc16 = XB ? (const u16*)Xv + (size_t)b * C * P + (size_t)xr * P + p0 + xcG * 16 : nullptr;
  const int NK = C / 32;
  f32x4 acc[4][4] = {};
  float4 wreg[4];
  u16 xst[16];

  // prologue
#pragma unroll
  for (int j = 0; j < 4; ++j) wreg[j] = *(const float4*)(wsrc + j * 4);
  if (XB) {
    union { u16 u[16]; uint4 q[2]; } xu;
    xu.q[0] = *(const uint4*)(xsrc16);
    xu.q[1] = *(const uint4*)(xsrc16 + 8);
#pragma unroll
    for (int i = 0; i < 16; ++i) xst[i] = xu.u[i];
  } else {
#pragma unroll
    for (int j = 0; j < 4; ++j) {
      float4 v = *(const float4*)(xsrc32 + j * 4);
      xst[j * 4 + 0] = f2b(v.x); xst[j * 4 + 1] = f2b(v.y);
      xst[j * 4 + 2] = f2b(v.z); xst[j * 4 + 3] = f2b(v.w);
    }
  }
  {
    u16* dst = Wl[0] + wr * 44 + wcH * 16;
#pragma unroll
    for (int j = 0; j < 4; ++j)
      *(ushort4*)(dst + j * 4) = make_ushort4(f2b(wreg[j].x), f2b(wreg[j].y), f2b(wreg[j].z), f2b(wreg[j].w));
#pragma unroll
    for (int i = 0; i < 16; ++i)
      Xl[0][(xcG * 16 + i) * 40 + csw] = xst[i];
  }
  __syncthreads();

  for (int kb = 0; kb < NK; ++kb) {
    const int cur = kb & 1;
    if (kb + 1 < NK) {
      const int c0n = (kb + 1) * 32;
#pragma unroll
      for (int j = 0; j < 4; ++j) wreg[j] = *(const float4*)(wsrc + c0n + j * 4);
      if (XB) {
        union { u16 u[16]; uint4 q[2]; } xu;
        xu.q[0] = *(const uint4*)(xsrc16 + (size_t)c0n * P);
        xu.q[1] = *(const uint4*)(xsrc16 + (size_t)c0n * P + 8);
#pragma unroll
        for (int i = 0; i < 16; ++i) xst[i] = xu.u[i];
      } else {
#pragma unroll
        for (int j = 0; j < 4; ++j) {
          float4 v = *(const float4*)(xsrc32 + (size_t)c0n * P + j * 4);
          xst[j * 4 + 0] = f2b(v.x); xst[j * 4 + 1] = f2b(v.y);
          xst[j * 4 + 2] = f2b(v.z); xst[j * 4 + 3] = f2b(v.w);
        }
      }
    }
    bf16x8 a[4], bb[4];
#pragma unroll
    for (int rr = 0; rr < 4; ++rr)
      a[rr] = *(const bf16x8*)(Wl[cur] + (wo * 64 + rr * 16 + l15) * 44 + lg * 8);
#pragma unroll
    for (int ss = 0; ss < 4; ++ss)
      bb[ss] = *(const bf16x8*)(Xl[cur] + (wq * 64 + ss * 16 + l15) * 40 + ((lg ^ ss) << 3));
#pragma unroll
    for (int rr = 0; rr < 4; ++rr)
#pragma unroll
      for (int ss = 0; ss < 4; ++ss)
        acc[rr][ss] = __builtin_amdgcn_mfma_f32_16x16x32_bf16(a[rr], bb[ss], acc[rr][ss], 0, 0, 0);
    if (kb + 1 < NK) {
      const int nxt = cur ^ 1;
      u16* dst = Wl[nxt] + wr * 44 + wcH * 16;
#pragma unroll
      for (int j = 0; j < 4; ++j)
        *(ushort4*)(dst + j * 4) = make_ushort4(f2b(wreg[j].x), f2b(wreg[j].y), f2b(wreg[j].z), f2b(wreg[j].w));
#pragma unroll
      for (int i = 0; i < 16; ++i)
        Xl[nxt][(xcG * 16 + i) * 40 + csw] = xst[i];
      __syncthreads();
    }
  }
#pragma unroll
  for (int rr = 0; rr < 4; ++rr) {
    int tb = t0 + wo * 64 + rr * 16 + lg * 4;
#pragma unroll
    for (int ss = 0; ss < 4; ++ss) {
      int p = p0 + wq * 64 + ss * 16 + l15;
#pragma unroll
      for (int k = 0; k < 4; ++k) {
        int t = tb + k;
        float val = acc[rr][ss][k];
        if (vec) val += vec[(size_t)b * T + t];
        if (YB) ((u16*)Yv)[((size_t)b * T + t) * P + p] = f2b(val);
        else    ((float*)Yv)[((size_t)b * T + t) * P + p] = val;
      }
    }
  }
}

// ---------------- fused gamma/beta GEMM + BN + ReLU + NHWC pack (bf16 ctx in) ----------------
template <bool XINB>
__global__ __launch_bounds__(256, 2) void gbact_kernel(
    const float* __restrict__ Wg, const float* __restrict__ Wb,
    const u16* __restrict__ ctx, const float* __restrict__ gvec,
    const float* __restrict__ bvec, const void* __restrict__ xinv,
    const float* __restrict__ mean, const float* __restrict__ rstd,
    const float* __restrict__ bnw, const float* __restrict__ bnb,
    u16* __restrict__ outb, int C, int P) {
  __shared__ u16 shmem[2][16384];
  const int b = blockIdx.z, t0 = blockIdx.y * 128, p0 = blockIdx.x * 128;
  const int tid = threadIdx.x;
  const int w = tid >> 6, lane = tid & 63;
  const int wo = w >> 1, wq = w & 1;
  const int l15 = lane & 15, lg = lane >> 4;
  const int wr = tid >> 1, wcH = tid & 1;
  const int xr = tid >> 3, xcG = tid & 7;
  const int csw = xr ^ ((xcG & 3) << 3);
  const float* gsrc = Wg + (size_t)(t0 + wr) * CONDC + GD + wcH * 16;
  const float* bsrc = Wb + (size_t)(t0 + wr) * CONDC + GD + wcH * 16;
  const u16* xsrc = ctx + (size_t)b * TD * P + (size_t)xr * P + p0 + xcG * 16;
  const int NK = TD / 32;
  f32x4 accg[4][4] = {}, accb[4][4] = {};
  float4 greg[4], breg[4];
  u16 xst[16];

#pragma unroll
  for (int j = 0; j < 4; ++j) {
    greg[j] = *(const float4*)(gsrc + j * 4);
    breg[j] = *(const float4*)(bsrc + j * 4);
  }
  {
    union { u16 u[16]; uint4 q[2]; } xu;
    xu.q[0] = *(const uint4*)(xsrc);
    xu.q[1] = *(const uint4*)(xsrc + 8);
#pragma unroll
    for (int i = 0; i < 16; ++i) xst[i] = xu.u[i];
  }
  {
    u16* dg = shmem[0] + wr * 44 + wcH * 16;
    u16* db = shmem[0] + 5632 + wr * 44 + wcH * 16;
    u16* xl = shmem[0] + 11264;
#pragma unroll
    for (int j = 0; j < 4; ++j) {
      *(ushort4*)(dg + j * 4) = make_ushort4(f2b(greg[j].x), f2b(greg[j].y), f2b(greg[j].z), f2b(greg[j].w));
      *(ushort4*)(db + j * 4) = make_ushort4(f2b(breg[j].x), f2b(breg[j].y), f2b(breg[j].z), f2b(breg[j].w));
    }
#pragma unroll
    for (int i = 0; i < 16; ++i)
      xl[(xcG * 16 + i) * 40 + csw] = xst[i];
  }
  __syncthreads();

  for (int kb = 0; kb < NK; ++kb) {
    const int cur = kb & 1;
    if (kb + 1 < NK) {
      const int c0n = (kb + 1) * 32;
#pragma unroll
      for (int j = 0; j < 4; ++j) {
        greg[j] = *(const float4*)(gsrc + c0n + j * 4);
        breg[j] = *(const float4*)(bsrc + c0n + j * 4);
      }
      union { u16 u[16]; uint4 q[2]; } xu;
      xu.q[0] = *(const uint4*)(xsrc + (size_t)c0n * P);
      xu.q[1] = *(const uint4*)(xsrc + (size_t)c0n * P + 8);
#pragma unroll
      for (int i = 0; i < 16; ++i) xst[i] = xu.u[i];
    }
    bf16x8 ag[4], ab[4], bb[4];
#pragma unroll
    for (int rr = 0; rr < 4; ++rr) {
      ag[rr] = *(const bf16x8*)(shmem[cur] + (wo * 64 + rr * 16 + l15) * 44 + lg * 8);
      ab[rr] = *(const bf16x8*)(shmem[cur] + 5632 + (wo * 64 + rr * 16 + l15) * 44 + lg * 8);
    }
#pragma unroll
    for (int ss = 0; ss < 4; ++ss)
      bb[ss] = *(const bf16x8*)(shmem[cur] + 11264 + (wq * 64 + ss * 16 + l15) * 40 + ((lg ^ ss) << 3));
#pragma unroll
    for (int rr = 0; rr < 4; ++rr)
#pragma unroll
      for (int ss = 0; ss < 4; ++ss) {
        accg[rr][ss] = __builtin_amdgcn_mfma_f32_16x16x32_bf16(ag[rr], bb[ss], accg[rr][ss], 0, 0, 0);
        accb[rr][ss] = __builtin_amdgcn_mfma_f32_16x16x32_bf16(ab[rr], bb[ss], accb[rr][ss], 0, 0, 0);
      }
    if (kb + 1 < NK) {
      const int nxt = cur ^ 1;
      u16* dg = shmem[nxt] + wr * 44 + wcH * 16;
      u16* db = shmem[nxt] + 5632 + wr * 44 + wcH * 16;
      u16* xl = shmem[nxt] + 11264;
#pragma unroll
      for (int j = 0; j < 4; ++j) {
        *(ushort4*)(dg + j * 4) = make_ushort4(f2b(greg[j].x), f2b(greg[j].y), f2b(greg[j].z), f2b(greg[j].w));
        *(ushort4*)(db + j * 4) = make_ushort4(f2b(breg[j].x), f2b(breg[j].y), f2b(breg[j].z), f2b(breg[j].w));
      }
#pragma unroll
      for (int i = 0; i < 16; ++i)
        xl[(xcG * 16 + i) * 40 + csw] = xst[i];
      __syncthreads();
    }
  }
  __syncthreads();
  u16* tbuf = &shmem[0][0];
#pragma unroll
  for (int rr = 0; rr < 4; ++rr) {
    float gv[4], bv[4], mm[4], rs[4], bB[4];
#pragma unroll
    for (int k = 0; k < 4; ++k) {
      int c = t0 + wo * 64 + rr * 16 + lg * 4 + k;
      gv[k] = gvec[(size_t)b * C + c];
      bv[k] = bvec[(size_t)b * C + c];
      mm[k] = mean[c]; rs[k] = rstd[c] * bnw[c]; bB[k] = bnb[c];
    }
#pragma unroll
    for (int ss = 0; ss < 4; ++ss) {
#pragma unroll
      for (int k = 0; k < 4; ++k) {
        int cl = wo * 64 + rr * 16 + lg * 4 + k;
        int pl = wq * 64 + ss * 16 + l15;
        size_t xidx = ((size_t)b * C + t0 + cl) * P + p0 + pl;
        float xv = XINB ? b2f(((const u16*)xinv)[xidx]) : ((const float*)xinv)[xidx];
        float g = accg[rr][ss][k] + gv[k];
        float be = accb[rr][ss][k] + bv[k];
        float val = fmaxf(g * ((xv - mm[k]) * rs[k] + bB[k]) + be, 0.f);
        tbuf[pl * 136 + cl] = f2b(val);
      }
    }
  }
  __syncthreads();
  const int pr = tid >> 1, h = tid & 1;
#pragma unroll
  for (int j = 0; j < 8; ++j) {
    uint4 v = *(uint4*)(tbuf + pr * 136 + h * 64 + j * 8);
    *(uint4*)(outb + ((size_t)b * P + p0 + pr) * C + t0 + h * 64 + j * 8) = v;
  }
}

// ---------------- pack conv weights: fragment-linear bf16 ----------------
__global__ void pack_w_kernel(const float* __restrict__ w, u16* __restrict__ wp, int O, int CIN) {
  int lin = blockIdx.x * 256 + threadIdx.x;
  if (lin >= O * CIN) return;
  int o = lin / CIN, c = lin - o * CIN;
  int c0blk = c >> 5, lg = (c >> 3) & 3, cc = c & 7;
  int ot = o >> 4, l15 = o & 15;
  int lane = lg * 16 + l15;
  size_t base = (((size_t)c0blk * (O >> 4) + ot) * 64 + lane) * 8 + cc;
  size_t posStride = (size_t)(CIN >> 5) * (O >> 4) * 512;
  const float* src = w + (size_t)lin * 9;
#pragma unroll
  for (int pos = 0; pos < 9; ++pos)
    wp[pos * posStride + base] = f2b(src[pos]);
}

// ---------------- bf16 MFMA implicit-GEMM 3x3 conv ----------------
// Block: 8 waves (512 thr) = 256o x 256px (4 output rows); wave tile 128o x 64px.
// Halves per-wave A-fragment L2 traffic vs 4-wave block (A chunk shared by 8 waves, L1-resident).
// Xs stride 36 u16: conflict-free b64 reads. Window 6 rows x 66 cols x 32c, dbuf 57KB.
template <int CIN, bool UP, bool OUTB>
__global__ __launch_bounds__(512, 2) void conv_mfma_kernel(
    const u16* __restrict__ Wp, const u16* __restrict__ Xt,
    const float* __restrict__ scs, const float* __restrict__ scb,
    void* __restrict__ Yv) {
  constexpr int S = UP ? 32 : 64;
  constexpr int NC0 = CIN >> 5;
  constexpr int NCH = 6 * 66 * 8;  // 3168 uint2 chunks per tile
  __shared__ u16 Xs[2][6 * 66 * 36];  // double buffer, 28512 B each
  const int b = blockIdx.z, pxT = blockIdx.x;
  const int tid = threadIdx.x;
  const int w = tid >> 6, lane = tid & 63;
  const int wo = w >> 2, wp_ = w & 3;
  const int l15 = lane & 15, lg = lane >> 4;
  const int Y0 = pxT * 4;
  const u16* Xb = Xt + (size_t)b * S * S * CIN;
  const size_t posStride = (size_t)NC0 * 16 * 512;
  f32x4 acc[8][4] = {};
  uint2 st[7];

  // prologue: load + write tile 0
#pragma unroll
  for (int j = 0; j < 7; ++j) {
    int i = tid + j * 512;
    if (i < NCH) {
      int r = i / 528, rem = i - r * 528, col = rem >> 3, ch = rem & 7;
      int uy = Y0 - 1 + r, ux = col - 1;
      uint2 v = make_uint2(0u, 0u);
      if (uy >= 0 && uy < 64 && ux >= 0 && ux < 64) {
        int sy = UP ? (uy >> 1) : uy, sx = UP ? (ux >> 1) : ux;
        v = *(const uint2*)(Xb + ((size_t)sy * S + sx) * CIN + ch * 4);
      }
      st[j] = v;
    }
  }
#pragma unroll
  for (int j = 0; j < 7; ++j) {
    int i = tid + j * 512;
    if (i < NCH) {
      int r = i / 528, rem = i - r * 528, col = rem >> 3, ch = rem & 7;
      *(uint2*)(&Xs[0][(r * 66 + col) * 36 + ch * 4]) = st[j];
    }
  }
  __syncthreads();

  for (int c0b = 0; c0b < NC0; ++c0b) {
    const int cur = c0b & 1;
    // early-issue loads for next tile (land during compute)
    if (c0b + 1 < NC0) {
      const int c0n = (c0b + 1) << 5;
#pragma unroll
      for (int j = 0; j < 7; ++j) {
        int i = tid + j * 512;
        if (i < NCH) {
          int r = i / 528, rem = i - r * 528, col = rem >> 3, ch = rem & 7;
          int uy = Y0 - 1 + r, ux = col - 1;
          uint2 v = make_uint2(0u, 0u);
          if (uy >= 0 && uy < 64 && ux >= 0 && ux < 64) {
            int sy = UP ? (uy >> 1) : uy, sx = UP ? (ux >> 1) : ux;
            v = *(const uint2*)(Xb + ((size_t)sy * S + sx) * CIN + c0n + ch * 4);
          }
          st[j] = v;
        }
      }
    }
    // compute: A-fragments (8 rr = 128 o) software-pipelined across pos
    {
      const u16* wbB = Wp + ((size_t)c0b * 16 + wo * 8) * 512 + lane * 8;
      bf16x8 aC[8], aN[8];
#pragma unroll
      for (int rr = 0; rr < 8; ++rr)
        aC[rr] = *(const bf16x8*)(wbB + rr * 512);
#pragma unroll
      for (int pos = 0; pos < 9; ++pos) {
        const int ky = pos / 3, kx = pos - ky * 3;
        if (pos < 8) {
          const u16* wbn = wbB + (size_t)(pos + 1) * posStride;
#pragma unroll
          for (int rr = 0; rr < 8; ++rr)
            aN[rr] = *(const bf16x8*)(wbn + rr * 512);
        }
        const int rowb = ((wp_ + ky) * 66 + kx) * 36 + lg * 8;
#pragma unroll
        for (int ss = 0; ss < 4; ++ss) {
          int idx = rowb + (ss * 16 + l15) * 36;
          union { uint2 q[2]; bf16x8 v; } u;
          u.q[0] = *(const uint2*)(&Xs[cur][idx]);
          u.q[1] = *(const uint2*)(&Xs[cur][idx + 4]);
#pragma unroll
          for (int rr = 0; rr < 8; ++rr)
            acc[rr][ss] = __builtin_amdgcn_mfma_f32_16x16x32_bf16(aC[rr], u.v, acc[rr][ss], 0, 0, 0);
        }
#pragma unroll
        for (int rr = 0; rr < 8; ++rr) aC[rr] = aN[rr];
      }
    }
    // write next tile into the other buffer; single barrier per iter
    if (c0b + 1 < NC0) {
#pragma unroll
      for (int j = 0; j < 7; ++j) {
        int i = tid + j * 512;
        if (i < NCH) {
          int r = i / 528, rem = i - r * 528, col = rem >> 3, ch = rem & 7;
          *(uint2*)(&Xs[cur ^ 1][(r * 66 + col) * 36 + ch * 4]) = st[j];
        }
      }
      __syncthreads();
    }
  }
  const int oBase = wo * 128 + lg * 4;
  const int pxBase = pxT * 256 + wp_ * 64 + l15;
  const int y = Y0 + wp_;
#pragma unroll
  for (int rr = 0; rr < 8; ++rr) {
#pragma unroll
    for (int ss = 0; ss < 4; ++ss) {
      int px = pxBase + ss * 16;
#pragma unroll
      for (int k = 0; k < 4; ++k) {
        int o = oBase + rr * 16 + k;
        float val = acc[rr][ss][k];
        if (scs) {
          int gx = px & 63;
          val += scs[((size_t)b * COUT + o) * P1 + (y >> 1) * 32 + (gx >> 1)] + scb[o];
        }
        if (OUTB) ((u16*)Yv)[((size_t)b * COUT + o) * 4096 + px] = f2b(val);
        else      ((float*)Yv)[((size_t)b * COUT + o) * 4096 + px] = val;
      }
    }
  }
}

extern "C" void kernel_launch(void* const* d_in, const int* in_sizes, int n_in,
                              void* d_out, int out_size, void* d_ws, size_t ws_size,
                              hipStream_t stream) {
  const float* x      = (const float*)d_in[0];
  const float* gcond  = (const float*)d_in[1];
  const float* wemb   = (const float*)d_in[2];
  const int*   mask   = (const int*)d_in[3];
  const float* w_img1 = (const float*)d_in[4];
  const float* w_img2 = (const float*)d_in[5];
  const float* w_c1   = (const float*)d_in[6];
  const float* w_c2   = (const float*)d_in[7];
  const float* bn1_w  = (const float*)d_in[8];
  const float* bn1_b  = (const float*)d_in[9];
  const float* bn2_w  = (const float*)d_in[10];
  const float* bn2_b  = (const float*)d_in[11];
  const float* w_g1   = (const float*)d_in[12];
  const float* b_g1   = (const float*)d_in[13];
  const float* w_b1   = (const float*)d_in[14];
  const float* b_b1   = (const float*)d_in[15];
  const float* w_g2   = (const float*)d_in[16];
  const float* b_g2   = (const float*)d_in[17];
  const float* w_b2   = (const float*)d_in[18];
  const float* b_b2   = (const float*)d_in[19];
  const float* w_sc   = (const float*)d_in[20];
  const float* b_sc   = (const float*)d_in[21];
  float* out = (float*)d_out;
  float* ws = (float*)d_ws;

  const size_t MF = 16777216;  // floats per 64MB region
  float* A  = ws;
  float* Br = ws + MF;
  float* Cr = ws + 2 * MF;
  float* SM = ws + 3 * MF;
  float* wdn   = SM;                     // 131072
  float* mean1 = SM + 131072;
  float* rstd1 = mean1 + 512;
  float* mean2 = rstd1 + 512;
  float* rstd2 = mean2 + 256;
  float* gvec1 = rstd2 + 256;            // 8192
  float* bvec1 = gvec1 + 8192;
  float* gvec2 = bvec1 + 8192;           // 4096
  float* bvec2 = gvec2 + 4096;
  float* wsp   = bvec2 + 4096;
  u16* Wp1 = (u16*)wsp;                  // 9*256*512 ushorts
  u16* Wp2 = (u16*)(wsp + 655360);       // 9*256*256 ushorts

  u16* img1   = (u16*)A;                 // 4.2M u16
  u16* ctx1   = (u16*)A + 4194304;       // 4.2M u16
  u16* Xt1    = (u16*)A + 8388608;       // 8.4M u16 NHWC bf16
  u16* conv1o = (u16*)Cr;                // 16.8M u16 NCHW bf16
  u16* img2   = (u16*)Br;                // 16.8M u16
  u16* ctx2   = (u16*)A;                 // reuse (A dead after conv1)
  u16* Xt2    = (u16*)Br;                // reuse (img2 dead after attnctx2)
  float* scs  = Cr;                      // reuse (conv1o dead after gbact2)

  // ---- stage 1 ----
  bn_stats_kernel<false><<<dim3(CIN1), dim3(256), 0, stream>>>(x, mean1, rstd1, CIN1, P1);
  wdn_kernel<<<dim3(NB * LL), dim3(64), 0, stream>>>(wemb, wdn);
  pack_w_kernel<<<dim3(COUT * CIN1 / 256), dim3(256), 0, stream>>>(w_c1, Wp1, COUT, CIN1);
  pack_w_kernel<<<dim3(COUT * COUT / 256), dim3(256), 0, stream>>>(w_c2, Wp2, COUT, COUT);
  gemm_mfma_kernel<false, true><<<dim3(P1 / 128, TD / 128, NB), dim3(256), 0, stream>>>(
      w_img1, CIN1, 0, x, nullptr, img1, TD, CIN1, P1);
  attnctx_kernel<<<dim3(P1 / 64, NB), dim3(256), 0, stream>>>(img1, wdn, mask, ctx1, P1);
  gvec_kernel<<<dim3(CIN1 / 64, NB), dim3(64), 0, stream>>>(w_g1, b_g1, gcond, gvec1, CIN1);
  gvec_kernel<<<dim3(CIN1 / 64, NB), dim3(64), 0, stream>>>(w_b1, b_b1, gcond, bvec1, CIN1);
  gbact_kernel<false><<<dim3(P1 / 128, CIN1 / 128, NB), dim3(256), 0, stream>>>(
      w_g1, w_b1, ctx1, gvec1, bvec1, x, mean1, rstd1, bn1_w, bn1_b, Xt1, CIN1, P1);
  conv_mfma_kernel<CIN1, true, true><<<dim3(16, 1, NB), dim3(512), 0, stream>>>(
      Wp1, Xt1, nullptr, nullptr, conv1o);

  // ---- stage 2 ----
  bn_stats_kernel<true><<<dim3(COUT), dim3(256), 0, stream>>>(conv1o, mean2, rstd2, COUT, P2);
  gemm_mfma_kernel<true, true><<<dim3(P2 / 128, TD / 128, NB), dim3(256), 0, stream>>>(
      w_img2, COUT, 0, conv1o, nullptr, img2, TD, COUT, P2);
  attnctx_kernel<<<dim3(P2 / 64, NB), dim3(256), 0, stream>>>(img2, wdn, mask, ctx2, P2);
  gvec_kernel<<<dim3(COUT / 64, NB), dim3(64), 0, stream>>>(w_g2, b_g2, gcond, gvec2, COUT);
  gvec_kernel<<<dim3(COUT / 64, NB), dim3(64), 0, stream>>>(w_b2, b_b2, gcond, bvec2, COUT);
  gbact_kernel<true><<<dim3(P2 / 128, COUT / 128, NB), dim3(256), 0, stream>>>(
      w_g2, w_b2, ctx2, gvec2, bvec2, conv1o, mean2, rstd2, bn2_w, bn2_b, Xt2, COUT, P2);
  gemm_mfma_kernel<false, false><<<dim3(P1 / 128, COUT / 128, NB), dim3(256), 0, stream>>>(
      w_sc, CIN1, 0, x, nullptr, scs, COUT, CIN1, P1);
  conv_mfma_kernel<COUT, false, false><<<dim3(16, 1, NB), dim3(512), 0, stream>>>(
      Wp2, Xt2, scs, b_sc, out);
}

// Round 16
// 469.960 us; speedup vs baseline: 1.4683x; 1.0536x over previous
//
#include <hip/hip_runtime.h>
#include <hip/hip_bf16.h>
#include <math.h>

#define NB 16
#define CIN1 512
#define COUT 256
#define GD 256
#define TD 256
#define LL 32
#define P1 1024
#define P2 4096
#define CONDC 512

typedef __attribute__((ext_vector_type(8))) short bf16x8;
typedef __attribute__((ext_vector_type(4))) float f32x4;
typedef unsigned short u16;

__device__ __forceinline__ u16 f2b(float f) {
  __hip_bfloat16 h = __float2bfloat16(f);
  return *(u16*)&h;
}
__device__ __forceinline__ float b2f(u16 v) {
  unsigned u = ((unsigned)v) << 16;
  float f;
  __builtin_memcpy(&f, &u, 4);
  return f;
}

// ---------------- BN stats (stage 1 only): mean + rsqrt(var+eps) per channel ----------------
template <bool BF>
__global__ void bn_stats_kernel(const void* xv, float* __restrict__ mean,
                                float* __restrict__ rstd, int C, int HW) {
  int c = blockIdx.x, t = threadIdx.x;
  float s = 0.f, sq = 0.f;
  for (int b = 0; b < NB; ++b) {
    size_t base = ((size_t)b * C + c) * HW;
    for (int i = t; i < HW; i += 256) {
      float v = BF ? b2f(((const u16*)xv)[base + i]) : ((const float*)xv)[base + i];
      s += v; sq += v * v;
    }
  }
  __shared__ float ss[256], sq2[256];
  ss[t] = s; sq2[t] = sq; __syncthreads();
  for (int o = 128; o > 0; o >>= 1) {
    if (t < o) { ss[t] += ss[t + o]; sq2[t] += sq2[t + o]; }
    __syncthreads();
  }
  if (t == 0) {
    float n = (float)NB * (float)HW;
    float m = ss[0] / n;
    float v = sq2[0] / n - m * m;
    mean[c] = m;
    rstd[c] = rsqrtf(v + 1e-5f);
  }
}

// ---------------- finalize conv1-fused BN2 stats from per-block partials ----------------
__global__ void bn_fin_kernel(const float* __restrict__ part, float* __restrict__ mean,
                              float* __restrict__ rstd) {
  int c = threadIdx.x;  // 256
  float s = 0.f, sq = 0.f;
  const float* ps = part + (size_t)c * 256;
  const float* pq = part + 65536 + (size_t)c * 256;
  for (int i = 0; i < 256; ++i) { s += ps[i]; sq += pq[i]; }
  float n = 16.f * 4096.f;
  float m = s / n;
  mean[c] = m;
  rstd[c] = rsqrtf(sq / n - m * m + 1e-5f);
}

// ---------------- normalize words_embs over channel dim per (b,l) ----------------
__global__ void wdn_kernel(const float* __restrict__ we, float* __restrict__ wdn) {
  int b = blockIdx.x >> 5, l = blockIdx.x & 31;
  int t = threadIdx.x; // 64
  const float* base = we + (size_t)b * TD * LL + l;
  float v[4]; float sq = 0.f;
#pragma unroll
  for (int k = 0; k < 4; ++k) { v[k] = base[(size_t)(t * 4 + k) * LL]; sq += v[k] * v[k]; }
#pragma unroll
  for (int o = 32; o > 0; o >>= 1) sq += __shfl_xor(sq, o);
  float r = 1.f / fmaxf(sqrtf(sq), 1e-12f);
  float* ob = wdn + (size_t)b * TD * LL + l;
#pragma unroll
  for (int k = 0; k < 4; ++k) ob[(size_t)(t * 4 + k) * LL] = v[k] * r;
}

// ---------------- fused attention (bf16 img in, bf16 ctx out) ----------------
__global__ __launch_bounds__(256) void attnctx_kernel(
    const u16* __restrict__ img, const float* __restrict__ wdn,
    const int* __restrict__ mask, u16* __restrict__ ctx, int P) {
  __shared__ u16 imgT[64 * 72];
  __shared__ u16 wdnT[32 * 264];
  __shared__ u16 wdnC[256 * 40];
  __shared__ u16 attnB[64 * 40];
  __shared__ float sqP[4][64];
  __shared__ float rnL[64];
  const int b = blockIdx.y, p0 = blockIdx.x * 64;
  const int tid = threadIdx.x;
  const int w = tid >> 6, lane = tid & 63;
  const int l15 = lane & 15, lg = lane >> 4;
  const u16* ib = img + (size_t)b * TD * P;
  const float* wb = wdn + (size_t)b * TD * LL;

  for (int i = tid; i < TD * LL; i += 256) {
    int t = i >> 5, l = i & 31;
    u16 v = f2b(wb[i]);
    wdnT[l * 264 + t] = v;
    wdnC[t * 40 + l] = v;
  }

  f32x4 s0 = {}, s1 = {};
  float ssq = 0.f;
  for (int q = 0; q < 4; ++q) {
#pragma unroll
    for (int i = 0; i < 16; i += 2) {
      int t = q * 64 + w * 16 + i;
      u16 h0 = ib[(size_t)t * P + p0 + lane];
      u16 h1 = ib[(size_t)(t + 1) * P + p0 + lane];
      float v0 = b2f(h0), v1 = b2f(h1);
      ssq += v0 * v0 + v1 * v1;
      unsigned pk = (unsigned)h0 | ((unsigned)h1 << 16);
      *(unsigned*)(imgT + lane * 72 + w * 16 + i) = pk;
    }
    __syncthreads();
#pragma unroll
    for (int ks = 0; ks < 2; ++ks) {
      bf16x8 a = *(const bf16x8*)(imgT + (w * 16 + l15) * 72 + ks * 32 + lg * 8);
      bf16x8 b0 = *(const bf16x8*)(wdnT + l15 * 264 + q * 64 + ks * 32 + lg * 8);
      bf16x8 b1 = *(const bf16x8*)(wdnT + (16 + l15) * 264 + q * 64 + ks * 32 + lg * 8);
      s0 = __builtin_amdgcn_mfma_f32_16x16x32_bf16(a, b0, s0, 0, 0, 0);
      s1 = __builtin_amdgcn_mfma_f32_16x16x32_bf16(a, b1, s1, 0, 0, 0);
    }
    __syncthreads();
  }
  sqP[w][lane] = ssq;
  __syncthreads();
  if (tid < 64) {
    float s = sqP[0][tid] + sqP[1][tid] + sqP[2][tid] + sqP[3][tid];
    rnL[tid] = 1.f / fmaxf(sqrtf(s), 1e-12f);
  }
  __syncthreads();
  const bool m0 = mask[b * LL + l15] != 0;
  const bool m1 = mask[b * LL + 16 + l15] != 0;
#pragma unroll
  for (int k = 0; k < 4; ++k) {
    float rn = rnL[w * 16 + lg * 4 + k];
    float v0 = m0 ? -INFINITY : s0[k] * rn;
    float v1 = m1 ? -INFINITY : s1[k] * rn;
    float mx = fmaxf(v0, v1);
#pragma unroll
    for (int o = 1; o < 16; o <<= 1) mx = fmaxf(mx, __shfl_xor(mx, o));
    float e0 = expf(v0 - mx), e1 = expf(v1 - mx);
    float sm = e0 + e1;
#pragma unroll
    for (int o = 1; o < 16; o <<= 1) sm += __shfl_xor(sm, o);
    float inv = 1.f / sm;
    int px = w * 16 + lg * 4 + k;
    attnB[px * 40 + l15] = f2b(e0 * inv);
    attnB[px * 40 + 16 + l15] = f2b(e1 * inv);
  }
  __syncthreads();
  f32x4 acc[4][4] = {};
  bf16x8 bfr[4];
#pragma unroll
  for (int pt = 0; pt < 4; ++pt)
    bfr[pt] = *(const bf16x8*)(attnB + (pt * 16 + l15) * 40 + lg * 8);
#pragma unroll
  for (int cc = 0; cc < 4; ++cc) {
    bf16x8 a = *(const bf16x8*)(wdnC + ((w * 4 + cc) * 16 + l15) * 40 + lg * 8);
#pragma unroll
    for (int pt = 0; pt < 4; ++pt)
      acc[cc][pt] = __builtin_amdgcn_mfma_f32_16x16x32_bf16(a, bfr[pt], acc[cc][pt], 0, 0, 0);
  }
#pragma unroll
  for (int cc = 0; cc < 4; ++cc) {
#pragma unroll
    for (int pt = 0; pt < 4; ++pt) {
#pragma unroll
      for (int k = 0; k < 4; ++k) {
        int c = (w * 4 + cc) * 16 + lg * 4 + k;
        ctx[((size_t)b * TD + c) * P + p0 + pt * 16 + l15] = f2b(acc[cc][pt][k]);
      }
    }
  }
}

// ---------------- bf16 MFMA GEMM, dbuf reg-staged; X fp32/bf16, Y fp32/bf16 ----------------
template <bool XB, bool YB>
__global__ __launch_bounds__(256, 2) void gemm_mfma_kernel(
    const float* __restrict__ W, int ldw, int c_off,
    const void* __restrict__ Xv, const float* __restrict__ vec,
    void* __restrict__ Yv, int T, int C, int P) {
  __shared__ u16 Wl[2][128 * 44];
  __shared__ u16 Xl[2][128 * 40];
  const int b = blockIdx.z;
  const int t0 = blockIdx.y * 128, p0 = blockIdx.x * 128;
  const int tid = threadIdx.x;
  const int w = tid >> 6, lane = tid & 63;
  const int wo = w >> 1, wq = w & 1;
  const int l15 = lane & 15, lg = lane >> 4;
  const int wr = tid >> 1, wcH = tid & 1;
  const int xr = tid >> 3, xcG = tid & 7;
  const int csw = xr ^ ((xcG & 3) << 3);
  const float* wsrc = W + (size_t)(t0 + wr) * ldw + c_off + wcH * 16;
  const float* xsrc32 = XB ? nullptr : (const float*)Xv + (size_t)b * C * P + (size_t)xr * P + p0 + xcG * 16;
  const u16* xsrc16 = XB ? (const u16*)Xv + (size_t)b * C * P + (size_t)xr * P + p0 + xcG * 16 : nullptr;
  const int NK = C / 32;
  f32x4 acc[4][4] = {};
  float4 wreg[4];
  u16 xst[16];

#pragma unroll
  for (int j = 0; j < 4; ++j) wreg[j] = *(const float4*)(wsrc + j * 4);
  if (XB) {
    union { u16 u[16]; uint4 q[2]; } xu;
    xu.q[0] = *(const uint4*)(xsrc16);
    xu.q[1] = *(const uint4*)(xsrc16 + 8);
#pragma unroll
    for (int i = 0; i < 16; ++i) xst[i] = xu.u[i];
  } else {
#pragma unroll
    for (int j = 0; j < 4; ++j) {
      float4 v = *(const float4*)(xsrc32 + j * 4);
      xst[j * 4 + 0] = f2b(v.x); xst[j * 4 + 1] = f2b(v.y);
      xst[j * 4 + 2] = f2b(v.z); xst[j * 4 + 3] = f2b(v.w);
    }
  }
  {
    u16* dst = Wl[0] + wr * 44 + wcH * 16;
#pragma unroll
    for (int j = 0; j < 4; ++j)
      *(ushort4*)(dst + j * 4) = make_ushort4(f2b(wreg[j].x), f2b(wreg[j].y), f2b(wreg[j].z), f2b(wreg[j].w));
#pragma unroll
    for (int i = 0; i < 16; ++i)
      Xl[0][(xcG * 16 + i) * 40 + csw] = xst[i];
  }
  __syncthreads();

  for (int kb = 0; kb < NK; ++kb) {
    const int cur = kb & 1;
    if (kb + 1 < NK) {
      const int c0n = (kb + 1) * 32;
#pragma unroll
      for (int j = 0; j < 4; ++j) wreg[j] = *(const float4*)(wsrc + c0n + j * 4);
      if (XB) {
        union { u16 u[16]; uint4 q[2]; } xu;
        xu.q[0] = *(const uint4*)(xsrc16 + (size_t)c0n * P);
        xu.q[1] = *(const uint4*)(xsrc16 + (size_t)c0n * P + 8);
#pragma unroll
        for (int i = 0; i < 16; ++i) xst[i] = xu.u[i];
      } else {
#pragma unroll
        for (int j = 0; j < 4; ++j) {
          float4 v = *(const float4*)(xsrc32 + (size_t)c0n * P + j * 4);
          xst[j * 4 + 0] = f2b(v.x); xst[j * 4 + 1] = f2b(v.y);
          xst[j * 4 + 2] = f2b(v.z); xst[j * 4 + 3] = f2b(v.w);
        }
      }
    }
    bf16x8 a[4], bb[4];
#pragma unroll
    for (int rr = 0; rr < 4; ++rr)
      a[rr] = *(const bf16x8*)(Wl[cur] + (wo * 64 + rr * 16 + l15) * 44 + lg * 8);
#pragma unroll
    for (int ss = 0; ss < 4; ++ss)
      bb[ss] = *(const bf16x8*)(Xl[cur] + (wq * 64 + ss * 16 + l15) * 40 + ((lg ^ ss) << 3));
#pragma unroll
    for (int rr = 0; rr < 4; ++rr)
#pragma unroll
      for (int ss = 0; ss < 4; ++ss)
        acc[rr][ss] = __builtin_amdgcn_mfma_f32_16x16x32_bf16(a[rr], bb[ss], acc[rr][ss], 0, 0, 0);
    if (kb + 1 < NK) {
      const int nxt = cur ^ 1;
      u16* dst = Wl[nxt] + wr * 44 + wcH * 16;
#pragma unroll
      for (int j = 0; j < 4; ++j)
        *(ushort4*)(dst + j * 4) = make_ushort4(f2b(wreg[j].x), f2b(wreg[j].y), f2b(wreg[j].z), f2b(wreg[j].w));
#pragma unroll
      for (int i = 0; i < 16; ++i)
        Xl[nxt][(xcG * 16 + i) * 40 + csw] = xst[i];
      __syncthreads();
    }
  }
#pragma unroll
  for (int rr = 0; rr < 4; ++rr) {
    int tb = t0 + wo * 64 + rr * 16 + lg * 4;
#pragma unroll
    for (int ss = 0; ss < 4; ++ss) {
      int p = p0 + wq * 64 + ss * 16 + l15;
#pragma unroll
      for (int k = 0; k < 4; ++k) {
        int t = tb + k;
        float val = acc[rr][ss][k];
        if (vec) val += vec[(size_t)b * T + t];
        if (YB) ((u16*)Yv)[((size_t)b * T + t) * P + p] = f2b(val);
        else    ((float*)Yv)[((size_t)b * T + t) * P + p] = val;
      }
    }
  }
}

// ---------------- fused gamma/beta GEMM + inline gvec + BN + ReLU + NHWC pack ----------------
template <bool XINB>
__global__ __launch_bounds__(256, 2) void gbact_kernel(
    const float* __restrict__ Wg, const float* __restrict__ bg,
    const float* __restrict__ Wb, const float* __restrict__ bb_,
    const u16* __restrict__ ctx, const float* __restrict__ gcond,
    const void* __restrict__ xinv,
    const float* __restrict__ mean, const float* __restrict__ rstd,
    const float* __restrict__ bnw, const float* __restrict__ bnb,
    u16* __restrict__ outb, int C, int P) {
  __shared__ u16 shmem[2][16384];
  __shared__ float gvl[128], bvl[128];
  const int b = blockIdx.z, t0 = blockIdx.y * 128, p0 = blockIdx.x * 128;
  const int tid = threadIdx.x;
  const int w = tid >> 6, lane = tid & 63;
  const int wo = w >> 1, wq = w & 1;
  const int l15 = lane & 15, lg = lane >> 4;
  const int wr = tid >> 1, wcH = tid & 1;
  const int xr = tid >> 3, xcG = tid & 7;
  const int csw = xr ^ ((xcG & 3) << 3);
  const float* gsrc = Wg + (size_t)(t0 + wr) * CONDC + GD + wcH * 16;
  const float* bsrc = Wb + (size_t)(t0 + wr) * CONDC + GD + wcH * 16;
  const u16* xsrc = ctx + (size_t)b * TD * P + (size_t)xr * P + p0 + xcG * 16;
  const int NK = TD / 32;
  f32x4 accg[4][4] = {}, accb[4][4] = {};
  float4 greg[4], breg[4];
  u16 xst[16];

  // inline gvec: thread t<128 -> gamma bias for t0+t; t>=128 -> beta bias
  {
    int t = tid & 127;
    const float* row = (tid < 128 ? Wg : Wb) + (size_t)(t0 + t) * CONDC;
    const float* gc = gcond + (size_t)b * GD;
    float s = 0.f;
    for (int c = 0; c < GD; c += 4) {
      float4 wv = *(const float4*)(row + c);
      float4 gv4 = *(const float4*)(gc + c);
      s += wv.x * gv4.x + wv.y * gv4.y + wv.z * gv4.z + wv.w * gv4.w;
    }
    s += (tid < 128 ? bg : bb_)[t0 + t];
    if (tid < 128) gvl[t] = s; else bvl[t] = s;
  }

#pragma unroll
  for (int j = 0; j < 4; ++j) {
    greg[j] = *(const float4*)(gsrc + j * 4);
    breg[j] = *(const float4*)(bsrc + j * 4);
  }
  {
    union { u16 u[16]; uint4 q[2]; } xu;
    xu.q[0] = *(const uint4*)(xsrc);
    xu.q[1] = *(const uint4*)(xsrc + 8);
#pragma unroll
    for (int i = 0; i < 16; ++i) xst[i] = xu.u[i];
  }
  {
    u16* dg = shmem[0] + wr * 44 + wcH * 16;
    u16* db = shmem[0] + 5632 + wr * 44 + wcH * 16;
    u16* xl = shmem[0] + 11264;
#pragma unroll
    for (int j = 0; j < 4; ++j) {
      *(ushort4*)(dg + j * 4) = make_ushort4(f2b(greg[j].x), f2b(greg[j].y), f2b(greg[j].z), f2b(greg[j].w));
      *(ushort4*)(db + j * 4) = make_ushort4(f2b(breg[j].x), f2b(breg[j].y), f2b(breg[j].z), f2b(breg[j].w));
    }
#pragma unroll
    for (int i = 0; i < 16; ++i)
      xl[(xcG * 16 + i) * 40 + csw] = xst[i];
  }
  __syncthreads();

  for (int kb = 0; kb < NK; ++kb) {
    const int cur = kb & 1;
    if (kb + 1 < NK) {
      const int c0n = (kb + 1) * 32;
#pragma unroll
      for (int j = 0; j < 4; ++j) {
        greg[j] = *(const float4*)(gsrc + c0n + j * 4);
        breg[j] = *(const float4*)(bsrc + c0n + j * 4);
      }
      union { u16 u[16]; uint4 q[2]; } xu;
      xu.q[0] = *(const uint4*)(xsrc + (size_t)c0n * P);
      xu.q[1] = *(const uint4*)(xsrc + (size_t)c0n * P + 8);
#pragma unroll
      for (int i = 0; i < 16; ++i) xst[i] = xu.u[i];
    }
    bf16x8 ag[4], ab[4], bb[4];
#pragma unroll
    for (int rr = 0; rr < 4; ++rr) {
      ag[rr] = *(const bf16x8*)(shmem[cur] + (wo * 64 + rr * 16 + l15) * 44 + lg * 8);
      ab[rr] = *(const bf16x8*)(shmem[cur] + 5632 + (wo * 64 + rr * 16 + l15) * 44 + lg * 8);
    }
#pragma unroll
    for (int ss = 0; ss < 4; ++ss)
      bb[ss] = *(const bf16x8*)(shmem[cur] + 11264 + (wq * 64 + ss * 16 + l15) * 40 + ((lg ^ ss) << 3));
#pragma unroll
    for (int rr = 0; rr < 4; ++rr)
#pragma unroll
      for (int ss = 0; ss < 4; ++ss) {
        accg[rr][ss] = __builtin_amdgcn_mfma_f32_16x16x32_bf16(ag[rr], bb[ss], accg[rr][ss], 0, 0, 0);
        accb[rr][ss] = __builtin_amdgcn_mfma_f32_16x16x32_bf16(ab[rr], bb[ss], accb[rr][ss], 0, 0, 0);
      }
    if (kb + 1 < NK) {
      const int nxt = cur ^ 1;
      u16* dg = shmem[nxt] + wr * 44 + wcH * 16;
      u16* db = shmem[nxt] + 5632 + wr * 44 + wcH * 16;
      u16* xl = shmem[nxt] + 11264;
#pragma unroll
      for (int j = 0; j < 4; ++j) {
        *(ushort4*)(dg + j * 4) = make_ushort4(f2b(greg[j].x), f2b(greg[j].y), f2b(greg[j].z), f2b(greg[j].w));
        *(ushort4*)(db + j * 4) = make_ushort4(f2b(breg[j].x), f2b(breg[j].y), f2b(breg[j].z), f2b(breg[j].w));
      }
#pragma unroll
      for (int i = 0; i < 16; ++i)
        xl[(xcG * 16 + i) * 40 + csw] = xst[i];
      __syncthreads();
    }
  }
  __syncthreads();
  u16* tbuf = &shmem[0][0];
#pragma unroll
  for (int rr = 0; rr < 4; ++rr) {
    float gv[4], bv[4], mm[4], rs[4], bB[4];
#pragma unroll
    for (int k = 0; k < 4; ++k) {
      int cl = wo * 64 + rr * 16 + lg * 4 + k;
      int c = t0 + cl;
      gv[k] = gvl[cl];
      bv[k] = bvl[cl];
      mm[k] = mean[c]; rs[k] = rstd[c] * bnw[c]; bB[k] = bnb[c];
    }
#pragma unroll
    for (int ss = 0; ss < 4; ++ss) {
#pragma unroll
      for (int k = 0; k < 4; ++k) {
        int cl = wo * 64 + rr * 16 + lg * 4 + k;
        int pl = wq * 64 + ss * 16 + l15;
        size_t xidx = ((size_t)b * C + t0 + cl) * P + p0 + pl;
        float xv = XINB ? b2f(((const u16*)xinv)[xidx]) : ((const float*)xinv)[xidx];
        float g = accg[rr][ss][k] + gv[k];
        float be = accb[rr][ss][k] + bv[k];
        float val = fmaxf(g * ((xv - mm[k]) * rs[k] + bB[k]) + be, 0.f);
        tbuf[pl * 136 + cl] = f2b(val);
      }
    }
  }
  __syncthreads();
  const int pr = tid >> 1, h = tid & 1;
#pragma unroll
  for (int j = 0; j < 8; ++j) {
    uint4 v = *(uint4*)(tbuf + pr * 136 + h * 64 + j * 8);
    *(uint4*)(outb + ((size_t)b * P + p0 + pr) * C + t0 + h * 64 + j * 8) = v;
  }
}

// ---------------- pack BOTH conv weights: fragment-linear bf16 ----------------
__global__ void pack2_kernel(const float* __restrict__ w1, u16* __restrict__ wp1,
                             const float* __restrict__ w2, u16* __restrict__ wp2) {
  int lin = blockIdx.x * 256 + threadIdx.x;
  const int N1 = COUT * CIN1;
  const float* w; u16* wp; int CIN;
  if (lin < N1) { w = w1; wp = wp1; CIN = CIN1; }
  else { lin -= N1; if (lin >= COUT * COUT) return; w = w2; wp = wp2; CIN = COUT; }
  int o = lin / CIN, c = lin - o * CIN;
  int c0blk = c >> 5, lg = (c >> 3) & 3, cc = c & 7;
  int ot = o >> 4, l15 = o & 15;
  int lane = lg * 16 + l15;
  size_t base = (((size_t)c0blk * (COUT >> 4) + ot) * 64 + lane) * 8 + cc;
  size_t posStride = (size_t)(CIN >> 5) * (COUT >> 4) * 512;
  const float* src = w + ((size_t)o * CIN + c) * 9;
#pragma unroll
  for (int pos = 0; pos < 9; ++pos)
    wp[pos * posStride + base] = f2b(src[pos]);
}

// ---------------- bf16 MFMA implicit-GEMM 3x3 conv (8-wave, optional fused BN stats) ----------------
template <int CIN, bool UP, bool OUTB, bool STATS>
__global__ __launch_bounds__(512, 2) void conv_mfma_kernel(
    const u16* __restrict__ Wp, const u16* __restrict__ Xt,
    const float* __restrict__ scs, const float* __restrict__ scb,
    void* __restrict__ Yv, float* __restrict__ part) {
  constexpr int S = UP ? 32 : 64;
  constexpr int NC0 = CIN >> 5;
  constexpr int NCH = 6 * 66 * 8;
  __shared__ u16 Xs[2][6 * 66 * 36];
  __shared__ float stats_ls[256], stats_lsq[256];
  const int b = blockIdx.z, pxT = blockIdx.x;
  const int tid = threadIdx.x;
  const int w = tid >> 6, lane = tid & 63;
  const int wo = w >> 2, wp_ = w & 3;
  const int l15 = lane & 15, lg = lane >> 4;
  const int Y0 = pxT * 4;
  const u16* Xb = Xt + (size_t)b * S * S * CIN;
  const size_t posStride = (size_t)NC0 * 16 * 512;
  f32x4 acc[8][4] = {};
  uint2 st[7];

  if (STATS && tid < 256) { stats_ls[tid] = 0.f; stats_lsq[tid] = 0.f; }

#pragma unroll
  for (int j = 0; j < 7; ++j) {
    int i = tid + j * 512;
    if (i < NCH) {
      int r = i / 528, rem = i - r * 528, col = rem >> 3, ch = rem & 7;
      int uy = Y0 - 1 + r, ux = col - 1;
      uint2 v = make_uint2(0u, 0u);
      if (uy >= 0 && uy < 64 && ux >= 0 && ux < 64) {
        int sy = UP ? (uy >> 1) : uy, sx = UP ? (ux >> 1) : ux;
        v = *(const uint2*)(Xb + ((size_t)sy * S + sx) * CIN + ch * 4);
      }
      st[j] = v;
    }
  }
#pragma unroll
  for (int j = 0; j < 7; ++j) {
    int i = tid + j * 512;
    if (i < NCH) {
      int r = i / 528, rem = i - r * 528, col = rem >> 3, ch = rem & 7;
      *(uint2*)(&Xs[0][(r * 66 + col) * 36 + ch * 4]) = st[j];
    }
  }
  __syncthreads();

  for (int c0b = 0; c0b < NC0; ++c0b) {
    const int cur = c0b & 1;
    if (c0b + 1 < NC0) {
      const int c0n = (c0b + 1) << 5;
#pragma unroll
      for (int j = 0; j < 7; ++j) {
        int i = tid + j * 512;
        if (i < NCH) {
          int r = i / 528, rem = i - r * 528, col = rem >> 3, ch = rem & 7;
          int uy = Y0 - 1 + r, ux = col - 1;
          uint2 v = make_uint2(0u, 0u);
          if (uy >= 0 && uy < 64 && ux >= 0 && ux < 64) {
            int sy = UP ? (uy >> 1) : uy, sx = UP ? (ux >> 1) : ux;
            v = *(const uint2*)(Xb + ((size_t)sy * S + sx) * CIN + c0n + ch * 4);
          }
          st[j] = v;
        }
      }
    }
    {
      const u16* wbB = Wp + ((size_t)c0b * 16 + wo * 8) * 512 + lane * 8;
      bf16x8 aC[8], aN[8];
#pragma unroll
      for (int rr = 0; rr < 8; ++rr)
        aC[rr] = *(const bf16x8*)(wbB + rr * 512);
#pragma unroll
      for (int pos = 0; pos < 9; ++pos) {
        const int ky = pos / 3, kx = pos - ky * 3;
        if (pos < 8) {
          const u16* wbn = wbB + (size_t)(pos + 1) * posStride;
#pragma unroll
          for (int rr = 0; rr < 8; ++rr)
            aN[rr] = *(const bf16x8*)(wbn + rr * 512);
        }
        const int rowb = ((wp_ + ky) * 66 + kx) * 36 + lg * 8;
#pragma unroll
        for (int ss = 0; ss < 4; ++ss) {
          int idx = rowb + (ss * 16 + l15) * 36;
          union { uint2 q[2]; bf16x8 v; } u;
          u.q[0] = *(const uint2*)(&Xs[cur][idx]);
          u.q[1] = *(const uint2*)(&Xs[cur][idx + 4]);
#pragma unroll
          for (int rr = 0; rr < 8; ++rr)
            acc[rr][ss] = __builtin_amdgcn_mfma_f32_16x16x32_bf16(aC[rr], u.v, acc[rr][ss], 0, 0, 0);
        }
#pragma unroll
        for (int rr = 0; rr < 8; ++rr) aC[rr] = aN[rr];
      }
    }
    if (c0b + 1 < NC0) {
#pragma unroll
      for (int j = 0; j < 7; ++j) {
        int i = tid + j * 512;
        if (i < NCH) {
          int r = i / 528, rem = i - r * 528, col = rem >> 3, ch = rem & 7;
          *(uint2*)(&Xs[cur ^ 1][(r * 66 + col) * 36 + ch * 4]) = st[j];
        }
      }
      __syncthreads();
    }
  }
  const int oBase = wo * 128 + lg * 4;
  const int pxBase = pxT * 256 + wp_ * 64 + l15;
  const int y = Y0 + wp_;
#pragma unroll
  for (int rr = 0; rr < 8; ++rr) {
#pragma unroll
    for (int ss = 0; ss < 4; ++ss) {
      int px = pxBase + ss * 16;
#pragma unroll
      for (int k = 0; k < 4; ++k) {
        int o = oBase + rr * 16 + k;
        float val = acc[rr][ss][k];
        if (scs) {
          int gx = px & 63;
          val += scs[((size_t)b * COUT + o) * P1 + (y >> 1) * 32 + (gx >> 1)] + scb[o];
        }
        if (OUTB) ((u16*)Yv)[((size_t)b * COUT + o) * 4096 + px] = f2b(val);
        else      ((float*)Yv)[((size_t)b * COUT + o) * 4096 + px] = val;
      }
    }
  }
  if (STATS) {
#pragma unroll
    for (int rr = 0; rr < 8; ++rr) {
#pragma unroll
      for (int k = 0; k < 4; ++k) {
        float s = acc[rr][0][k] + acc[rr][1][k] + acc[rr][2][k] + acc[rr][3][k];
        float sq = acc[rr][0][k] * acc[rr][0][k] + acc[rr][1][k] * acc[rr][1][k] +
                   acc[rr][2][k] * acc[rr][2][k] + acc[rr][3][k] * acc[rr][3][k];
#pragma unroll
        for (int o = 1; o < 16; o <<= 1) { s += __shfl_xor(s, o); sq += __shfl_xor(sq, o); }
        if (l15 == 0) {
          int o_ = oBase + rr * 16 + k;
          atomicAdd(&stats_ls[o_], s);
          atomicAdd(&stats_lsq[o_], sq);
        }
      }
    }
    __syncthreads();
    if (tid < 256) {
      int blk = b * 16 + pxT;
      part[(size_t)tid * 256 + blk] = stats_ls[tid];
      part[65536 + (size_t)tid * 256 + blk] = stats_lsq[tid];
    }
  }
}

extern "C" void kernel_launch(void* const* d_in, const int* in_sizes, int n_in,
                              void* d_out, int out_size, void* d_ws, size_t ws_size,
                              hipStream_t stream) {
  const float* x      = (const float*)d_in[0];
  const float* gcond  = (const float*)d_in[1];
  const float* wemb   = (const float*)d_in[2];
  const int*   mask   = (const int*)d_in[3];
  const float* w_img1 = (const float*)d_in[4];
  const float* w_img2 = (const float*)d_in[5];
  const float* w_c1   = (const float*)d_in[6];
  const float* w_c2   = (const float*)d_in[7];
  const float* bn1_w  = (const float*)d_in[8];
  const float* bn1_b  = (const float*)d_in[9];
  const float* bn2_w  = (const float*)d_in[10];
  const float* bn2_b  = (const float*)d_in[11];
  const float* w_g1   = (const float*)d_in[12];
  const float* b_g1   = (const float*)d_in[13];
  const float* w_b1   = (const float*)d_in[14];
  const float* b_b1   = (const float*)d_in[15];
  const float* w_g2   = (const float*)d_in[16];
  const float* b_g2   = (const float*)d_in[17];
  const float* w_b2   = (const float*)d_in[18];
  const float* b_b2   = (const float*)d_in[19];
  const float* w_sc   = (const float*)d_in[20];
  const float* b_sc   = (const float*)d_in[21];
  float* out = (float*)d_out;
  float* ws = (float*)d_ws;

  const size_t MF = 16777216;  // floats per 64MB region
  float* A  = ws;
  float* Br = ws + MF;
  float* Cr = ws + 2 * MF;
  float* SM = ws + 3 * MF;
  float* wdn   = SM;                     // 131072
  float* mean1 = SM + 131072;
  float* rstd1 = mean1 + 512;
  float* mean2 = rstd1 + 512;
  float* rstd2 = mean2 + 256;
  float* part  = rstd2 + 256;            // 131072 (conv1-fused BN2 partials)
  float* wsp   = part + 131072;
  u16* Wp1 = (u16*)wsp;                  // 9*256*512 ushorts
  u16* Wp2 = (u16*)(wsp + 655360);       // 9*256*256 ushorts

  u16* img1   = (u16*)A;                 // 4.2M u16
  u16* ctx1   = (u16*)A + 4194304;       // 4.2M u16
  u16* Xt1    = (u16*)A + 8388608;       // 8.4M u16 NHWC bf16
  u16* conv1o = (u16*)Cr;                // 16.8M u16 NCHW bf16
  u16* img2   = (u16*)Br;                // 16.8M u16
  u16* ctx2   = (u16*)A;                 // reuse (A dead after conv1)
  u16* Xt2    = (u16*)Br;                // reuse (img2 dead after attnctx2)
  float* scs  = Cr;                      // reuse (conv1o dead after gbact2)

  // ---- stage 1 ----
  bn_stats_kernel<false><<<dim3(CIN1), dim3(256), 0, stream>>>(x, mean1, rstd1, CIN1, P1);
  wdn_kernel<<<dim3(NB * LL), dim3(64), 0, stream>>>(wemb, wdn);
  pack2_kernel<<<dim3((COUT * CIN1 + COUT * COUT) / 256), dim3(256), 0, stream>>>(
      w_c1, Wp1, w_c2, Wp2);
  gemm_mfma_kernel<false, true><<<dim3(P1 / 128, TD / 128, NB), dim3(256), 0, stream>>>(
      w_img1, CIN1, 0, x, nullptr, img1, TD, CIN1, P1);
  attnctx_kernel<<<dim3(P1 / 64, NB), dim3(256), 0, stream>>>(img1, wdn, mask, ctx1, P1);
  gbact_kernel<false><<<dim3(P1 / 128, CIN1 / 128, NB), dim3(256), 0, stream>>>(
      w_g1, b_g1, w_b1, b_b1, ctx1, gcond, x, mean1, rstd1, bn1_w, bn1_b, Xt1, CIN1, P1);
  conv_mfma_kernel<CIN1, true, true, true><<<dim3(16, 1, NB), dim3(512), 0, stream>>>(
      Wp1, Xt1, nullptr, nullptr, conv1o, part);

  // ---- stage 2 ----
  bn_fin_kernel<<<dim3(1), dim3(256), 0, stream>>>(part, mean2, rstd2);
  gemm_mfma_kernel<true, true><<<dim3(P2 / 128, TD / 128, NB), dim3(256), 0, stream>>>(
      w_img2, COUT, 0, conv1o, nullptr, img2, TD, COUT, P2);
  attnctx_kernel<<<dim3(P2 / 64, NB), dim3(256), 0, stream>>>(img2, wdn, mask, ctx2, P2);
  gbact_kernel<true><<<dim3(P2 / 128, COUT / 128, NB), dim3(256), 0, stream>>>(
      w_g2, b_g2, w_b2, b_b2, ctx2, gcond, conv1o, mean2, rstd2, bn2_w, bn2_b, Xt2, COUT, P2);
  gemm_mfma_kernel<false, false><<<dim3(P1 / 128, COUT / 128, NB), dim3(256), 0, stream>>>(
      w_sc, CIN1, 0, x, nullptr, scs, COUT, CIN1, P1);
  conv_mfma_kernel<COUT, false, false, false><<<dim3(16, 1, NB), dim3(512), 0, stream>>>(
      Wp2, Xt2, scs, b_sc, out, nullptr);
}

// Round 17
// 461.289 us; speedup vs baseline: 1.4959x; 1.0188x over previous
//
#include <hip/hip_runtime.h>
#include <hip/hip_bf16.h>
#include <math.h>

#define NB 16
#define CIN1 512
#define COUT 256
#define GD 256
#define TD 256
#define LL 32
#define P1 1024
#define P2 4096
#define CONDC 512

typedef __attribute__((ext_vector_type(8))) short bf16x8;
typedef __attribute__((ext_vector_type(4))) float f32x4;
typedef unsigned short u16;

__device__ __forceinline__ u16 f2b(float f) {
  __hip_bfloat16 h = __float2bfloat16(f);
  return *(u16*)&h;
}
__device__ __forceinline__ float b2f(u16 v) {
  unsigned u = ((unsigned)v) << 16;
  float f;
  __builtin_memcpy(&f, &u, 4);
  return f;
}

// ---------------- BN stats (stage 1): mean + rsqrt(var+eps); optional x->bf16 emit ----------------
__global__ void bn_stats_x_kernel(const float* __restrict__ x, float* __restrict__ mean,
                                  float* __restrict__ rstd, u16* __restrict__ xbf,
                                  int C, int HW) {
  int c = blockIdx.x, t = threadIdx.x;
  float s = 0.f, sq = 0.f;
  for (int b = 0; b < NB; ++b) {
    size_t base = ((size_t)b * C + c) * HW;
    for (int i = t; i < HW; i += 256) {
      float v = x[base + i];
      s += v; sq += v * v;
      xbf[base + i] = f2b(v);
    }
  }
  __shared__ float ss[256], sq2[256];
  ss[t] = s; sq2[t] = sq; __syncthreads();
  for (int o = 128; o > 0; o >>= 1) {
    if (t < o) { ss[t] += ss[t + o]; sq2[t] += sq2[t + o]; }
    __syncthreads();
  }
  if (t == 0) {
    float n = (float)NB * (float)HW;
    float m = ss[0] / n;
    float v = sq2[0] / n - m * m;
    mean[c] = m;
    rstd[c] = rsqrtf(v + 1e-5f);
  }
}

// ---------------- finalize conv1-fused BN2 stats from per-block partials ----------------
__global__ void bn_fin_kernel(const float* __restrict__ part, float* __restrict__ mean,
                              float* __restrict__ rstd) {
  int c = threadIdx.x;  // 256
  float s = 0.f, sq = 0.f;
  const float* ps = part + (size_t)c * 256;
  const float* pq = part + 65536 + (size_t)c * 256;
  for (int i = 0; i < 256; ++i) { s += ps[i]; sq += pq[i]; }
  float n = 16.f * 4096.f;
  float m = s / n;
  mean[c] = m;
  rstd[c] = rsqrtf(sq / n - m * m + 1e-5f);
}

// ---------------- normalize words_embs over channel dim per (b,l) ----------------
__global__ void wdn_kernel(const float* __restrict__ we, float* __restrict__ wdn) {
  int b = blockIdx.x >> 5, l = blockIdx.x & 31;
  int t = threadIdx.x; // 64
  const float* base = we + (size_t)b * TD * LL + l;
  float v[4]; float sq = 0.f;
#pragma unroll
  for (int k = 0; k < 4; ++k) { v[k] = base[(size_t)(t * 4 + k) * LL]; sq += v[k] * v[k]; }
#pragma unroll
  for (int o = 32; o > 0; o >>= 1) sq += __shfl_xor(sq, o);
  float r = 1.f / fmaxf(sqrtf(sq), 1e-12f);
  float* ob = wdn + (size_t)b * TD * LL + l;
#pragma unroll
  for (int k = 0; k < 4; ++k) ob[(size_t)(t * 4 + k) * LL] = v[k] * r;
}

// ---------------- fused attention (bf16 img in, bf16 ctx out), dbuf imgT ----------------
__global__ __launch_bounds__(256) void attnctx_kernel(
    const u16* __restrict__ img, const float* __restrict__ wdn,
    const int* __restrict__ mask, u16* __restrict__ ctx, int P) {
  __shared__ u16 imgT[2][64 * 72];
  __shared__ u16 wdnT[32 * 264];
  __shared__ u16 wdnC[256 * 40];
  __shared__ u16 attnB[64 * 40];
  __shared__ float sqP[4][64];
  __shared__ float rnL[64];
  const int b = blockIdx.y, p0 = blockIdx.x * 64;
  const int tid = threadIdx.x;
  const int w = tid >> 6, lane = tid & 63;
  const int l15 = lane & 15, lg = lane >> 4;
  const u16* ib = img + (size_t)b * TD * P;
  const float* wb = wdn + (size_t)b * TD * LL;

  for (int i = tid; i < TD * LL; i += 256) {
    int t = i >> 5, l = i & 31;
    u16 v = f2b(wb[i]);
    wdnT[l * 264 + t] = v;
    wdnC[t * 40 + l] = v;
  }

  f32x4 s0 = {}, s1 = {};
  float ssq = 0.f;
  unsigned pk[8];
  // load chunk 0
#pragma unroll
  for (int i = 0; i < 8; ++i) {
    int t = w * 16 + 2 * i;
    u16 h0 = ib[(size_t)t * P + p0 + lane];
    u16 h1 = ib[(size_t)(t + 1) * P + p0 + lane];
    float v0 = b2f(h0), v1 = b2f(h1);
    ssq += v0 * v0 + v1 * v1;
    pk[i] = (unsigned)h0 | ((unsigned)h1 << 16);
  }
#pragma unroll
  for (int i = 0; i < 8; ++i)
    *(unsigned*)(imgT[0] + lane * 72 + w * 16 + 2 * i) = pk[i];
  __syncthreads();

  for (int q = 0; q < 4; ++q) {
    const int cur = q & 1;
    if (q < 3) {
#pragma unroll
      for (int i = 0; i < 8; ++i) {
        int t = (q + 1) * 64 + w * 16 + 2 * i;
        u16 h0 = ib[(size_t)t * P + p0 + lane];
        u16 h1 = ib[(size_t)(t + 1) * P + p0 + lane];
        float v0 = b2f(h0), v1 = b2f(h1);
        ssq += v0 * v0 + v1 * v1;
        pk[i] = (unsigned)h0 | ((unsigned)h1 << 16);
      }
    }
#pragma unroll
    for (int ks = 0; ks < 2; ++ks) {
      bf16x8 a = *(const bf16x8*)(imgT[cur] + (w * 16 + l15) * 72 + ks * 32 + lg * 8);
      bf16x8 b0 = *(const bf16x8*)(wdnT + l15 * 264 + q * 64 + ks * 32 + lg * 8);
      bf16x8 b1 = *(const bf16x8*)(wdnT + (16 + l15) * 264 + q * 64 + ks * 32 + lg * 8);
      s0 = __builtin_amdgcn_mfma_f32_16x16x32_bf16(a, b0, s0, 0, 0, 0);
      s1 = __builtin_amdgcn_mfma_f32_16x16x32_bf16(a, b1, s1, 0, 0, 0);
    }
    if (q < 3) {
#pragma unroll
      for (int i = 0; i < 8; ++i)
        *(unsigned*)(imgT[cur ^ 1] + lane * 72 + w * 16 + 2 * i) = pk[i];
      __syncthreads();
    }
  }
  sqP[w][lane] = ssq;
  __syncthreads();
  if (tid < 64) {
    float s = sqP[0][tid] + sqP[1][tid] + sqP[2][tid] + sqP[3][tid];
    rnL[tid] = 1.f / fmaxf(sqrtf(s), 1e-12f);
  }
  __syncthreads();
  const bool m0 = mask[b * LL + l15] != 0;
  const bool m1 = mask[b * LL + 16 + l15] != 0;
#pragma unroll
  for (int k = 0; k < 4; ++k) {
    float rn = rnL[w * 16 + lg * 4 + k];
    float v0 = m0 ? -INFINITY : s0[k] * rn;
    float v1 = m1 ? -INFINITY : s1[k] * rn;
    float mx = fmaxf(v0, v1);
#pragma unroll
    for (int o = 1; o < 16; o <<= 1) mx = fmaxf(mx, __shfl_xor(mx, o));
    float e0 = expf(v0 - mx), e1 = expf(v1 - mx);
    float sm = e0 + e1;
#pragma unroll
    for (int o = 1; o < 16; o <<= 1) sm += __shfl_xor(sm, o);
    float inv = 1.f / sm;
    int px = w * 16 + lg * 4 + k;
    attnB[px * 40 + l15] = f2b(e0 * inv);
    attnB[px * 40 + 16 + l15] = f2b(e1 * inv);
  }
  __syncthreads();
  f32x4 acc[4][4] = {};
  bf16x8 bfr[4];
#pragma unroll
  for (int pt = 0; pt < 4; ++pt)
    bfr[pt] = *(const bf16x8*)(attnB + (pt * 16 + l15) * 40 + lg * 8);
#pragma unroll
  for (int cc = 0; cc < 4; ++cc) {
    bf16x8 a = *(const bf16x8*)(wdnC + ((w * 4 + cc) * 16 + l15) * 40 + lg * 8);
#pragma unroll
    for (int pt = 0; pt < 4; ++pt)
      acc[cc][pt] = __builtin_amdgcn_mfma_f32_16x16x32_bf16(a, bfr[pt], acc[cc][pt], 0, 0, 0);
  }
#pragma unroll
  for (int cc = 0; cc < 4; ++cc) {
#pragma unroll
    for (int pt = 0; pt < 4; ++pt) {
#pragma unroll
      for (int k = 0; k < 4; ++k) {
        int c = (w * 4 + cc) * 16 + lg * 4 + k;
        ctx[((size_t)b * TD + c) * P + p0 + pt * 16 + l15] = f2b(acc[cc][pt][k]);
      }
    }
  }
}

// ---------------- bf16 MFMA GEMM, dbuf reg-staged; X fp32/bf16, Y fp32/bf16 ----------------
template <bool XB, bool YB>
__global__ __launch_bounds__(256, 2) void gemm_mfma_kernel(
    const float* __restrict__ W, int ldw, int c_off,
    const void* __restrict__ Xv, const float* __restrict__ vec,
    void* __restrict__ Yv, int T, int C, int P) {
  __shared__ u16 Wl[2][128 * 44];
  __shared__ u16 Xl[2][128 * 40];
  const int b = blockIdx.z;
  const int t0 = blockIdx.y * 128, p0 = blockIdx.x * 128;
  const int tid = threadIdx.x;
  const int w = tid >> 6, lane = tid & 63;
  const int wo = w >> 1, wq = w & 1;
  const int l15 = lane & 15, lg = lane >> 4;
  const int wr = tid >> 1, wcH = tid & 1;
  const int xr = tid >> 3, xcG = tid & 7;
  const int csw = xr ^ ((xcG & 3) << 3);
  const float* wsrc = W + (size_t)(t0 + wr) * ldw + c_off + wcH * 16;
  const float* xsrc32 = XB ? nullptr : (const float*)Xv + (size_t)b * C * P + (size_t)xr * P + p0 + xcG * 16;
  const u16* xsrc16 = XB ? (const u16*)Xv + (size_t)b * C * P + (size_t)xr * P + p0 + xcG * 16 : nullptr;
  const int NK = C / 32;
  f32x4 acc[4][4] = {};
  float4 wreg[4];
  u16 xst[16];

#pragma unroll
  for (int j = 0; j < 4; ++j) wreg[j] = *(const float4*)(wsrc + j * 4);
  if (XB) {
    union { u16 u[16]; uint4 q[2]; } xu;
    xu.q[0] = *(const uint4*)(xsrc16);
    xu.q[1] = *(const uint4*)(xsrc16 + 8);
#pragma unroll
    for (int i = 0; i < 16; ++i) xst[i] = xu.u[i];
  } else {
#pragma unroll
    for (int j = 0; j < 4; ++j) {
      float4 v = *(const float4*)(xsrc32 + j * 4);
      xst[j * 4 + 0] = f2b(v.x); xst[j * 4 + 1] = f2b(v.y);
      xst[j * 4 + 2] = f2b(v.z); xst[j * 4 + 3] = f2b(v.w);
    }
  }
  {
    u16* dst = Wl[0] + wr * 44 + wcH * 16;
#pragma unroll
    for (int j = 0; j < 4; ++j)
      *(ushort4*)(dst + j * 4) = make_ushort4(f2b(wreg[j].x), f2b(wreg[j].y), f2b(wreg[j].z), f2b(wreg[j].w));
#pragma unroll
    for (int i = 0; i < 16; ++i)
      Xl[0][(xcG * 16 + i) * 40 + csw] = xst[i];
  }
  __syncthreads();

  for (int kb = 0; kb < NK; ++kb) {
    const int cur = kb & 1;
    if (kb + 1 < NK) {
      const int c0n = (kb + 1) * 32;
#pragma unroll
      for (int j = 0; j < 4; ++j) wreg[j] = *(const float4*)(wsrc + c0n + j * 4);
      if (XB) {
        union { u16 u[16]; uint4 q[2]; } xu;
        xu.q[0] = *(const uint4*)(xsrc16 + (size_t)c0n * P);
        xu.q[1] = *(const uint4*)(xsrc16 + (size_t)c0n * P + 8);
#pragma unroll
        for (int i = 0; i < 16; ++i) xst[i] = xu.u[i];
      } else {
#pragma unroll
        for (int j = 0; j < 4; ++j) {
          float4 v = *(const float4*)(xsrc32 + (size_t)c0n * P + j * 4);
          xst[j * 4 + 0] = f2b(v.x); xst[j * 4 + 1] = f2b(v.y);
          xst[j * 4 + 2] = f2b(v.z); xst[j * 4 + 3] = f2b(v.w);
        }
      }
    }
    bf16x8 a[4], bb[4];
#pragma unroll
    for (int rr = 0; rr < 4; ++rr)
      a[rr] = *(const bf16x8*)(Wl[cur] + (wo * 64 + rr * 16 + l15) * 44 + lg * 8);
#pragma unroll
    for (int ss = 0; ss < 4; ++ss)
      bb[ss] = *(const bf16x8*)(Xl[cur] + (wq * 64 + ss * 16 + l15) * 40 + ((lg ^ ss) << 3));
#pragma unroll
    for (int rr = 0; rr < 4; ++rr)
#pragma unroll
      for (int ss = 0; ss < 4; ++ss)
        acc[rr][ss] = __builtin_amdgcn_mfma_f32_16x16x32_bf16(a[rr], bb[ss], acc[rr][ss], 0, 0, 0);
    if (kb + 1 < NK) {
      const int nxt = cur ^ 1;
      u16* dst = Wl[nxt] + wr * 44 + wcH * 16;
#pragma unroll
      for (int j = 0; j < 4; ++j)
        *(ushort4*)(dst + j * 4) = make_ushort4(f2b(wreg[j].x), f2b(wreg[j].y), f2b(wreg[j].z), f2b(wreg[j].w));
#pragma unroll
      for (int i = 0; i < 16; ++i)
        Xl[nxt][(xcG * 16 + i) * 40 + csw] = xst[i];
      __syncthreads();
    }
  }
#pragma unroll
  for (int rr = 0; rr < 4; ++rr) {
    int tb = t0 + wo * 64 + rr * 16 + lg * 4;
#pragma unroll
    for (int ss = 0; ss < 4; ++ss) {
      int p = p0 + wq * 64 + ss * 16 + l15;
#pragma unroll
      for (int k = 0; k < 4; ++k) {
        int t = tb + k;
        float val = acc[rr][ss][k];
        if (vec) val += vec[(size_t)b * T + t];
        if (YB) ((u16*)Yv)[((size_t)b * T + t) * P + p] = f2b(val);
        else    ((float*)Yv)[((size_t)b * T + t) * P + p] = val;
      }
    }
  }
}

// ---------------- fused gamma/beta GEMM + inline gvec + BN + ReLU + NHWC pack ----------------
template <bool XINB>
__global__ __launch_bounds__(256, 2) void gbact_kernel(
    const float* __restrict__ Wg, const float* __restrict__ bg,
    const float* __restrict__ Wb, const float* __restrict__ bb_,
    const u16* __restrict__ ctx, const float* __restrict__ gcond,
    const void* __restrict__ xinv,
    const float* __restrict__ mean, const float* __restrict__ rstd,
    const float* __restrict__ bnw, const float* __restrict__ bnb,
    u16* __restrict__ outb, int C, int P) {
  __shared__ u16 shmem[2][16384];
  __shared__ float gvl[128], bvl[128];
  const int b = blockIdx.z, t0 = blockIdx.y * 128, p0 = blockIdx.x * 128;
  const int tid = threadIdx.x;
  const int w = tid >> 6, lane = tid & 63;
  const int wo = w >> 1, wq = w & 1;
  const int l15 = lane & 15, lg = lane >> 4;
  const int wr = tid >> 1, wcH = tid & 1;
  const int xr = tid >> 3, xcG = tid & 7;
  const int csw = xr ^ ((xcG & 3) << 3);
  const float* gsrc = Wg + (size_t)(t0 + wr) * CONDC + GD + wcH * 16;
  const float* bsrc = Wb + (size_t)(t0 + wr) * CONDC + GD + wcH * 16;
  const u16* xsrc = ctx + (size_t)b * TD * P + (size_t)xr * P + p0 + xcG * 16;
  const int NK = TD / 32;
  f32x4 accg[4][4] = {}, accb[4][4] = {};
  float4 greg[4], breg[4];
  u16 xst[16];

  {
    int t = tid & 127;
    const float* row = (tid < 128 ? Wg : Wb) + (size_t)(t0 + t) * CONDC;
    const float* gc = gcond + (size_t)b * GD;
    float s = 0.f;
    for (int c = 0; c < GD; c += 4) {
      float4 wv = *(const float4*)(row + c);
      float4 gv4 = *(const float4*)(gc + c);
      s += wv.x * gv4.x + wv.y * gv4.y + wv.z * gv4.z + wv.w * gv4.w;
    }
    s += (tid < 128 ? bg : bb_)[t0 + t];
    if (tid < 128) gvl[t] = s; else bvl[t] = s;
  }

#pragma unroll
  for (int j = 0; j < 4; ++j) {
    greg[j] = *(const float4*)(gsrc + j * 4);
    breg[j] = *(const float4*)(bsrc + j * 4);
  }
  {
    union { u16 u[16]; uint4 q[2]; } xu;
    xu.q[0] = *(const uint4*)(xsrc);
    xu.q[1] = *(const uint4*)(xsrc + 8);
#pragma unroll
    for (int i = 0; i < 16; ++i) xst[i] = xu.u[i];
  }
  {
    u16* dg = shmem[0] + wr * 44 + wcH * 16;
    u16* db = shmem[0] + 5632 + wr * 44 + wcH * 16;
    u16* xl = shmem[0] + 11264;
#pragma unroll
    for (int j = 0; j < 4; ++j) {
      *(ushort4*)(dg + j * 4) = make_ushort4(f2b(greg[j].x), f2b(greg[j].y), f2b(greg[j].z), f2b(greg[j].w));
      *(ushort4*)(db + j * 4) = make_ushort4(f2b(breg[j].x), f2b(breg[j].y), f2b(breg[j].z), f2b(breg[j].w));
    }
#pragma unroll
    for (int i = 0; i < 16; ++i)
      xl[(xcG * 16 + i) * 40 + csw] = xst[i];
  }
  __syncthreads();

  for (int kb = 0; kb < NK; ++kb) {
    const int cur = kb & 1;
    if (kb + 1 < NK) {
      const int c0n = (kb + 1) * 32;
#pragma unroll
      for (int j = 0; j < 4; ++j) {
        greg[j] = *(const float4*)(gsrc + c0n + j * 4);
        breg[j] = *(const float4*)(bsrc + c0n + j * 4);
      }
      union { u16 u[16]; uint4 q[2]; } xu;
      xu.q[0] = *(const uint4*)(xsrc + (size_t)c0n * P);
      xu.q[1] = *(const uint4*)(xsrc + (size_t)c0n * P + 8);
#pragma unroll
      for (int i = 0; i < 16; ++i) xst[i] = xu.u[i];
    }
    bf16x8 ag[4], ab[4], bb[4];
#pragma unroll
    for (int rr = 0; rr < 4; ++rr) {
      ag[rr] = *(const bf16x8*)(shmem[cur] + (wo * 64 + rr * 16 + l15) * 44 + lg * 8);
      ab[rr] = *(const bf16x8*)(shmem[cur] + 5632 + (wo * 64 + rr * 16 + l15) * 44 + lg * 8);
    }
#pragma unroll
    for (int ss = 0; ss < 4; ++ss)
      bb[ss] = *(const bf16x8*)(shmem[cur] + 11264 + (wq * 64 + ss * 16 + l15) * 40 + ((lg ^ ss) << 3));
#pragma unroll
    for (int rr = 0; rr < 4; ++rr)
#pragma unroll
      for (int ss = 0; ss < 4; ++ss) {
        accg[rr][ss] = __builtin_amdgcn_mfma_f32_16x16x32_bf16(ag[rr], bb[ss], accg[rr][ss], 0, 0, 0);
        accb[rr][ss] = __builtin_amdgcn_mfma_f32_16x16x32_bf16(ab[rr], bb[ss], accb[rr][ss], 0, 0, 0);
      }
    if (kb + 1 < NK) {
      const int nxt = cur ^ 1;
      u16* dg = shmem[nxt] + wr * 44 + wcH * 16;
      u16* db = shmem[nxt] + 5632 + wr * 44 + wcH * 16;
      u16* xl = shmem[nxt] + 11264;
#pragma unroll
      for (int j = 0; j < 4; ++j) {
        *(ushort4*)(dg + j * 4) = make_ushort4(f2b(greg[j].x), f2b(greg[j].y), f2b(greg[j].z), f2b(greg[j].w));
        *(ushort4*)(db + j * 4) = make_ushort4(f2b(breg[j].x), f2b(breg[j].y), f2b(breg[j].z), f2b(breg[j].w));
      }
#pragma unroll
      for (int i = 0; i < 16; ++i)
        xl[(xcG * 16 + i) * 40 + csw] = xst[i];
      __syncthreads();
    }
  }
  __syncthreads();
  u16* tbuf = &shmem[0][0];
#pragma unroll
  for (int rr = 0; rr < 4; ++rr) {
    float gv[4], bv[4], mm[4], rs[4], bB[4];
#pragma unroll
    for (int k = 0; k < 4; ++k) {
      int cl = wo * 64 + rr * 16 + lg * 4 + k;
      int c = t0 + cl;
      gv[k] = gvl[cl];
      bv[k] = bvl[cl];
      mm[k] = mean[c]; rs[k] = rstd[c] * bnw[c]; bB[k] = bnb[c];
    }
#pragma unroll
    for (int ss = 0; ss < 4; ++ss) {
#pragma unroll
      for (int k = 0; k < 4; ++k) {
        int cl = wo * 64 + rr * 16 + lg * 4 + k;
        int pl = wq * 64 + ss * 16 + l15;
        size_t xidx = ((size_t)b * C + t0 + cl) * P + p0 + pl;
        float xv = XINB ? b2f(((const u16*)xinv)[xidx]) : ((const float*)xinv)[xidx];
        float g = accg[rr][ss][k] + gv[k];
        float be = accb[rr][ss][k] + bv[k];
        float val = fmaxf(g * ((xv - mm[k]) * rs[k] + bB[k]) + be, 0.f);
        tbuf[pl * 136 + cl] = f2b(val);
      }
    }
  }
  __syncthreads();
  const int pr = tid >> 1, h = tid & 1;
#pragma unroll
  for (int j = 0; j < 8; ++j) {
    uint4 v = *(uint4*)(tbuf + pr * 136 + h * 64 + j * 8);
    *(uint4*)(outb + ((size_t)b * P + p0 + pr) * C + t0 + h * 64 + j * 8) = v;
  }
}

// ---------------- pack BOTH conv weights: fragment-linear bf16 ----------------
__global__ void pack2_kernel(const float* __restrict__ w1, u16* __restrict__ wp1,
                             const float* __restrict__ w2, u16* __restrict__ wp2) {
  int lin = blockIdx.x * 256 + threadIdx.x;
  const int N1 = COUT * CIN1;
  const float* w; u16* wp; int CIN;
  if (lin < N1) { w = w1; wp = wp1; CIN = CIN1; }
  else { lin -= N1; if (lin >= COUT * COUT) return; w = w2; wp = wp2; CIN = COUT; }
  int o = lin / CIN, c = lin - o * CIN;
  int c0blk = c >> 5, lg = (c >> 3) & 3, cc = c & 7;
  int ot = o >> 4, l15 = o & 15;
  int lane = lg * 16 + l15;
  size_t base = (((size_t)c0blk * (COUT >> 4) + ot) * 64 + lane) * 8 + cc;
  size_t posStride = (size_t)(CIN >> 5) * (COUT >> 4) * 512;
  const float* src = w + ((size_t)o * CIN + c) * 9;
#pragma unroll
  for (int pos = 0; pos < 9; ++pos)
    wp[pos * posStride + base] = f2b(src[pos]);
}

// ---------------- bf16 MFMA implicit-GEMM 3x3 conv (8-wave, optional fused BN stats) ----------------
// scs (shortcut) is bf16 when present.
template <int CIN, bool UP, bool OUTB, bool STATS>
__global__ __launch_bounds__(512, 2) void conv_mfma_kernel(
    const u16* __restrict__ Wp, const u16* __restrict__ Xt,
    const u16* __restrict__ scs, const float* __restrict__ scb,
    void* __restrict__ Yv, float* __restrict__ part) {
  constexpr int S = UP ? 32 : 64;
  constexpr int NC0 = CIN >> 5;
  constexpr int NCH = 6 * 66 * 8;
  __shared__ u16 Xs[2][6 * 66 * 36];
  __shared__ float stats_ls[256], stats_lsq[256];
  const int b = blockIdx.z, pxT = blockIdx.x;
  const int tid = threadIdx.x;
  const int w = tid >> 6, lane = tid & 63;
  const int wo = w >> 2, wp_ = w & 3;
  const int l15 = lane & 15, lg = lane >> 4;
  const int Y0 = pxT * 4;
  const u16* Xb = Xt + (size_t)b * S * S * CIN;
  const size_t posStride = (size_t)NC0 * 16 * 512;
  f32x4 acc[8][4] = {};
  uint2 st[7];

  if (STATS && tid < 256) { stats_ls[tid] = 0.f; stats_lsq[tid] = 0.f; }

#pragma unroll
  for (int j = 0; j < 7; ++j) {
    int i = tid + j * 512;
    if (i < NCH) {
      int r = i / 528, rem = i - r * 528, col = rem >> 3, ch = rem & 7;
      int uy = Y0 - 1 + r, ux = col - 1;
      uint2 v = make_uint2(0u, 0u);
      if (uy >= 0 && uy < 64 && ux >= 0 && ux < 64) {
        int sy = UP ? (uy >> 1) : uy, sx = UP ? (ux >> 1) : ux;
        v = *(const uint2*)(Xb + ((size_t)sy * S + sx) * CIN + ch * 4);
      }
      st[j] = v;
    }
  }
#pragma unroll
  for (int j = 0; j < 7; ++j) {
    int i = tid + j * 512;
    if (i < NCH) {
      int r = i / 528, rem = i - r * 528, col = rem >> 3, ch = rem & 7;
      *(uint2*)(&Xs[0][(r * 66 + col) * 36 + ch * 4]) = st[j];
    }
  }
  __syncthreads();

  for (int c0b = 0; c0b < NC0; ++c0b) {
    const int cur = c0b & 1;
    if (c0b + 1 < NC0) {
      const int c0n = (c0b + 1) << 5;
#pragma unroll
      for (int j = 0; j < 7; ++j) {
        int i = tid + j * 512;
        if (i < NCH) {
          int r = i / 528, rem = i - r * 528, col = rem >> 3, ch = rem & 7;
          int uy = Y0 - 1 + r, ux = col - 1;
          uint2 v = make_uint2(0u, 0u);
          if (uy >= 0 && uy < 64 && ux >= 0 && ux < 64) {
            int sy = UP ? (uy >> 1) : uy, sx = UP ? (ux >> 1) : ux;
            v = *(const uint2*)(Xb + ((size_t)sy * S + sx) * CIN + c0n + ch * 4);
          }
          st[j] = v;
        }
      }
    }
    {
      const u16* wbB = Wp + ((size_t)c0b * 16 + wo * 8) * 512 + lane * 8;
      bf16x8 aC[8], aN[8];
#pragma unroll
      for (int rr = 0; rr < 8; ++rr)
        aC[rr] = *(const bf16x8*)(wbB + rr * 512);
#pragma unroll
      for (int pos = 0; pos < 9; ++pos) {
        const int ky = pos / 3, kx = pos - ky * 3;
        if (pos < 8) {
          const u16* wbn = wbB + (size_t)(pos + 1) * posStride;
#pragma unroll
          for (int rr = 0; rr < 8; ++rr)
            aN[rr] = *(const bf16x8*)(wbn + rr * 512);
        }
        const int rowb = ((wp_ + ky) * 66 + kx) * 36 + lg * 8;
#pragma unroll
        for (int ss = 0; ss < 4; ++ss) {
          int idx = rowb + (ss * 16 + l15) * 36;
          union { uint2 q[2]; bf16x8 v; } u;
          u.q[0] = *(const uint2*)(&Xs[cur][idx]);
          u.q[1] = *(const uint2*)(&Xs[cur][idx + 4]);
#pragma unroll
          for (int rr = 0; rr < 8; ++rr)
            acc[rr][ss] = __builtin_amdgcn_mfma_f32_16x16x32_bf16(aC[rr], u.v, acc[rr][ss], 0, 0, 0);
        }
#pragma unroll
        for (int rr = 0; rr < 8; ++rr) aC[rr] = aN[rr];
      }
    }
    if (c0b + 1 < NC0) {
#pragma unroll
      for (int j = 0; j < 7; ++j) {
        int i = tid + j * 512;
        if (i < NCH) {
          int r = i / 528, rem = i - r * 528, col = rem >> 3, ch = rem & 7;
          *(uint2*)(&Xs[cur ^ 1][(r * 66 + col) * 36 + ch * 4]) = st[j];
        }
      }
      __syncthreads();
    }
  }
  const int oBase = wo * 128 + lg * 4;
  const int pxBase = pxT * 256 + wp_ * 64 + l15;
  const int y = Y0 + wp_;
#pragma unroll
  for (int rr = 0; rr < 8; ++rr) {
#pragma unroll
    for (int ss = 0; ss < 4; ++ss) {
      int px = pxBase + ss * 16;
#pragma unroll
      for (int k = 0; k < 4; ++k) {
        int o = oBase + rr * 16 + k;
        float val = acc[rr][ss][k];
        if (scs) {
          int gx = px & 63;
          val += b2f(scs[((size_t)b * COUT + o) * P1 + (y >> 1) * 32 + (gx >> 1)]) + scb[o];
        }
        if (OUTB) ((u16*)Yv)[((size_t)b * COUT + o) * 4096 + px] = f2b(val);
        else      ((float*)Yv)[((size_t)b * COUT + o) * 4096 + px] = val;
      }
    }
  }
  if (STATS) {
#pragma unroll
    for (int rr = 0; rr < 8; ++rr) {
#pragma unroll
      for (int k = 0; k < 4; ++k) {
        float s = acc[rr][0][k] + acc[rr][1][k] + acc[rr][2][k] + acc[rr][3][k];
        float sq = acc[rr][0][k] * acc[rr][0][k] + acc[rr][1][k] * acc[rr][1][k] +
                   acc[rr][2][k] * acc[rr][2][k] + acc[rr][3][k] * acc[rr][3][k];
#pragma unroll
        for (int o = 1; o < 16; o <<= 1) { s += __shfl_xor(s, o); sq += __shfl_xor(sq, o); }
        if (l15 == 0) {
          int o_ = oBase + rr * 16 + k;
          atomicAdd(&stats_ls[o_], s);
          atomicAdd(&stats_lsq[o_], sq);
        }
      }
    }
    __syncthreads();
    if (tid < 256) {
      int blk = b * 16 + pxT;
      part[(size_t)tid * 256 + blk] = stats_ls[tid];
      part[65536 + (size_t)tid * 256 + blk] = stats_lsq[tid];
    }
  }
}

extern "C" void kernel_launch(void* const* d_in, const int* in_sizes, int n_in,
                              void* d_out, int out_size, void* d_ws, size_t ws_size,
                              hipStream_t stream) {
  const float* x      = (const float*)d_in[0];
  const float* gcond  = (const float*)d_in[1];
  const float* wemb   = (const float*)d_in[2];
  const int*   mask   = (const int*)d_in[3];
  const float* w_img1 = (const float*)d_in[4];
  const float* w_img2 = (const float*)d_in[5];
  const float* w_c1   = (const float*)d_in[6];
  const float* w_c2   = (const float*)d_in[7];
  const float* bn1_w  = (const float*)d_in[8];
  const float* bn1_b  = (const float*)d_in[9];
  const float* bn2_w  = (const float*)d_in[10];
  const float* bn2_b  = (const float*)d_in[11];
  const float* w_g1   = (const float*)d_in[12];
  const float* b_g1   = (const float*)d_in[13];
  const float* w_b1   = (const float*)d_in[14];
  const float* b_b1   = (const float*)d_in[15];
  const float* w_g2   = (const float*)d_in[16];
  const float* b_g2   = (const float*)d_in[17];
  const float* w_b2   = (const float*)d_in[18];
  const float* b_b2   = (const float*)d_in[19];
  const float* w_sc   = (const float*)d_in[20];
  const float* b_sc   = (const float*)d_in[21];
  float* out = (float*)d_out;
  float* ws = (float*)d_ws;

  const size_t MF = 16777216;  // floats per 64MB region
  float* A  = ws;
  float* Br = ws + MF;
  float* Cr = ws + 2 * MF;
  float* SM = ws + 3 * MF;
  float* wdn   = SM;                     // 131072
  float* mean1 = SM + 131072;
  float* rstd1 = mean1 + 512;
  float* mean2 = rstd1 + 512;
  float* rstd2 = mean2 + 256;
  float* part  = rstd2 + 256;            // 131072 (conv1-fused BN2 partials)
  float* wsp   = part + 131072;
  u16* Wp1 = (u16*)wsp;                  // 9*256*512 u16
  u16* Wp2 = (u16*)(wsp + 655360);       // 9*256*256 u16
  u16* scs = (u16*)(wsp + 655360 + 294912);  // 4.2M u16 (bf16 shortcut)

  u16* img1   = (u16*)A;                 // 4.2M u16
  u16* ctx1   = (u16*)A + 4194304;       // 4.2M u16
  u16* Xt1    = (u16*)A + 8388608;       // 8.4M u16 NHWC bf16
  u16* xbf    = (u16*)A + 16777216;      // 8.4M u16 (bf16 copy of x)
  u16* conv1o = (u16*)Cr;                // 16.8M u16 NCHW bf16
  u16* img2   = (u16*)Br;                // 16.8M u16
  u16* ctx2   = (u16*)A;                 // reuse (A dead after conv1 + shortcut)
  u16* Xt2    = (u16*)Br;                // reuse (img2 dead after attnctx2)

  // ---- stage 1 ----
  bn_stats_x_kernel<<<dim3(CIN1), dim3(256), 0, stream>>>(x, mean1, rstd1, xbf, CIN1, P1);
  wdn_kernel<<<dim3(NB * LL), dim3(64), 0, stream>>>(wemb, wdn);
  pack2_kernel<<<dim3((COUT * CIN1 + COUT * COUT) / 256), dim3(256), 0, stream>>>(
      w_c1, Wp1, w_c2, Wp2);
  gemm_mfma_kernel<true, true><<<dim3(P1 / 128, TD / 128, NB), dim3(256), 0, stream>>>(
      w_img1, CIN1, 0, xbf, nullptr, img1, TD, CIN1, P1);
  gemm_mfma_kernel<true, true><<<dim3(P1 / 128, COUT / 128, NB), dim3(256), 0, stream>>>(
      w_sc, CIN1, 0, xbf, nullptr, scs, COUT, CIN1, P1);
  attnctx_kernel<<<dim3(P1 / 64, NB), dim3(256), 0, stream>>>(img1, wdn, mask, ctx1, P1);
  gbact_kernel<true><<<dim3(P1 / 128, CIN1 / 128, NB), dim3(256), 0, stream>>>(
      w_g1, b_g1, w_b1, b_b1, ctx1, gcond, xbf, mean1, rstd1, bn1_w, bn1_b, Xt1, CIN1, P1);
  conv_mfma_kernel<CIN1, true, true, true><<<dim3(16, 1, NB), dim3(512), 0, stream>>>(
      Wp1, Xt1, nullptr, nullptr, conv1o, part);

  // ---- stage 2 ----
  bn_fin_kernel<<<dim3(1), dim3(256), 0, stream>>>(part, mean2, rstd2);
  gemm_mfma_kernel<true, true><<<dim3(P2 / 128, TD / 128, NB), dim3(256), 0, stream>>>(
      w_img2, COUT, 0, conv1o, nullptr, img2, TD, COUT, P2);
  attnctx_kernel<<<dim3(P2 / 64, NB), dim3(256), 0, stream>>>(img2, wdn, mask, ctx2, P2);
  gbact_kernel<true><<<dim3(P2 / 128, COUT / 128, NB), dim3(256), 0, stream>>>(
      w_g2, b_g2, w_b2, b_b2, ctx2, gcond, conv1o, mean2, rstd2, bn2_w, bn2_b, Xt2, COUT, P2);
  conv_mfma_kernel<COUT, false, false, false><<<dim3(16, 1, NB), dim3(512), 0, stream>>>(
      Wp2, Xt2, scs, b_sc, out, nullptr);
}

// Round 18
// 458.065 us; speedup vs baseline: 1.5064x; 1.0070x over previous
//
#include <hip/hip_runtime.h>
#include <hip/hip_bf16.h>
#include <math.h>

#define NB 16
#define CIN1 512
#define COUT 256
#define GD 256
#define TD 256
#define LL 32
#define P1 1024
#define P2 4096
#define CONDC 512

typedef __attribute__((ext_vector_type(8))) short bf16x8;
typedef __attribute__((ext_vector_type(4))) float f32x4;
typedef unsigned short u16;

__device__ __forceinline__ u16 f2b(float f) {
  __hip_bfloat16 h = __float2bfloat16(f);
  return *(u16*)&h;
}
__device__ __forceinline__ float b2f(u16 v) {
  unsigned u = ((unsigned)v) << 16;
  float f;
  __builtin_memcpy(&f, &u, 4);
  return f;
}

// ---------------- BN stats (stage 1): mean + rsqrt(var+eps); x->bf16 emit ----------------
__global__ void bn_stats_x_kernel(const float* __restrict__ x, float* __restrict__ mean,
                                  float* __restrict__ rstd, u16* __restrict__ xbf,
                                  int C, int HW) {
  int c = blockIdx.x, t = threadIdx.x;
  float s = 0.f, sq = 0.f;
  for (int b = 0; b < NB; ++b) {
    size_t base = ((size_t)b * C + c) * HW;
    for (int i = t; i < HW; i += 256) {
      float v = x[base + i];
      s += v; sq += v * v;
      xbf[base + i] = f2b(v);
    }
  }
  __shared__ float ss[256], sq2[256];
  ss[t] = s; sq2[t] = sq; __syncthreads();
  for (int o = 128; o > 0; o >>= 1) {
    if (t < o) { ss[t] += ss[t + o]; sq2[t] += sq2[t + o]; }
    __syncthreads();
  }
  if (t == 0) {
    float n = (float)NB * (float)HW;
    float m = ss[0] / n;
    float v = sq2[0] / n - m * m;
    mean[c] = m;
    rstd[c] = rsqrtf(v + 1e-5f);
  }
}

// ---------------- finalize conv1-fused BN2 stats ----------------
__global__ void bn_fin_kernel(const float* __restrict__ part, float* __restrict__ mean,
                              float* __restrict__ rstd) {
  int c = threadIdx.x;  // 256
  float s = 0.f, sq = 0.f;
  const float* ps = part + (size_t)c * 256;
  const float* pq = part + 65536 + (size_t)c * 256;
  for (int i = 0; i < 256; ++i) { s += ps[i]; sq += pq[i]; }
  float n = 16.f * 4096.f;
  float m = s / n;
  mean[c] = m;
  rstd[c] = rsqrtf(sq / n - m * m + 1e-5f);
}

// ---------------- normalize words_embs ----------------
__global__ void wdn_kernel(const float* __restrict__ we, float* __restrict__ wdn) {
  int b = blockIdx.x >> 5, l = blockIdx.x & 31;
  int t = threadIdx.x; // 64
  const float* base = we + (size_t)b * TD * LL + l;
  float v[4]; float sq = 0.f;
#pragma unroll
  for (int k = 0; k < 4; ++k) { v[k] = base[(size_t)(t * 4 + k) * LL]; sq += v[k] * v[k]; }
#pragma unroll
  for (int o = 32; o > 0; o >>= 1) sq += __shfl_xor(sq, o);
  float r = 1.f / fmaxf(sqrtf(sq), 1e-12f);
  float* ob = wdn + (size_t)b * TD * LL + l;
#pragma unroll
  for (int k = 0; k < 4; ++k) ob[(size_t)(t * 4 + k) * LL] = v[k] * r;
}

// ---------------- stage-1 fused attention (bf16 img in, bf16 ctx out), dbuf imgT ----------------
__global__ __launch_bounds__(256) void attnctx_kernel(
    const u16* __restrict__ img, const float* __restrict__ wdn,
    const int* __restrict__ mask, u16* __restrict__ ctx, int P) {
  __shared__ u16 imgT[2][64 * 72];
  __shared__ u16 wdnT[32 * 264];
  __shared__ u16 wdnC[256 * 40];
  __shared__ u16 attnB[64 * 40];
  __shared__ float sqP[4][64];
  __shared__ float rnL[64];
  const int b = blockIdx.y, p0 = blockIdx.x * 64;
  const int tid = threadIdx.x;
  const int w = tid >> 6, lane = tid & 63;
  const int l15 = lane & 15, lg = lane >> 4;
  const u16* ib = img + (size_t)b * TD * P;
  const float* wb = wdn + (size_t)b * TD * LL;

  for (int i = tid; i < TD * LL; i += 256) {
    int t = i >> 5, l = i & 31;
    u16 v = f2b(wb[i]);
    wdnT[l * 264 + t] = v;
    wdnC[t * 40 + l] = v;
  }

  f32x4 s0 = {}, s1 = {};
  float ssq = 0.f;
  unsigned pk[8];
#pragma unroll
  for (int i = 0; i < 8; ++i) {
    int t = w * 16 + 2 * i;
    u16 h0 = ib[(size_t)t * P + p0 + lane];
    u16 h1 = ib[(size_t)(t + 1) * P + p0 + lane];
    float v0 = b2f(h0), v1 = b2f(h1);
    ssq += v0 * v0 + v1 * v1;
    pk[i] = (unsigned)h0 | ((unsigned)h1 << 16);
  }
#pragma unroll
  for (int i = 0; i < 8; ++i)
    *(unsigned*)(imgT[0] + lane * 72 + w * 16 + 2 * i) = pk[i];
  __syncthreads();

  for (int q = 0; q < 4; ++q) {
    const int cur = q & 1;
    if (q < 3) {
#pragma unroll
      for (int i = 0; i < 8; ++i) {
        int t = (q + 1) * 64 + w * 16 + 2 * i;
        u16 h0 = ib[(size_t)t * P + p0 + lane];
        u16 h1 = ib[(size_t)(t + 1) * P + p0 + lane];
        float v0 = b2f(h0), v1 = b2f(h1);
        ssq += v0 * v0 + v1 * v1;
        pk[i] = (unsigned)h0 | ((unsigned)h1 << 16);
      }
    }
#pragma unroll
    for (int ks = 0; ks < 2; ++ks) {
      bf16x8 a = *(const bf16x8*)(imgT[cur] + (w * 16 + l15) * 72 + ks * 32 + lg * 8);
      bf16x8 b0 = *(const bf16x8*)(wdnT + l15 * 264 + q * 64 + ks * 32 + lg * 8);
      bf16x8 b1 = *(const bf16x8*)(wdnT + (16 + l15) * 264 + q * 64 + ks * 32 + lg * 8);
      s0 = __builtin_amdgcn_mfma_f32_16x16x32_bf16(a, b0, s0, 0, 0, 0);
      s1 = __builtin_amdgcn_mfma_f32_16x16x32_bf16(a, b1, s1, 0, 0, 0);
    }
    if (q < 3) {
#pragma unroll
      for (int i = 0; i < 8; ++i)
        *(unsigned*)(imgT[cur ^ 1] + lane * 72 + w * 16 + 2 * i) = pk[i];
      __syncthreads();
    }
  }
  sqP[w][lane] = ssq;
  __syncthreads();
  if (tid < 64) {
    float s = sqP[0][tid] + sqP[1][tid] + sqP[2][tid] + sqP[3][tid];
    rnL[tid] = 1.f / fmaxf(sqrtf(s), 1e-12f);
  }
  __syncthreads();
  const bool m0 = mask[b * LL + l15] != 0;
  const bool m1 = mask[b * LL + 16 + l15] != 0;
#pragma unroll
  for (int k = 0; k < 4; ++k) {
    float rn = rnL[w * 16 + lg * 4 + k];
    float v0 = m0 ? -INFINITY : s0[k] * rn;
    float v1 = m1 ? -INFINITY : s1[k] * rn;
    float mx = fmaxf(v0, v1);
#pragma unroll
    for (int o = 1; o < 16; o <<= 1) mx = fmaxf(mx, __shfl_xor(mx, o));
    float e0 = expf(v0 - mx), e1 = expf(v1 - mx);
    float sm = e0 + e1;
#pragma unroll
    for (int o = 1; o < 16; o <<= 1) sm += __shfl_xor(sm, o);
    float inv = 1.f / sm;
    int px = w * 16 + lg * 4 + k;
    attnB[px * 40 + l15] = f2b(e0 * inv);
    attnB[px * 40 + 16 + l15] = f2b(e1 * inv);
  }
  __syncthreads();
  f32x4 acc[4][4] = {};
  bf16x8 bfr[4];
#pragma unroll
  for (int pt = 0; pt < 4; ++pt)
    bfr[pt] = *(const bf16x8*)(attnB + (pt * 16 + l15) * 40 + lg * 8);
#pragma unroll
  for (int cc = 0; cc < 4; ++cc) {
    bf16x8 a = *(const bf16x8*)(wdnC + ((w * 4 + cc) * 16 + l15) * 40 + lg * 8);
#pragma unroll
    for (int pt = 0; pt < 4; ++pt)
      acc[cc][pt] = __builtin_amdgcn_mfma_f32_16x16x32_bf16(a, bfr[pt], acc[cc][pt], 0, 0, 0);
  }
#pragma unroll
  for (int cc = 0; cc < 4; ++cc) {
#pragma unroll
    for (int pt = 0; pt < 4; ++pt) {
#pragma unroll
      for (int k = 0; k < 4; ++k) {
        int c = (w * 4 + cc) * 16 + lg * 4 + k;
        ctx[((size_t)b * TD + c) * P + p0 + pt * 16 + l15] = f2b(acc[cc][pt][k]);
      }
    }
  }
}

// ---------------- stage-2 fused img-GEMM + attention + ctx ----------------
// img[px][t] = sum_c conv1o[c][px] * W2[t][c] via MFMA; then l2norm/sim/softmax/ctx.
// LDS overlay: region0 = imgT[64][264] (phase A/B) -> wdnC+attnB (phase C);
//              region1 = Xl dbuf (phase A) -> wdnT (phase B).
__global__ __launch_bounds__(256) void attnimg_kernel(
    const u16* __restrict__ W2p, const u16* __restrict__ xin,
    const float* __restrict__ wdn, const int* __restrict__ mask,
    u16* __restrict__ ctx, int P) {
  __shared__ u16 smem[(33792 + 16896) / 2];
  __shared__ float rnL[64];
  u16* imgT  = smem;                     // [64][264]
  u16* Xl    = smem + 16896;             // dbuf 2 x (64*40), aliases region1
  u16* wdnT  = smem + 16896;             // [32][264], phase B
  u16* wdnC  = smem;                     // [256][40], phase C (over imgT)
  u16* attnB = smem + 10240;             // [64][40], phase C (over imgT)
  const int b = blockIdx.y, p0 = blockIdx.x * 64;
  const int tid = threadIdx.x;
  const int w = tid >> 6, lane = tid & 63;
  const int l15 = lane & 15, lg = lane >> 4;
  const u16* xb = xin + (size_t)b * COUT * P;
  const float* wb = wdn + (size_t)b * TD * LL;

  // ---- phase A: img GEMM (K=256, 8 steps of 32c) ----
  const int xr = tid >> 3, xcG = tid & 7;
  const int csw = xr ^ (((xcG >> 1) & 3) << 3);
  const u16* xsrc = xb + (size_t)xr * P + p0 + xcG * 8;
  u16 xst[8];
  {
    union { u16 u[8]; uint4 q; } xu;
    xu.q = *(const uint4*)xsrc;
#pragma unroll
    for (int i = 0; i < 8; ++i) xst[i] = xu.u[i];
  }
#pragma unroll
  for (int i = 0; i < 8; ++i)
    Xl[(xcG * 8 + i) * 40 + csw] = xst[i];
  __syncthreads();

  f32x4 acc[16];
#pragma unroll
  for (int tt = 0; tt < 16; ++tt) acc[tt] = (f32x4){0.f, 0.f, 0.f, 0.f};
  for (int c0b = 0; c0b < 8; ++c0b) {
    const int cur = c0b & 1;
    if (c0b + 1 < 8) {
      union { u16 u[8]; uint4 q; } xu;
      xu.q = *(const uint4*)(xsrc + (size_t)((c0b + 1) * 32) * P);
#pragma unroll
      for (int i = 0; i < 8; ++i) xst[i] = xu.u[i];
    }
    bf16x8 aA = *(const bf16x8*)(Xl + cur * 2560 + (w * 16 + l15) * 40 + ((lg ^ w) << 3));
#pragma unroll
    for (int tt = 0; tt < 16; ++tt) {
      bf16x8 bfr = *(const bf16x8*)(W2p + (((size_t)c0b * 16 + tt) * 64 + lane) * 8);
      acc[tt] = __builtin_amdgcn_mfma_f32_16x16x32_bf16(aA, bfr, acc[tt], 0, 0, 0);
    }
    if (c0b + 1 < 8) {
      const int nxt = cur ^ 1;
#pragma unroll
      for (int i = 0; i < 8; ++i)
        Xl[nxt * 2560 + (xcG * 8 + i) * 40 + csw] = xst[i];
      __syncthreads();
    }
  }
  // ssq per px (row = w*16+lg*4+k): sum over t = lane-local tt sweep + l15-group reduce
#pragma unroll
  for (int k = 0; k < 4; ++k) {
    float s = 0.f;
#pragma unroll
    for (int tt = 0; tt < 16; ++tt) s += acc[tt][k] * acc[tt][k];
#pragma unroll
    for (int o = 1; o < 16; o <<= 1) s += __shfl_xor(s, o);
    if (l15 == 0) rnL[w * 16 + lg * 4 + k] = 1.f / fmaxf(sqrtf(s), 1e-12f);
  }
  // materialize imgT[px][t]
#pragma unroll
  for (int tt = 0; tt < 16; ++tt)
#pragma unroll
    for (int k = 0; k < 4; ++k)
      imgT[(w * 16 + lg * 4 + k) * 264 + tt * 16 + l15] = f2b(acc[tt][k]);
  __syncthreads();

  // ---- phase B: stage wdnT (over Xl), sim ----
  for (int i = tid; i < TD * LL; i += 256) {
    int t = i >> 5, l = i & 31;
    wdnT[l * 264 + t] = f2b(wb[i]);
  }
  __syncthreads();
  f32x4 s0 = {}, s1 = {};
#pragma unroll
  for (int q = 0; q < 4; ++q) {
#pragma unroll
    for (int ks = 0; ks < 2; ++ks) {
      bf16x8 a = *(const bf16x8*)(imgT + (w * 16 + l15) * 264 + q * 64 + ks * 32 + lg * 8);
      bf16x8 b0 = *(const bf16x8*)(wdnT + l15 * 264 + q * 64 + ks * 32 + lg * 8);
      bf16x8 b1 = *(const bf16x8*)(wdnT + (16 + l15) * 264 + q * 64 + ks * 32 + lg * 8);
      s0 = __builtin_amdgcn_mfma_f32_16x16x32_bf16(a, b0, s0, 0, 0, 0);
      s1 = __builtin_amdgcn_mfma_f32_16x16x32_bf16(a, b1, s1, 0, 0, 0);
    }
  }
  const bool m0 = mask[b * LL + l15] != 0;
  const bool m1 = mask[b * LL + 16 + l15] != 0;
  float a0[4], a1[4];
#pragma unroll
  for (int k = 0; k < 4; ++k) {
    float rn = rnL[w * 16 + lg * 4 + k];
    float v0 = m0 ? -INFINITY : s0[k] * rn;
    float v1 = m1 ? -INFINITY : s1[k] * rn;
    float mx = fmaxf(v0, v1);
#pragma unroll
    for (int o = 1; o < 16; o <<= 1) mx = fmaxf(mx, __shfl_xor(mx, o));
    float e0 = expf(v0 - mx), e1 = expf(v1 - mx);
    float sm = e0 + e1;
#pragma unroll
    for (int o = 1; o < 16; o <<= 1) sm += __shfl_xor(sm, o);
    float inv = 1.f / sm;
    a0[k] = e0 * inv; a1[k] = e1 * inv;
  }
  __syncthreads();  // imgT reads done; safe to overlay wdnC/attnB

  // ---- phase C: stage wdnC + attnB, ctx ----
  for (int i = tid; i < TD * LL; i += 256) {
    int t = i >> 5, l = i & 31;
    wdnC[t * 40 + l] = f2b(wb[i]);
  }
#pragma unroll
  for (int k = 0; k < 4; ++k) {
    int px = w * 16 + lg * 4 + k;
    attnB[px * 40 + l15] = f2b(a0[k]);
    attnB[px * 40 + 16 + l15] = f2b(a1[k]);
  }
  __syncthreads();
  f32x4 acc2[4][4] = {};
  bf16x8 bfr[4];
#pragma unroll
  for (int pt = 0; pt < 4; ++pt)
    bfr[pt] = *(const bf16x8*)(attnB + (pt * 16 + l15) * 40 + lg * 8);
#pragma unroll
  for (int cc = 0; cc < 4; ++cc) {
    bf16x8 a = *(const bf16x8*)(wdnC + ((w * 4 + cc) * 16 + l15) * 40 + lg * 8);
#pragma unroll
    for (int pt = 0; pt < 4; ++pt)
      acc2[cc][pt] = __builtin_amdgcn_mfma_f32_16x16x32_bf16(a, bfr[pt], acc2[cc][pt], 0, 0, 0);
  }
#pragma unroll
  for (int cc = 0; cc < 4; ++cc) {
#pragma unroll
    for (int pt = 0; pt < 4; ++pt) {
#pragma unroll
      for (int k = 0; k < 4; ++k) {
        int c = (w * 4 + cc) * 16 + lg * 4 + k;
        ctx[((size_t)b * TD + c) * P + p0 + pt * 16 + l15] = f2b(acc2[cc][pt][k]);
      }
    }
  }
}

// ---------------- bf16 MFMA GEMM, dbuf reg-staged ----------------
template <bool XB, bool YB>
__global__ __launch_bounds__(256, 2) void gemm_mfma_kernel(
    const float* __restrict__ W, int ldw, int c_off,
    const void* __restrict__ Xv, const float* __restrict__ vec,
    void* __restrict__ Yv, int T, int C, int P) {
  __shared__ u16 Wl[2][128 * 44];
  __shared__ u16 Xl[2][128 * 40];
  const int b = blockIdx.z;
  const int t0 = blockIdx.y * 128, p0 = blockIdx.x * 128;
  const int tid = threadIdx.x;
  const int w = tid >> 6, lane = tid & 63;
  const int wo = w >> 1, wq = w & 1;
  const int l15 = lane & 15, lg = lane >> 4;
  const int wr = tid >> 1, wcH = tid & 1;
  const int xr = tid >> 3, xcG = tid & 7;
  const int csw = xr ^ ((xcG & 3) << 3);
  const float* wsrc = W + (size_t)(t0 + wr) * ldw + c_off + wcH * 16;
  const float* xsrc32 = XB ? nullptr : (const float*)Xv + (size_t)b * C * P + (size_t)xr * P + p0 + xcG * 16;
  const u16* xsrc16 = XB ? (const u16*)Xv + (size_t)b * C * P + (size_t)xr * P + p0 + xcG * 16 : nullptr;
  const int NK = C / 32;
  f32x4 acc[4][4] = {};
  float4 wreg[4];
  u16 xst[16];

#pragma unroll
  for (int j = 0; j < 4; ++j) wreg[j] = *(const float4*)(wsrc + j * 4);
  if (XB) {
    union { u16 u[16]; uint4 q[2]; } xu;
    xu.q[0] = *(const uint4*)(xsrc16);
    xu.q[1] = *(const uint4*)(xsrc16 + 8);
#pragma unroll
    for (int i = 0; i < 16; ++i) xst[i] = xu.u[i];
  } else {
#pragma unroll
    for (int j = 0; j < 4; ++j) {
      float4 v = *(const float4*)(xsrc32 + j * 4);
      xst[j * 4 + 0] = f2b(v.x); xst[j * 4 + 1] = f2b(v.y);
      xst[j * 4 + 2] = f2b(v.z); xst[j * 4 + 3] = f2b(v.w);
    }
  }
  {
    u16* dst = Wl[0] + wr * 44 + wcH * 16;
#pragma unroll
    for (int j = 0; j < 4; ++j)
      *(ushort4*)(dst + j * 4) = make_ushort4(f2b(wreg[j].x), f2b(wreg[j].y), f2b(wreg[j].z), f2b(wreg[j].w));
#pragma unroll
    for (int i = 0; i < 16; ++i)
      Xl[0][(xcG * 16 + i) * 40 + csw] = xst[i];
  }
  __syncthreads();

  for (int kb = 0; kb < NK; ++kb) {
    const int cur = kb & 1;
    if (kb + 1 < NK) {
      const int c0n = (kb + 1) * 32;
#pragma unroll
      for (int j = 0; j < 4; ++j) wreg[j] = *(const float4*)(wsrc + c0n + j * 4);
      if (XB) {
        union { u16 u[16]; uint4 q[2]; } xu;
        xu.q[0] = *(const uint4*)(xsrc16 + (size_t)c0n * P);
        xu.q[1] = *(const uint4*)(xsrc16 + (size_t)c0n * P + 8);
#pragma unroll
        for (int i = 0; i < 16; ++i) xst[i] = xu.u[i];
      } else {
#pragma unroll
        for (int j = 0; j < 4; ++j) {
          float4 v = *(const float4*)(xsrc32 + (size_t)c0n * P + j * 4);
          xst[j * 4 + 0] = f2b(v.x); xst[j * 4 + 1] = f2b(v.y);
          xst[j * 4 + 2] = f2b(v.z); xst[j * 4 + 3] = f2b(v.w);
        }
      }
    }
    bf16x8 a[4], bb[4];
#pragma unroll
    for (int rr = 0; rr < 4; ++rr)
      a[rr] = *(const bf16x8*)(Wl[cur] + (wo * 64 + rr * 16 + l15) * 44 + lg * 8);
#pragma unroll
    for (int ss = 0; ss < 4; ++ss)
      bb[ss] = *(const bf16x8*)(Xl[cur] + (wq * 64 + ss * 16 + l15) * 40 + ((lg ^ ss) << 3));
#pragma unroll
    for (int rr = 0; rr < 4; ++rr)
#pragma unroll
      for (int ss = 0; ss < 4; ++ss)
        acc[rr][ss] = __builtin_amdgcn_mfma_f32_16x16x32_bf16(a[rr], bb[ss], acc[rr][ss], 0, 0, 0);
    if (kb + 1 < NK) {
      const int nxt = cur ^ 1;
      u16* dst = Wl[nxt] + wr * 44 + wcH * 16;
#pragma unroll
      for (int j = 0; j < 4; ++j)
        *(ushort4*)(dst + j * 4) = make_ushort4(f2b(wreg[j].x), f2b(wreg[j].y), f2b(wreg[j].z), f2b(wreg[j].w));
#pragma unroll
      for (int i = 0; i < 16; ++i)
        Xl[nxt][(xcG * 16 + i) * 40 + csw] = xst[i];
      __syncthreads();
    }
  }
#pragma unroll
  for (int rr = 0; rr < 4; ++rr) {
    int tb = t0 + wo * 64 + rr * 16 + lg * 4;
#pragma unroll
    for (int ss = 0; ss < 4; ++ss) {
      int p = p0 + wq * 64 + ss * 16 + l15;
#pragma unroll
      for (int k = 0; k < 4; ++k) {
        int t = tb + k;
        float val = acc[rr][ss][k];
        if (vec) val += vec[(size_t)b * T + t];
        if (YB) ((u16*)Yv)[((size_t)b * T + t) * P + p] = f2b(val);
        else    ((float*)Yv)[((size_t)b * T + t) * P + p] = val;
      }
    }
  }
}

// ---------------- fused gamma/beta GEMM + inline gvec + BN + ReLU + NHWC pack ----------------
template <bool XINB>
__global__ __launch_bounds__(256, 2) void gbact_kernel(
    const float* __restrict__ Wg, const float* __restrict__ bg,
    const float* __restrict__ Wb, const float* __restrict__ bb_,
    const u16* __restrict__ ctx, const float* __restrict__ gcond,
    const void* __restrict__ xinv,
    const float* __restrict__ mean, const float* __restrict__ rstd,
    const float* __restrict__ bnw, const float* __restrict__ bnb,
    u16* __restrict__ outb, int C, int P) {
  __shared__ u16 shmem[2][16384];
  __shared__ float gvl[128], bvl[128];
  const int b = blockIdx.z, t0 = blockIdx.y * 128, p0 = blockIdx.x * 128;
  const int tid = threadIdx.x;
  const int w = tid >> 6, lane = tid & 63;
  const int wo = w >> 1, wq = w & 1;
  const int l15 = lane & 15, lg = lane >> 4;
  const int wr = tid >> 1, wcH = tid & 1;
  const int xr = tid >> 3, xcG = tid & 7;
  const int csw = xr ^ ((xcG & 3) << 3);
  const float* gsrc = Wg + (size_t)(t0 + wr) * CONDC + GD + wcH * 16;
  const float* bsrc = Wb + (size_t)(t0 + wr) * CONDC + GD + wcH * 16;
  const u16* xsrc = ctx + (size_t)b * TD * P + (size_t)xr * P + p0 + xcG * 16;
  const int NK = TD / 32;
  f32x4 accg[4][4] = {}, accb[4][4] = {};
  float4 greg[4], breg[4];
  u16 xst[16];

  {
    int t = tid & 127;
    const float* row = (tid < 128 ? Wg : Wb) + (size_t)(t0 + t) * CONDC;
    const float* gc = gcond + (size_t)b * GD;
    float s = 0.f;
    for (int c = 0; c < GD; c += 4) {
      float4 wv = *(const float4*)(row + c);
      float4 gv4 = *(const float4*)(gc + c);
      s += wv.x * gv4.x + wv.y * gv4.y + wv.z * gv4.z + wv.w * gv4.w;
    }
    s += (tid < 128 ? bg : bb_)[t0 + t];
    if (tid < 128) gvl[t] = s; else bvl[t] = s;
  }

#pragma unroll
  for (int j = 0; j < 4; ++j) {
    greg[j] = *(const float4*)(gsrc + j * 4);
    breg[j] = *(const float4*)(bsrc + j * 4);
  }
  {
    union { u16 u[16]; uint4 q[2]; } xu;
    xu.q[0] = *(const uint4*)(xsrc);
    xu.q[1] = *(const uint4*)(xsrc + 8);
#pragma unroll
    for (int i = 0; i < 16; ++i) xst[i] = xu.u[i];
  }
  {
    u16* dg = shmem[0] + wr * 44 + wcH * 16;
    u16* db = shmem[0] + 5632 + wr * 44 + wcH * 16;
    u16* xl = shmem[0] + 11264;
#pragma unroll
    for (int j = 0; j < 4; ++j) {
      *(ushort4*)(dg + j * 4) = make_ushort4(f2b(greg[j].x), f2b(greg[j].y), f2b(greg[j].z), f2b(greg[j].w));
      *(ushort4*)(db + j * 4) = make_ushort4(f2b(breg[j].x), f2b(breg[j].y), f2b(breg[j].z), f2b(breg[j].w));
    }
#pragma unroll
    for (int i = 0; i < 16; ++i)
      xl[(xcG * 16 + i) * 40 + csw] = xst[i];
  }
  __syncthreads();

  for (int kb = 0; kb < NK; ++kb) {
    const int cur = kb & 1;
    if (kb + 1 < NK) {
      const int c0n = (kb + 1) * 32;
#pragma unroll
      for (int j = 0; j < 4; ++j) {
        greg[j] = *(const float4*)(gsrc + c0n + j * 4);
        breg[j] = *(const float4*)(bsrc + c0n + j * 4);
      }
      union { u16 u[16]; uint4 q[2]; } xu;
      xu.q[0] = *(const uint4*)(xsrc + (size_t)c0n * P);
      xu.q[1] = *(const uint4*)(xsrc + (size_t)c0n * P + 8);
#pragma unroll
      for (int i = 0; i < 16; ++i) xst[i] = xu.u[i];
    }
    bf16x8 ag[4], ab[4], bb[4];
#pragma unroll
    for (int rr = 0; rr < 4; ++rr) {
      ag[rr] = *(const bf16x8*)(shmem[cur] + (wo * 64 + rr * 16 + l15) * 44 + lg * 8);
      ab[rr] = *(const bf16x8*)(shmem[cur] + 5632 + (wo * 64 + rr * 16 + l15) * 44 + lg * 8);
    }
#pragma unroll
    for (int ss = 0; ss < 4; ++ss)
      bb[ss] = *(const bf16x8*)(shmem[cur] + 11264 + (wq * 64 + ss * 16 + l15) * 40 + ((lg ^ ss) << 3));
#pragma unroll
    for (int rr = 0; rr < 4; ++rr)
#pragma unroll
      for (int ss = 0; ss < 4; ++ss) {
        accg[rr][ss] = __builtin_amdgcn_mfma_f32_16x16x32_bf16(ag[rr], bb[ss], accg[rr][ss], 0, 0, 0);
        accb[rr][ss] = __builtin_amdgcn_mfma_f32_16x16x32_bf16(ab[rr], bb[ss], accb[rr][ss], 0, 0, 0);
      }
    if (kb + 1 < NK) {
      const int nxt = cur ^ 1;
      u16* dg = shmem[nxt] + wr * 44 + wcH * 16;
      u16* db = shmem[nxt] + 5632 + wr * 44 + wcH * 16;
      u16* xl = shmem[nxt] + 11264;
#pragma unroll
      for (int j = 0; j < 4; ++j) {
        *(ushort4*)(dg + j * 4) = make_ushort4(f2b(greg[j].x), f2b(greg[j].y), f2b(greg[j].z), f2b(greg[j].w));
        *(ushort4*)(db + j * 4) = make_ushort4(f2b(breg[j].x), f2b(breg[j].y), f2b(breg[j].z), f2b(breg[j].w));
      }
#pragma unroll
      for (int i = 0; i < 16; ++i)
        xl[(xcG * 16 + i) * 40 + csw] = xst[i];
      __syncthreads();
    }
  }
  __syncthreads();
  u16* tbuf = &shmem[0][0];
#pragma unroll
  for (int rr = 0; rr < 4; ++rr) {
    float gv[4], bv[4], mm[4], rs[4], bB[4];
#pragma unroll
    for (int k = 0; k < 4; ++k) {
      int cl = wo * 64 + rr * 16 + lg * 4 + k;
      int c = t0 + cl;
      gv[k] = gvl[cl];
      bv[k] = bvl[cl];
      mm[k] = mean[c]; rs[k] = rstd[c] * bnw[c]; bB[k] = bnb[c];
    }
#pragma unroll
    for (int ss = 0; ss < 4; ++ss) {
#pragma unroll
      for (int k = 0; k < 4; ++k) {
        int cl = wo * 64 + rr * 16 + lg * 4 + k;
        int pl = wq * 64 + ss * 16 + l15;
        size_t xidx = ((size_t)b * C + t0 + cl) * P + p0 + pl;
        float xv = XINB ? b2f(((const u16*)xinv)[xidx]) : ((const float*)xinv)[xidx];
        float g = accg[rr][ss][k] + gv[k];
        float be = accb[rr][ss][k] + bv[k];
        float val = fmaxf(g * ((xv - mm[k]) * rs[k] + bB[k]) + be, 0.f);
        tbuf[pl * 136 + cl] = f2b(val);
      }
    }
  }
  __syncthreads();
  const int pr = tid >> 1, h = tid & 1;
#pragma unroll
  for (int j = 0; j < 8; ++j) {
    uint4 v = *(uint4*)(tbuf + pr * 136 + h * 64 + j * 8);
    *(uint4*)(outb + ((size_t)b * P + p0 + pr) * C + t0 + h * 64 + j * 8) = v;
  }
}

// ---------------- pack conv weights + W2 (img2 weights) fragment-linear bf16 ----------------
__global__ void pack3_kernel(const float* __restrict__ w1, u16* __restrict__ wp1,
                             const float* __restrict__ w2, u16* __restrict__ wp2,
                             const float* __restrict__ wi2, u16* __restrict__ w2p) {
  int lin = blockIdx.x * 256 + threadIdx.x;
  const int N1 = COUT * CIN1;
  const int N2 = COUT * COUT;
  if (lin < N1 + N2) {
    const float* w; u16* wp; int CIN;
    if (lin < N1) { w = w1; wp = wp1; CIN = CIN1; }
    else { lin -= N1; w = w2; wp = wp2; CIN = COUT; }
    int o = lin / CIN, c = lin - o * CIN;
    int c0blk = c >> 5, lg = (c >> 3) & 3, cc = c & 7;
    int ot = o >> 4, l15 = o & 15;
    int lane = lg * 16 + l15;
    size_t base = (((size_t)c0blk * (COUT >> 4) + ot) * 64 + lane) * 8 + cc;
    size_t posStride = (size_t)(CIN >> 5) * (COUT >> 4) * 512;
    const float* src = w + ((size_t)o * CIN + c) * 9;
#pragma unroll
    for (int pos = 0; pos < 9; ++pos)
      wp[pos * posStride + base] = f2b(src[pos]);
  } else {
    lin -= N1 + N2;
    if (lin >= COUT * COUT) return;
    int t = lin >> 8, c = lin & 255;
    int tt = t >> 4, l15 = t & 15;
    int c0b = c >> 5, lg = (c >> 3) & 3, cc = c & 7;
    w2p[(((size_t)c0b * 16 + tt) * 64 + lg * 16 + l15) * 8 + cc] = f2b(wi2[(size_t)t * COUT + c]);
  }
}

// ---------------- bf16 MFMA implicit-GEMM 3x3 conv (8-wave, optional fused BN stats) ----------------
template <int CIN, bool UP, bool OUTB, bool STATS>
__global__ __launch_bounds__(512, 2) void conv_mfma_kernel(
    const u16* __restrict__ Wp, const u16* __restrict__ Xt,
    const u16* __restrict__ scs, const float* __restrict__ scb,
    void* __restrict__ Yv, float* __restrict__ part) {
  constexpr int S = UP ? 32 : 64;
  constexpr int NC0 = CIN >> 5;
  constexpr int NCH = 6 * 66 * 8;
  __shared__ u16 Xs[2][6 * 66 * 36];
  __shared__ float stats_ls[256], stats_lsq[256];
  const int b = blockIdx.z, pxT = blockIdx.x;
  const int tid = threadIdx.x;
  const int w = tid >> 6, lane = tid & 63;
  const int wo = w >> 2, wp_ = w & 3;
  const int l15 = lane & 15, lg = lane >> 4;
  const int Y0 = pxT * 4;
  const u16* Xb = Xt + (size_t)b * S * S * CIN;
  const size_t posStride = (size_t)NC0 * 16 * 512;
  f32x4 acc[8][4] = {};
  uint2 st[7];

  if (STATS && tid < 256) { stats_ls[tid] = 0.f; stats_lsq[tid] = 0.f; }

#pragma unroll
  for (int j = 0; j < 7; ++j) {
    int i = tid + j * 512;
    if (i < NCH) {
      int r = i / 528, rem = i - r * 528, col = rem >> 3, ch = rem & 7;
      int uy = Y0 - 1 + r, ux = col - 1;
      uint2 v = make_uint2(0u, 0u);
      if (uy >= 0 && uy < 64 && ux >= 0 && ux < 64) {
        int sy = UP ? (uy >> 1) : uy, sx = UP ? (ux >> 1) : ux;
        v = *(const uint2*)(Xb + ((size_t)sy * S + sx) * CIN + ch * 4);
      }
      st[j] = v;
    }
  }
#pragma unroll
  for (int j = 0; j < 7; ++j) {
    int i = tid + j * 512;
    if (i < NCH) {
      int r = i / 528, rem = i - r * 528, col = rem >> 3, ch = rem & 7;
      *(uint2*)(&Xs[0][(r * 66 + col) * 36 + ch * 4]) = st[j];
    }
  }
  __syncthreads();

  for (int c0b = 0; c0b < NC0; ++c0b) {
    const int cur = c0b & 1;
    if (c0b + 1 < NC0) {
      const int c0n = (c0b + 1) << 5;
#pragma unroll
      for (int j = 0; j < 7; ++j) {
        int i = tid + j * 512;
        if (i < NCH) {
          int r = i / 528, rem = i - r * 528, col = rem >> 3, ch = rem & 7;
          int uy = Y0 - 1 + r, ux = col - 1;
          uint2 v = make_uint2(0u, 0u);
          if (uy >= 0 && uy < 64 && ux >= 0 && ux < 64) {
            int sy = UP ? (uy >> 1) : uy, sx = UP ? (ux >> 1) : ux;
            v = *(const uint2*)(Xb + ((size_t)sy * S + sx) * CIN + c0n + ch * 4);
          }
          st[j] = v;
        }
      }
    }
    {
      const u16* wbB = Wp + ((size_t)c0b * 16 + wo * 8) * 512 + lane * 8;
      bf16x8 aC[8], aN[8];
#pragma unroll
      for (int rr = 0; rr < 8; ++rr)
        aC[rr] = *(const bf16x8*)(wbB + rr * 512);
#pragma unroll
      for (int pos = 0; pos < 9; ++pos) {
        const int ky = pos / 3, kx = pos - ky * 3;
        if (pos < 8) {
          const u16* wbn = wbB + (size_t)(pos + 1) * posStride;
#pragma unroll
          for (int rr = 0; rr < 8; ++rr)
            aN[rr] = *(const bf16x8*)(wbn + rr * 512);
        }
        const int rowb = ((wp_ + ky) * 66 + kx) * 36 + lg * 8;
#pragma unroll
        for (int ss = 0; ss < 4; ++ss) {
          int idx = rowb + (ss * 16 + l15) * 36;
          union { uint2 q[2]; bf16x8 v; } u;
          u.q[0] = *(const uint2*)(&Xs[cur][idx]);
          u.q[1] = *(const uint2*)(&Xs[cur][idx + 4]);
#pragma unroll
          for (int rr = 0; rr < 8; ++rr)
            acc[rr][ss] = __builtin_amdgcn_mfma_f32_16x16x32_bf16(aC[rr], u.v, acc[rr][ss], 0, 0, 0);
        }
#pragma unroll
        for (int rr = 0; rr < 8; ++rr) aC[rr] = aN[rr];
      }
    }
    if (c0b + 1 < NC0) {
#pragma unroll
      for (int j = 0; j < 7; ++j) {
        int i = tid + j * 512;
        if (i < NCH) {
          int r = i / 528, rem = i - r * 528, col = rem >> 3, ch = rem & 7;
          *(uint2*)(&Xs[cur ^ 1][(r * 66 + col) * 36 + ch * 4]) = st[j];
        }
      }
      __syncthreads();
    }
  }
  const int oBase = wo * 128 + lg * 4;
  const int pxBase = pxT * 256 + wp_ * 64 + l15;
  const int y = Y0 + wp_;
#pragma unroll
  for (int rr = 0; rr < 8; ++rr) {
#pragma unroll
    for (int ss = 0; ss < 4; ++ss) {
      int px = pxBase + ss * 16;
#pragma unroll
      for (int k = 0; k < 4; ++k) {
        int o = oBase + rr * 16 + k;
        float val = acc[rr][ss][k];
        if (scs) {
          int gx = px & 63;
          val += b2f(scs[((size_t)b * COUT + o) * P1 + (y >> 1) * 32 + (gx >> 1)]) + scb[o];
        }
        if (OUTB) ((u16*)Yv)[((size_t)b * COUT + o) * 4096 + px] = f2b(val);
        else      ((float*)Yv)[((size_t)b * COUT + o) * 4096 + px] = val;
      }
    }
  }
  if (STATS) {
#pragma unroll
    for (int rr = 0; rr < 8; ++rr) {
#pragma unroll
      for (int k = 0; k < 4; ++k) {
        float s = acc[rr][0][k] + acc[rr][1][k] + acc[rr][2][k] + acc[rr][3][k];
        float sq = acc[rr][0][k] * acc[rr][0][k] + acc[rr][1][k] * acc[rr][1][k] +
                   acc[rr][2][k] * acc[rr][2][k] + acc[rr][3][k] * acc[rr][3][k];
#pragma unroll
        for (int o = 1; o < 16; o <<= 1) { s += __shfl_xor(s, o); sq += __shfl_xor(sq, o); }
        if (l15 == 0) {
          int o_ = oBase + rr * 16 + k;
          atomicAdd(&stats_ls[o_], s);
          atomicAdd(&stats_lsq[o_], sq);
        }
      }
    }
    __syncthreads();
    if (tid < 256) {
      int blk = b * 16 + pxT;
      part[(size_t)tid * 256 + blk] = stats_ls[tid];
      part[65536 + (size_t)tid * 256 + blk] = stats_lsq[tid];
    }
  }
}

extern "C" void kernel_launch(void* const* d_in, const int* in_sizes, int n_in,
                              void* d_out, int out_size, void* d_ws, size_t ws_size,
                              hipStream_t stream) {
  const float* x      = (const float*)d_in[0];
  const float* gcond  = (const float*)d_in[1];
  const float* wemb   = (const float*)d_in[2];
  const int*   mask   = (const int*)d_in[3];
  const float* w_img1 = (const float*)d_in[4];
  const float* w_img2 = (const float*)d_in[5];
  const float* w_c1   = (const float*)d_in[6];
  const float* w_c2   = (const float*)d_in[7];
  const float* bn1_w  = (const float*)d_in[8];
  const float* bn1_b  = (const float*)d_in[9];
  const float* bn2_w  = (const float*)d_in[10];
  const float* bn2_b  = (const float*)d_in[11];
  const float* w_g1   = (const float*)d_in[12];
  const float* b_g1   = (const float*)d_in[13];
  const float* w_b1   = (const float*)d_in[14];
  const float* b_b1   = (const float*)d_in[15];
  const float* w_g2   = (const float*)d_in[16];
  const float* b_g2   = (const float*)d_in[17];
  const float* w_b2   = (const float*)d_in[18];
  const float* b_b2   = (const float*)d_in[19];
  const float* w_sc   = (const float*)d_in[20];
  const float* b_sc   = (const float*)d_in[21];
  float* out = (float*)d_out;
  float* ws = (float*)d_ws;

  const size_t MF = 16777216;  // floats per 64MB region
  float* A  = ws;
  float* Br = ws + MF;
  float* Cr = ws + 2 * MF;
  float* SM = ws + 3 * MF;
  float* wdn   = SM;                     // 131072
  float* mean1 = SM + 131072;
  float* rstd1 = mean1 + 512;
  float* mean2 = rstd1 + 512;
  float* rstd2 = mean2 + 256;
  float* part  = rstd2 + 256;            // 131072
  float* wsp   = part + 131072;
  u16* Wp1 = (u16*)wsp;                       // 9*256*512 u16
  u16* Wp2 = (u16*)(wsp + 655360);            // 9*256*256 u16
  u16* scs = (u16*)(wsp + 655360 + 294912);   // 4.2M u16 (bf16 shortcut)
  u16* W2p = (u16*)(wsp + 655360 + 294912 + 2097152);  // 64K u16 (img2 weights)

  u16* img1   = (u16*)A;                 // 4.2M u16
  u16* ctx1   = (u16*)A + 4194304;       // 4.2M u16
  u16* Xt1    = (u16*)A + 8388608;       // 8.4M u16 NHWC bf16
  u16* xbf    = (u16*)A + 16777216;      // 8.4M u16 (bf16 copy of x)
  u16* conv1o = (u16*)Cr;                // 16.8M u16 NCHW bf16
  u16* ctx2   = (u16*)A;                 // reuse (A dead after conv1 + shortcut)
  u16* Xt2    = (u16*)Br;                // reuse

  // ---- stage 1 ----
  bn_stats_x_kernel<<<dim3(CIN1), dim3(256), 0, stream>>>(x, mean1, rstd1, xbf, CIN1, P1);
  wdn_kernel<<<dim3(NB * LL), dim3(64), 0, stream>>>(wemb, wdn);
  pack3_kernel<<<dim3((COUT * CIN1 + 2 * COUT * COUT + 255) / 256), dim3(256), 0, stream>>>(
      w_c1, Wp1, w_c2, Wp2, w_img2, W2p);
  gemm_mfma_kernel<true, true><<<dim3(P1 / 128, TD / 128, NB), dim3(256), 0, stream>>>(
      w_img1, CIN1, 0, xbf, nullptr, img1, TD, CIN1, P1);
  gemm_mfma_kernel<true, true><<<dim3(P1 / 128, COUT / 128, NB), dim3(256), 0, stream>>>(
      w_sc, CIN1, 0, xbf, nullptr, scs, COUT, CIN1, P1);
  attnctx_kernel<<<dim3(P1 / 64, NB), dim3(256), 0, stream>>>(img1, wdn, mask, ctx1, P1);
  gbact_kernel<true><<<dim3(P1 / 128, CIN1 / 128, NB), dim3(256), 0, stream>>>(
      w_g1, b_g1, w_b1, b_b1, ctx1, gcond, xbf, mean1, rstd1, bn1_w, bn1_b, Xt1, CIN1, P1);
  conv_mfma_kernel<CIN1, true, true, true><<<dim3(16, 1, NB), dim3(512), 0, stream>>>(
      Wp1, Xt1, nullptr, nullptr, conv1o, part);

  // ---- stage 2 ----
  bn_fin_kernel<<<dim3(1), dim3(256), 0, stream>>>(part, mean2, rstd2);
  attnimg_kernel<<<dim3(P2 / 64, NB), dim3(256), 0, stream>>>(
      W2p, conv1o, wdn, mask, ctx2, P2);
  gbact_kernel<true><<<dim3(P2 / 128, COUT / 128, NB), dim3(256), 0, stream>>>(
      w_g2, b_g2, w_b2, b_b2, ctx2, gcond, conv1o, mean2, rstd2, bn2_w, bn2_b, Xt2, COUT, P2);
  conv_mfma_kernel<COUT, false, false, false><<<dim3(16, 1, NB), dim3(512), 0, stream>>>(
      Wp2, Xt2, scs, b_sc, out, nullptr);
}

// Round 19
// 448.052 us; speedup vs baseline: 1.5401x; 1.0223x over previous
//
#include <hip/hip_runtime.h>
#include <hip/hip_bf16.h>
#include <math.h>

#define NB 16
#define CIN1 512
#define COUT 256
#define GD 256
#define TD 256
#define LL 32
#define P1 1024
#define P2 4096
#define CONDC 512

typedef __attribute__((ext_vector_type(8))) short bf16x8;
typedef __attribute__((ext_vector_type(4))) float f32x4;
typedef unsigned short u16;

__device__ __forceinline__ u16 f2b(float f) {
  __hip_bfloat16 h = __float2bfloat16(f);
  return *(u16*)&h;
}
__device__ __forceinline__ float b2f(u16 v) {
  unsigned u = ((unsigned)v) << 16;
  float f;
  __builtin_memcpy(&f, &u, 4);
  return f;
}

// ---------------- merged prelude: BN1 stats + x->bf16 | wdn | weight packing ----------------
__global__ void prelude_kernel(const float* __restrict__ x, float* __restrict__ mean,
                               float* __restrict__ rstd, u16* __restrict__ xbf,
                               const float* __restrict__ we, float* __restrict__ wdn,
                               const float* __restrict__ w1, u16* __restrict__ wp1,
                               const float* __restrict__ w2, u16* __restrict__ wp2,
                               const float* __restrict__ wi2, u16* __restrict__ w2p) {
  const int bid = blockIdx.x;
  if (bid < CIN1) {
    // --- BN1 stats + bf16 emit, c = bid ---
    int c = bid, t = threadIdx.x;
    float s = 0.f, sq = 0.f;
    for (int b = 0; b < NB; ++b) {
      size_t base = ((size_t)b * CIN1 + c) * P1;
      for (int i = t; i < P1; i += 256) {
        float v = x[base + i];
        s += v; sq += v * v;
        xbf[base + i] = f2b(v);
      }
    }
    __shared__ float ss[256], sq2[256];
    ss[t] = s; sq2[t] = sq; __syncthreads();
    for (int o = 128; o > 0; o >>= 1) {
      if (t < o) { ss[t] += ss[t + o]; sq2[t] += sq2[t + o]; }
      __syncthreads();
    }
    if (t == 0) {
      float n = (float)NB * (float)P1;
      float m = ss[0] / n;
      float v = sq2[0] / n - m * m;
      mean[c] = m;
      rstd[c] = rsqrtf(v + 1e-5f);
    }
  } else if (bid < CIN1 + 128) {
    // --- wdn: 4 (b,l) pairs per block, one wave each ---
    int g = (bid - CIN1) * 4 + (threadIdx.x >> 6);
    int b = g >> 5, l = g & 31;
    int t = threadIdx.x & 63;
    const float* base = we + (size_t)b * TD * LL + l;
    float v[4]; float sq = 0.f;
#pragma unroll
    for (int k = 0; k < 4; ++k) { v[k] = base[(size_t)(t * 4 + k) * LL]; sq += v[k] * v[k]; }
#pragma unroll
    for (int o = 32; o > 0; o >>= 1) sq += __shfl_xor(sq, o);
    float r = 1.f / fmaxf(sqrtf(sq), 1e-12f);
    float* ob = wdn + (size_t)b * TD * LL + l;
#pragma unroll
    for (int k = 0; k < 4; ++k) ob[(size_t)(t * 4 + k) * LL] = v[k] * r;
  } else {
    // --- weight packing ---
    int lin = (bid - CIN1 - 128) * 256 + threadIdx.x;
    const int N1 = COUT * CIN1;
    const int N2 = COUT * COUT;
    if (lin < N1 + N2) {
      const float* w; u16* wp; int CIN;
      if (lin < N1) { w = w1; wp = wp1; CIN = CIN1; }
      else { lin -= N1; w = w2; wp = wp2; CIN = COUT; }
      int o = lin / CIN, c = lin - o * CIN;
      int c0blk = c >> 5, lg = (c >> 3) & 3, cc = c & 7;
      int ot = o >> 4, l15 = o & 15;
      int lane = lg * 16 + l15;
      size_t base = (((size_t)c0blk * (COUT >> 4) + ot) * 64 + lane) * 8 + cc;
      size_t posStride = (size_t)(CIN >> 5) * (COUT >> 4) * 512;
      const float* src = w + ((size_t)o * CIN + c) * 9;
#pragma unroll
      for (int pos = 0; pos < 9; ++pos)
        wp[pos * posStride + base] = f2b(src[pos]);
    } else {
      lin -= N1 + N2;
      if (lin >= COUT * COUT) return;
      int t = lin >> 8, c = lin & 255;
      int tt = t >> 4, l15 = t & 15;
      int c0b = c >> 5, lg = (c >> 3) & 3, cc = c & 7;
      w2p[(((size_t)c0b * 16 + tt) * 64 + lg * 16 + l15) * 8 + cc] = f2b(wi2[(size_t)t * COUT + c]);
    }
  }
}

// ---------------- finalize conv1-fused BN2 stats ----------------
__global__ void bn_fin_kernel(const float* __restrict__ part, float* __restrict__ mean,
                              float* __restrict__ rstd) {
  int c = threadIdx.x;  // 256
  float s = 0.f, sq = 0.f;
  const float* ps = part + (size_t)c * 256;
  const float* pq = part + 65536 + (size_t)c * 256;
  for (int i = 0; i < 256; ++i) { s += ps[i]; sq += pq[i]; }
  float n = 16.f * 4096.f;
  float m = s / n;
  mean[c] = m;
  rstd[c] = rsqrtf(sq / n - m * m + 1e-5f);
}

// ---------------- stage-1 fused attention (bf16 img in, bf16 ctx out), dbuf imgT ----------------
__global__ __launch_bounds__(256) void attnctx_kernel(
    const u16* __restrict__ img, const float* __restrict__ wdn,
    const int* __restrict__ mask, u16* __restrict__ ctx, int P) {
  __shared__ u16 imgT[2][64 * 72];
  __shared__ u16 wdnT[32 * 264];
  __shared__ u16 wdnC[256 * 40];
  __shared__ u16 attnB[64 * 40];
  __shared__ float sqP[4][64];
  __shared__ float rnL[64];
  const int b = blockIdx.y, p0 = blockIdx.x * 64;
  const int tid = threadIdx.x;
  const int w = tid >> 6, lane = tid & 63;
  const int l15 = lane & 15, lg = lane >> 4;
  const u16* ib = img + (size_t)b * TD * P;
  const float* wb = wdn + (size_t)b * TD * LL;

  for (int i = tid; i < TD * LL; i += 256) {
    int t = i >> 5, l = i & 31;
    u16 v = f2b(wb[i]);
    wdnT[l * 264 + t] = v;
    wdnC[t * 40 + l] = v;
  }

  f32x4 s0 = {}, s1 = {};
  float ssq = 0.f;
  unsigned pk[8];
#pragma unroll
  for (int i = 0; i < 8; ++i) {
    int t = w * 16 + 2 * i;
    u16 h0 = ib[(size_t)t * P + p0 + lane];
    u16 h1 = ib[(size_t)(t + 1) * P + p0 + lane];
    float v0 = b2f(h0), v1 = b2f(h1);
    ssq += v0 * v0 + v1 * v1;
    pk[i] = (unsigned)h0 | ((unsigned)h1 << 16);
  }
#pragma unroll
  for (int i = 0; i < 8; ++i)
    *(unsigned*)(imgT[0] + lane * 72 + w * 16 + 2 * i) = pk[i];
  __syncthreads();

  for (int q = 0; q < 4; ++q) {
    const int cur = q & 1;
    if (q < 3) {
#pragma unroll
      for (int i = 0; i < 8; ++i) {
        int t = (q + 1) * 64 + w * 16 + 2 * i;
        u16 h0 = ib[(size_t)t * P + p0 + lane];
        u16 h1 = ib[(size_t)(t + 1) * P + p0 + lane];
        float v0 = b2f(h0), v1 = b2f(h1);
        ssq += v0 * v0 + v1 * v1;
        pk[i] = (unsigned)h0 | ((unsigned)h1 << 16);
      }
    }
#pragma unroll
    for (int ks = 0; ks < 2; ++ks) {
      bf16x8 a = *(const bf16x8*)(imgT[cur] + (w * 16 + l15) * 72 + ks * 32 + lg * 8);
      bf16x8 b0 = *(const bf16x8*)(wdnT + l15 * 264 + q * 64 + ks * 32 + lg * 8);
      bf16x8 b1 = *(const bf16x8*)(wdnT + (16 + l15) * 264 + q * 64 + ks * 32 + lg * 8);
      s0 = __builtin_amdgcn_mfma_f32_16x16x32_bf16(a, b0, s0, 0, 0, 0);
      s1 = __builtin_amdgcn_mfma_f32_16x16x32_bf16(a, b1, s1, 0, 0, 0);
    }
    if (q < 3) {
#pragma unroll
      for (int i = 0; i < 8; ++i)
        *(unsigned*)(imgT[cur ^ 1] + lane * 72 + w * 16 + 2 * i) = pk[i];
      __syncthreads();
    }
  }
  sqP[w][lane] = ssq;
  __syncthreads();
  if (tid < 64) {
    float s = sqP[0][tid] + sqP[1][tid] + sqP[2][tid] + sqP[3][tid];
    rnL[tid] = 1.f / fmaxf(sqrtf(s), 1e-12f);
  }
  __syncthreads();
  const bool m0 = mask[b * LL + l15] != 0;
  const bool m1 = mask[b * LL + 16 + l15] != 0;
#pragma unroll
  for (int k = 0; k < 4; ++k) {
    float rn = rnL[w * 16 + lg * 4 + k];
    float v0 = m0 ? -INFINITY : s0[k] * rn;
    float v1 = m1 ? -INFINITY : s1[k] * rn;
    float mx = fmaxf(v0, v1);
#pragma unroll
    for (int o = 1; o < 16; o <<= 1) mx = fmaxf(mx, __shfl_xor(mx, o));
    float e0 = expf(v0 - mx), e1 = expf(v1 - mx);
    float sm = e0 + e1;
#pragma unroll
    for (int o = 1; o < 16; o <<= 1) sm += __shfl_xor(sm, o);
    float inv = 1.f / sm;
    int px = w * 16 + lg * 4 + k;
    attnB[px * 40 + l15] = f2b(e0 * inv);
    attnB[px * 40 + 16 + l15] = f2b(e1 * inv);
  }
  __syncthreads();
  f32x4 acc[4][4] = {};
  bf16x8 bfr[4];
#pragma unroll
  for (int pt = 0; pt < 4; ++pt)
    bfr[pt] = *(const bf16x8*)(attnB + (pt * 16 + l15) * 40 + lg * 8);
#pragma unroll
  for (int cc = 0; cc < 4; ++cc) {
    bf16x8 a = *(const bf16x8*)(wdnC + ((w * 4 + cc) * 16 + l15) * 40 + lg * 8);
#pragma unroll
    for (int pt = 0; pt < 4; ++pt)
      acc[cc][pt] = __builtin_amdgcn_mfma_f32_16x16x32_bf16(a, bfr[pt], acc[cc][pt], 0, 0, 0);
  }
#pragma unroll
  for (int cc = 0; cc < 4; ++cc) {
#pragma unroll
    for (int pt = 0; pt < 4; ++pt) {
#pragma unroll
      for (int k = 0; k < 4; ++k) {
        int c = (w * 4 + cc) * 16 + lg * 4 + k;
        ctx[((size_t)b * TD + c) * P + p0 + pt * 16 + l15] = f2b(acc[cc][pt][k]);
      }
    }
  }
}

// ---------------- stage-2 fused img-GEMM + attention + ctx ----------------
__global__ __launch_bounds__(256) void attnimg_kernel(
    const u16* __restrict__ W2p, const u16* __restrict__ xin,
    const float* __restrict__ wdn, const int* __restrict__ mask,
    u16* __restrict__ ctx, int P) {
  __shared__ u16 smem[(33792 + 16896) / 2];
  __shared__ float rnL[64];
  u16* imgT  = smem;
  u16* Xl    = smem + 16896;
  u16* wdnT  = smem + 16896;
  u16* wdnC  = smem;
  u16* attnB = smem + 10240;
  const int b = blockIdx.y, p0 = blockIdx.x * 64;
  const int tid = threadIdx.x;
  const int w = tid >> 6, lane = tid & 63;
  const int l15 = lane & 15, lg = lane >> 4;
  const u16* xb = xin + (size_t)b * COUT * P;
  const float* wb = wdn + (size_t)b * TD * LL;

  const int xr = tid >> 3, xcG = tid & 7;
  const int csw = xr ^ (((xcG >> 1) & 3) << 3);
  const u16* xsrc = xb + (size_t)xr * P + p0 + xcG * 8;
  u16 xst[8];
  {
    union { u16 u[8]; uint4 q; } xu;
    xu.q = *(const uint4*)xsrc;
#pragma unroll
    for (int i = 0; i < 8; ++i) xst[i] = xu.u[i];
  }
#pragma unroll
  for (int i = 0; i < 8; ++i)
    Xl[(xcG * 8 + i) * 40 + csw] = xst[i];
  __syncthreads();

  f32x4 acc[16];
#pragma unroll
  for (int tt = 0; tt < 16; ++tt) acc[tt] = (f32x4){0.f, 0.f, 0.f, 0.f};
  for (int c0b = 0; c0b < 8; ++c0b) {
    const int cur = c0b & 1;
    if (c0b + 1 < 8) {
      union { u16 u[8]; uint4 q; } xu;
      xu.q = *(const uint4*)(xsrc + (size_t)((c0b + 1) * 32) * P);
#pragma unroll
      for (int i = 0; i < 8; ++i) xst[i] = xu.u[i];
    }
    bf16x8 aA = *(const bf16x8*)(Xl + cur * 2560 + (w * 16 + l15) * 40 + ((lg ^ w) << 3));
#pragma unroll
    for (int tt = 0; tt < 16; ++tt) {
      bf16x8 bfr = *(const bf16x8*)(W2p + (((size_t)c0b * 16 + tt) * 64 + lane) * 8);
      acc[tt] = __builtin_amdgcn_mfma_f32_16x16x32_bf16(aA, bfr, acc[tt], 0, 0, 0);
    }
    if (c0b + 1 < 8) {
      const int nxt = cur ^ 1;
#pragma unroll
      for (int i = 0; i < 8; ++i)
        Xl[nxt * 2560 + (xcG * 8 + i) * 40 + csw] = xst[i];
      __syncthreads();
    }
  }
#pragma unroll
  for (int k = 0; k < 4; ++k) {
    float s = 0.f;
#pragma unroll
    for (int tt = 0; tt < 16; ++tt) s += acc[tt][k] * acc[tt][k];
#pragma unroll
    for (int o = 1; o < 16; o <<= 1) s += __shfl_xor(s, o);
    if (l15 == 0) rnL[w * 16 + lg * 4 + k] = 1.f / fmaxf(sqrtf(s), 1e-12f);
  }
#pragma unroll
  for (int tt = 0; tt < 16; ++tt)
#pragma unroll
    for (int k = 0; k < 4; ++k)
      imgT[(w * 16 + lg * 4 + k) * 264 + tt * 16 + l15] = f2b(acc[tt][k]);
  __syncthreads();

  for (int i = tid; i < TD * LL; i += 256) {
    int t = i >> 5, l = i & 31;
    wdnT[l * 264 + t] = f2b(wb[i]);
  }
  __syncthreads();
  f32x4 s0 = {}, s1 = {};
#pragma unroll
  for (int q = 0; q < 4; ++q) {
#pragma unroll
    for (int ks = 0; ks < 2; ++ks) {
      bf16x8 a = *(const bf16x8*)(imgT + (w * 16 + l15) * 264 + q * 64 + ks * 32 + lg * 8);
      bf16x8 b0 = *(const bf16x8*)(wdnT + l15 * 264 + q * 64 + ks * 32 + lg * 8);
      bf16x8 b1 = *(const bf16x8*)(wdnT + (16 + l15) * 264 + q * 64 + ks * 32 + lg * 8);
      s0 = __builtin_amdgcn_mfma_f32_16x16x32_bf16(a, b0, s0, 0, 0, 0);
      s1 = __builtin_amdgcn_mfma_f32_16x16x32_bf16(a, b1, s1, 0, 0, 0);
    }
  }
  const bool m0 = mask[b * LL + l15] != 0;
  const bool m1 = mask[b * LL + 16 + l15] != 0;
  float a0[4], a1[4];
#pragma unroll
  for (int k = 0; k < 4; ++k) {
    float rn = rnL[w * 16 + lg * 4 + k];
    float v0 = m0 ? -INFINITY : s0[k] * rn;
    float v1 = m1 ? -INFINITY : s1[k] * rn;
    float mx = fmaxf(v0, v1);
#pragma unroll
    for (int o = 1; o < 16; o <<= 1) mx = fmaxf(mx, __shfl_xor(mx, o));
    float e0 = expf(v0 - mx), e1 = expf(v1 - mx);
    float sm = e0 + e1;
#pragma unroll
    for (int o = 1; o < 16; o <<= 1) sm += __shfl_xor(sm, o);
    float inv = 1.f / sm;
    a0[k] = e0 * inv; a1[k] = e1 * inv;
  }
  __syncthreads();

  for (int i = tid; i < TD * LL; i += 256) {
    int t = i >> 5, l = i & 31;
    wdnC[t * 40 + l] = f2b(wb[i]);
  }
#pragma unroll
  for (int k = 0; k < 4; ++k) {
    int px = w * 16 + lg * 4 + k;
    attnB[px * 40 + l15] = f2b(a0[k]);
    attnB[px * 40 + 16 + l15] = f2b(a1[k]);
  }
  __syncthreads();
  f32x4 acc2[4][4] = {};
  bf16x8 bfr[4];
#pragma unroll
  for (int pt = 0; pt < 4; ++pt)
    bfr[pt] = *(const bf16x8*)(attnB + (pt * 16 + l15) * 40 + lg * 8);
#pragma unroll
  for (int cc = 0; cc < 4; ++cc) {
    bf16x8 a = *(const bf16x8*)(wdnC + ((w * 4 + cc) * 16 + l15) * 40 + lg * 8);
#pragma unroll
    for (int pt = 0; pt < 4; ++pt)
      acc2[cc][pt] = __builtin_amdgcn_mfma_f32_16x16x32_bf16(a, bfr[pt], acc2[cc][pt], 0, 0, 0);
  }
#pragma unroll
  for (int cc = 0; cc < 4; ++cc) {
#pragma unroll
    for (int pt = 0; pt < 4; ++pt) {
#pragma unroll
      for (int k = 0; k < 4; ++k) {
        int c = (w * 4 + cc) * 16 + lg * 4 + k;
        ctx[((size_t)b * TD + c) * P + p0 + pt * 16 + l15] = f2b(acc2[cc][pt][k]);
      }
    }
  }
}

// ---------------- dual bf16 MFMA GEMM (img1 + shortcut share X), dbuf reg-staged ----------------
__global__ __launch_bounds__(256, 2) void gemm2_mfma_kernel(
    const float* __restrict__ W1, const float* __restrict__ W2,
    const u16* __restrict__ X, u16* __restrict__ Y1, u16* __restrict__ Y2,
    int C, int P) {
  __shared__ u16 shmem[2][16384];  // Wl1 5632 | Wl2 5632 | Xl 5120 per buf
  const int b = blockIdx.z, t0 = blockIdx.y * 128, p0 = blockIdx.x * 128;
  const int tid = threadIdx.x;
  const int w = tid >> 6, lane = tid & 63;
  const int wo = w >> 1, wq = w & 1;
  const int l15 = lane & 15, lg = lane >> 4;
  const int wr = tid >> 1, wcH = tid & 1;
  const int xr = tid >> 3, xcG = tid & 7;
  const int csw = xr ^ ((xcG & 3) << 3);
  const float* s1src = W1 + (size_t)(t0 + wr) * C + wcH * 16;
  const float* s2src = W2 + (size_t)(t0 + wr) * C + wcH * 16;
  const u16* xsrc = X + (size_t)b * C * P + (size_t)xr * P + p0 + xcG * 16;
  const int NK = C / 32;
  f32x4 acc1[4][4] = {}, acc2[4][4] = {};
  float4 w1reg[4], w2reg[4];
  u16 xst[16];

#pragma unroll
  for (int j = 0; j < 4; ++j) {
    w1reg[j] = *(const float4*)(s1src + j * 4);
    w2reg[j] = *(const float4*)(s2src + j * 4);
  }
  {
    union { u16 u[16]; uint4 q[2]; } xu;
    xu.q[0] = *(const uint4*)(xsrc);
    xu.q[1] = *(const uint4*)(xsrc + 8);
#pragma unroll
    for (int i = 0; i < 16; ++i) xst[i] = xu.u[i];
  }
  {
    u16* d1 = shmem[0] + wr * 44 + wcH * 16;
    u16* d2 = shmem[0] + 5632 + wr * 44 + wcH * 16;
    u16* xl = shmem[0] + 11264;
#pragma unroll
    for (int j = 0; j < 4; ++j) {
      *(ushort4*)(d1 + j * 4) = make_ushort4(f2b(w1reg[j].x), f2b(w1reg[j].y), f2b(w1reg[j].z), f2b(w1reg[j].w));
      *(ushort4*)(d2 + j * 4) = make_ushort4(f2b(w2reg[j].x), f2b(w2reg[j].y), f2b(w2reg[j].z), f2b(w2reg[j].w));
    }
#pragma unroll
    for (int i = 0; i < 16; ++i)
      xl[(xcG * 16 + i) * 40 + csw] = xst[i];
  }
  __syncthreads();

  for (int kb = 0; kb < NK; ++kb) {
    const int cur = kb & 1;
    if (kb + 1 < NK) {
      const int c0n = (kb + 1) * 32;
#pragma unroll
      for (int j = 0; j < 4; ++j) {
        w1reg[j] = *(const float4*)(s1src + c0n + j * 4);
        w2reg[j] = *(const float4*)(s2src + c0n + j * 4);
      }
      union { u16 u[16]; uint4 q[2]; } xu;
      xu.q[0] = *(const uint4*)(xsrc + (size_t)c0n * P);
      xu.q[1] = *(const uint4*)(xsrc + (size_t)c0n * P + 8);
#pragma unroll
      for (int i = 0; i < 16; ++i) xst[i] = xu.u[i];
    }
    bf16x8 a1[4], a2[4], bb[4];
#pragma unroll
    for (int rr = 0; rr < 4; ++rr) {
      a1[rr] = *(const bf16x8*)(shmem[cur] + (wo * 64 + rr * 16 + l15) * 44 + lg * 8);
      a2[rr] = *(const bf16x8*)(shmem[cur] + 5632 + (wo * 64 + rr * 16 + l15) * 44 + lg * 8);
    }
#pragma unroll
    for (int ss = 0; ss < 4; ++ss)
      bb[ss] = *(const bf16x8*)(shmem[cur] + 11264 + (wq * 64 + ss * 16 + l15) * 40 + ((lg ^ ss) << 3));
#pragma unroll
    for (int rr = 0; rr < 4; ++rr)
#pragma unroll
      for (int ss = 0; ss < 4; ++ss) {
        acc1[rr][ss] = __builtin_amdgcn_mfma_f32_16x16x32_bf16(a1[rr], bb[ss], acc1[rr][ss], 0, 0, 0);
        acc2[rr][ss] = __builtin_amdgcn_mfma_f32_16x16x32_bf16(a2[rr], bb[ss], acc2[rr][ss], 0, 0, 0);
      }
    if (kb + 1 < NK) {
      const int nxt = cur ^ 1;
      u16* d1 = shmem[nxt] + wr * 44 + wcH * 16;
      u16* d2 = shmem[nxt] + 5632 + wr * 44 + wcH * 16;
      u16* xl = shmem[nxt] + 11264;
#pragma unroll
      for (int j = 0; j < 4; ++j) {
        *(ushort4*)(d1 + j * 4) = make_ushort4(f2b(w1reg[j].x), f2b(w1reg[j].y), f2b(w1reg[j].z), f2b(w1reg[j].w));
        *(ushort4*)(d2 + j * 4) = make_ushort4(f2b(w2reg[j].x), f2b(w2reg[j].y), f2b(w2reg[j].z), f2b(w2reg[j].w));
      }
#pragma unroll
      for (int i = 0; i < 16; ++i)
        xl[(xcG * 16 + i) * 40 + csw] = xst[i];
      __syncthreads();
    }
  }
#pragma unroll
  for (int rr = 0; rr < 4; ++rr) {
    int tb = t0 + wo * 64 + rr * 16 + lg * 4;
#pragma unroll
    for (int ss = 0; ss < 4; ++ss) {
      int p = p0 + wq * 64 + ss * 16 + l15;
#pragma unroll
      for (int k = 0; k < 4; ++k) {
        int t = tb + k;
        Y1[((size_t)b * TD + t) * P + p] = f2b(acc1[rr][ss][k]);
        Y2[((size_t)b * COUT + t) * P + p] = f2b(acc2[rr][ss][k]);
      }
    }
  }
}

// ---------------- fused gamma/beta GEMM + inline gvec + BN + ReLU + NHWC pack ----------------
template <bool XINB>
__global__ __launch_bounds__(256, 2) void gbact_kernel(
    const float* __restrict__ Wg, const float* __restrict__ bg,
    const float* __restrict__ Wb, const float* __restrict__ bb_,
    const u16* __restrict__ ctx, const float* __restrict__ gcond,
    const void* __restrict__ xinv,
    const float* __restrict__ mean, const float* __restrict__ rstd,
    const float* __restrict__ bnw, const float* __restrict__ bnb,
    u16* __restrict__ outb, int C, int P) {
  __shared__ u16 shmem[2][16384];
  __shared__ float gvl[128], bvl[128];
  const int b = blockIdx.z, t0 = blockIdx.y * 128, p0 = blockIdx.x * 128;
  const int tid = threadIdx.x;
  const int w = tid >> 6, lane = tid & 63;
  const int wo = w >> 1, wq = w & 1;
  const int l15 = lane & 15, lg = lane >> 4;
  const int wr = tid >> 1, wcH = tid & 1;
  const int xr = tid >> 3, xcG = tid & 7;
  const int csw = xr ^ ((xcG & 3) << 3);
  const float* gsrc = Wg + (size_t)(t0 + wr) * CONDC + GD + wcH * 16;
  const float* bsrc = Wb + (size_t)(t0 + wr) * CONDC + GD + wcH * 16;
  const u16* xsrc = ctx + (size_t)b * TD * P + (size_t)xr * P + p0 + xcG * 16;
  const int NK = TD / 32;
  f32x4 accg[4][4] = {}, accb[4][4] = {};
  float4 greg[4], breg[4];
  u16 xst[16];

  {
    int t = tid & 127;
    const float* row = (tid < 128 ? Wg : Wb) + (size_t)(t0 + t) * CONDC;
    const float* gc = gcond + (size_t)b * GD;
    float s = 0.f;
    for (int c = 0; c < GD; c += 4) {
      float4 wv = *(const float4*)(row + c);
      float4 gv4 = *(const float4*)(gc + c);
      s += wv.x * gv4.x + wv.y * gv4.y + wv.z * gv4.z + wv.w * gv4.w;
    }
    s += (tid < 128 ? bg : bb_)[t0 + t];
    if (tid < 128) gvl[t] = s; else bvl[t] = s;
  }

#pragma unroll
  for (int j = 0; j < 4; ++j) {
    greg[j] = *(const float4*)(gsrc + j * 4);
    breg[j] = *(const float4*)(bsrc + j * 4);
  }
  {
    union { u16 u[16]; uint4 q[2]; } xu;
    xu.q[0] = *(const uint4*)(xsrc);
    xu.q[1] = *(const uint4*)(xsrc + 8);
#pragma unroll
    for (int i = 0; i < 16; ++i) xst[i] = xu.u[i];
  }
  {
    u16* dg = shmem[0] + wr * 44 + wcH * 16;
    u16* db = shmem[0] + 5632 + wr * 44 + wcH * 16;
    u16* xl = shmem[0] + 11264;
#pragma unroll
    for (int j = 0; j < 4; ++j) {
      *(ushort4*)(dg + j * 4) = make_ushort4(f2b(greg[j].x), f2b(greg[j].y), f2b(greg[j].z), f2b(greg[j].w));
      *(ushort4*)(db + j * 4) = make_ushort4(f2b(breg[j].x), f2b(breg[j].y), f2b(breg[j].z), f2b(breg[j].w));
    }
#pragma unroll
    for (int i = 0; i < 16; ++i)
      xl[(xcG * 16 + i) * 40 + csw] = xst[i];
  }
  __syncthreads();

  for (int kb = 0; kb < NK; ++kb) {
    const int cur = kb & 1;
    if (kb + 1 < NK) {
      const int c0n = (kb + 1) * 32;
#pragma unroll
      for (int j = 0; j < 4; ++j) {
        greg[j] = *(const float4*)(gsrc + c0n + j * 4);
        breg[j] = *(const float4*)(bsrc + c0n + j * 4);
      }
      union { u16 u[16]; uint4 q[2]; } xu;
      xu.q[0] = *(const uint4*)(xsrc + (size_t)c0n * P);
      xu.q[1] = *(const uint4*)(xsrc + (size_t)c0n * P + 8);
#pragma unroll
      for (int i = 0; i < 16; ++i) xst[i] = xu.u[i];
    }
    bf16x8 ag[4], ab[4], bb[4];
#pragma unroll
    for (int rr = 0; rr < 4; ++rr) {
      ag[rr] = *(const bf16x8*)(shmem[cur] + (wo * 64 + rr * 16 + l15) * 44 + lg * 8);
      ab[rr] = *(const bf16x8*)(shmem[cur] + 5632 + (wo * 64 + rr * 16 + l15) * 44 + lg * 8);
    }
#pragma unroll
    for (int ss = 0; ss < 4; ++ss)
      bb[ss] = *(const bf16x8*)(shmem[cur] + 11264 + (wq * 64 + ss * 16 + l15) * 40 + ((lg ^ ss) << 3));
#pragma unroll
    for (int rr = 0; rr < 4; ++rr)
#pragma unroll
      for (int ss = 0; ss < 4; ++ss) {
        accg[rr][ss] = __builtin_amdgcn_mfma_f32_16x16x32_bf16(ag[rr], bb[ss], accg[rr][ss], 0, 0, 0);
        accb[rr][ss] = __builtin_amdgcn_mfma_f32_16x16x32_bf16(ab[rr], bb[ss], accb[rr][ss], 0, 0, 0);
      }
    if (kb + 1 < NK) {
      const int nxt = cur ^ 1;
      u16* dg = shmem[nxt] + wr * 44 + wcH * 16;
      u16* db = shmem[nxt] + 5632 + wr * 44 + wcH * 16;
      u16* xl = shmem[nxt] + 11264;
#pragma unroll
      for (int j = 0; j < 4; ++j) {
        *(ushort4*)(dg + j * 4) = make_ushort4(f2b(greg[j].x), f2b(greg[j].y), f2b(greg[j].z), f2b(greg[j].w));
        *(ushort4*)(db + j * 4) = make_ushort4(f2b(breg[j].x), f2b(breg[j].y), f2b(breg[j].z), f2b(breg[j].w));
      }
#pragma unroll
      for (int i = 0; i < 16; ++i)
        xl[(xcG * 16 + i) * 40 + csw] = xst[i];
      __syncthreads();
    }
  }
  __syncthreads();
  u16* tbuf = &shmem[0][0];
#pragma unroll
  for (int rr = 0; rr < 4; ++rr) {
    float gv[4], bv[4], mm[4], rs[4], bB[4];
#pragma unroll
    for (int k = 0; k < 4; ++k) {
      int cl = wo * 64 + rr * 16 + lg * 4 + k;
      int c = t0 + cl;
      gv[k] = gvl[cl];
      bv[k] = bvl[cl];
      mm[k] = mean[c]; rs[k] = rstd[c] * bnw[c]; bB[k] = bnb[c];
    }
#pragma unroll
    for (int ss = 0; ss < 4; ++ss) {
#pragma unroll
      for (int k = 0; k < 4; ++k) {
        int cl = wo * 64 + rr * 16 + lg * 4 + k;
        int pl = wq * 64 + ss * 16 + l15;
        size_t xidx = ((size_t)b * C + t0 + cl) * P + p0 + pl;
        float xv = XINB ? b2f(((const u16*)xinv)[xidx]) : ((const float*)xinv)[xidx];
        float g = accg[rr][ss][k] + gv[k];
        float be = accb[rr][ss][k] + bv[k];
        float val = fmaxf(g * ((xv - mm[k]) * rs[k] + bB[k]) + be, 0.f);
        tbuf[pl * 136 + cl] = f2b(val);
      }
    }
  }
  __syncthreads();
  const int pr = tid >> 1, h = tid & 1;
#pragma unroll
  for (int j = 0; j < 8; ++j) {
    uint4 v = *(uint4*)(tbuf + pr * 136 + h * 64 + j * 8);
    *(uint4*)(outb + ((size_t)b * P + p0 + pr) * C + t0 + h * 64 + j * 8) = v;
  }
}

// ---------------- bf16 MFMA implicit-GEMM 3x3 conv (8-wave, optional fused BN stats) ----------------
template <int CIN, bool UP, bool OUTB, bool STATS>
__global__ __launch_bounds__(512, 2) void conv_mfma_kernel(
    const u16* __restrict__ Wp, const u16* __restrict__ Xt,
    const u16* __restrict__ scs, const float* __restrict__ scb,
    void* __restrict__ Yv, float* __restrict__ part) {
  constexpr int S = UP ? 32 : 64;
  constexpr int NC0 = CIN >> 5;
  constexpr int NCH = 6 * 66 * 8;
  __shared__ u16 Xs[2][6 * 66 * 36];
  __shared__ float stats_ls[256], stats_lsq[256];
  const int b = blockIdx.z, pxT = blockIdx.x;
  const int tid = threadIdx.x;
  const int w = tid >> 6, lane = tid & 63;
  const int wo = w >> 2, wp_ = w & 3;
  const int l15 = lane & 15, lg = lane >> 4;
  const int Y0 = pxT * 4;
  const u16* Xb = Xt + (size_t)b * S * S * CIN;
  const size_t posStride = (size_t)NC0 * 16 * 512;
  f32x4 acc[8][4] = {};
  uint2 st[7];

  if (STATS && tid < 256) { stats_ls[tid] = 0.f; stats_lsq[tid] = 0.f; }

#pragma unroll
  for (int j = 0; j < 7; ++j) {
    int i = tid + j * 512;
    if (i < NCH) {
      int r = i / 528, rem = i - r * 528, col = rem >> 3, ch = rem & 7;
      int uy = Y0 - 1 + r, ux = col - 1;
      uint2 v = make_uint2(0u, 0u);
      if (uy >= 0 && uy < 64 && ux >= 0 && ux < 64) {
        int sy = UP ? (uy >> 1) : uy, sx = UP ? (ux >> 1) : ux;
        v = *(const uint2*)(Xb + ((size_t)sy * S + sx) * CIN + ch * 4);
      }
      st[j] = v;
    }
  }
#pragma unroll
  for (int j = 0; j < 7; ++j) {
    int i = tid + j * 512;
    if (i < NCH) {
      int r = i / 528, rem = i - r * 528, col = rem >> 3, ch = rem & 7;
      *(uint2*)(&Xs[0][(r * 66 + col) * 36 + ch * 4]) = st[j];
    }
  }
  __syncthreads();

  for (int c0b = 0; c0b < NC0; ++c0b) {
    const int cur = c0b & 1;
    if (c0b + 1 < NC0) {
      const int c0n = (c0b + 1) << 5;
#pragma unroll
      for (int j = 0; j < 7; ++j) {
        int i = tid + j * 512;
        if (i < NCH) {
          int r = i / 528, rem = i - r * 528, col = rem >> 3, ch = rem & 7;
          int uy = Y0 - 1 + r, ux = col - 1;
          uint2 v = make_uint2(0u, 0u);
          if (uy >= 0 && uy < 64 && ux >= 0 && ux < 64) {
            int sy = UP ? (uy >> 1) : uy, sx = UP ? (ux >> 1) : ux;
            v = *(const uint2*)(Xb + ((size_t)sy * S + sx) * CIN + c0n + ch * 4);
          }
          st[j] = v;
        }
      }
    }
    {
      const u16* wbB = Wp + ((size_t)c0b * 16 + wo * 8) * 512 + lane * 8;
      bf16x8 aC[8], aN[8];
#pragma unroll
      for (int rr = 0; rr < 8; ++rr)
        aC[rr] = *(const bf16x8*)(wbB + rr * 512);
#pragma unroll
      for (int pos = 0; pos < 9; ++pos) {
        const int ky = pos / 3, kx = pos - ky * 3;
        if (pos < 8) {
          const u16* wbn = wbB + (size_t)(pos + 1) * posStride;
#pragma unroll
          for (int rr = 0; rr < 8; ++rr)
            aN[rr] = *(const bf16x8*)(wbn + rr * 512);
        }
        const int rowb = ((wp_ + ky) * 66 + kx) * 36 + lg * 8;
#pragma unroll
        for (int ss = 0; ss < 4; ++ss) {
          int idx = rowb + (ss * 16 + l15) * 36;
          union { uint2 q[2]; bf16x8 v; } u;
          u.q[0] = *(const uint2*)(&Xs[cur][idx]);
          u.q[1] = *(const uint2*)(&Xs[cur][idx + 4]);
#pragma unroll
          for (int rr = 0; rr < 8; ++rr)
            acc[rr][ss] = __builtin_amdgcn_mfma_f32_16x16x32_bf16(aC[rr], u.v, acc[rr][ss], 0, 0, 0);
        }
#pragma unroll
        for (int rr = 0; rr < 8; ++rr) aC[rr] = aN[rr];
      }
    }
    if (c0b + 1 < NC0) {
#pragma unroll
      for (int j = 0; j < 7; ++j) {
        int i = tid + j * 512;
        if (i < NCH) {
          int r = i / 528, rem = i - r * 528, col = rem >> 3, ch = rem & 7;
          *(uint2*)(&Xs[cur ^ 1][(r * 66 + col) * 36 + ch * 4]) = st[j];
        }
      }
      __syncthreads();
    }
  }
  const int oBase = wo * 128 + lg * 4;
  const int pxBase = pxT * 256 + wp_ * 64 + l15;
  const int y = Y0 + wp_;
#pragma unroll
  for (int rr = 0; rr < 8; ++rr) {
#pragma unroll
    for (int ss = 0; ss < 4; ++ss) {
      int px = pxBase + ss * 16;
#pragma unroll
      for (int k = 0; k < 4; ++k) {
        int o = oBase + rr * 16 + k;
        float val = acc[rr][ss][k];
        if (scs) {
          int gx = px & 63;
          val += b2f(scs[((size_t)b * COUT + o) * P1 + (y >> 1) * 32 + (gx >> 1)]) + scb[o];
        }
        if (OUTB) ((u16*)Yv)[((size_t)b * COUT + o) * 4096 + px] = f2b(val);
        else      ((float*)Yv)[((size_t)b * COUT + o) * 4096 + px] = val;
      }
    }
  }
  if (STATS) {
#pragma unroll
    for (int rr = 0; rr < 8; ++rr) {
#pragma unroll
      for (int k = 0; k < 4; ++k) {
        float s = acc[rr][0][k] + acc[rr][1][k] + acc[rr][2][k] + acc[rr][3][k];
        float sq = acc[rr][0][k] * acc[rr][0][k] + acc[rr][1][k] * acc[rr][1][k] +
                   acc[rr][2][k] * acc[rr][2][k] + acc[rr][3][k] * acc[rr][3][k];
#pragma unroll
        for (int o = 1; o < 16; o <<= 1) { s += __shfl_xor(s, o); sq += __shfl_xor(sq, o); }
        if (l15 == 0) {
          int o_ = oBase + rr * 16 + k;
          atomicAdd(&stats_ls[o_], s);
          atomicAdd(&stats_lsq[o_], sq);
        }
      }
    }
    __syncthreads();
    if (tid < 256) {
      int blk = b * 16 + pxT;
      part[(size_t)tid * 256 + blk] = stats_ls[tid];
      part[65536 + (size_t)tid * 256 + blk] = stats_lsq[tid];
    }
  }
}

extern "C" void kernel_launch(void* const* d_in, const int* in_sizes, int n_in,
                              void* d_out, int out_size, void* d_ws, size_t ws_size,
                              hipStream_t stream) {
  const float* x      = (const float*)d_in[0];
  const float* gcond  = (const float*)d_in[1];
  const float* wemb   = (const float*)d_in[2];
  const int*   mask   = (const int*)d_in[3];
  const float* w_img1 = (const float*)d_in[4];
  const float* w_img2 = (const float*)d_in[5];
  const float* w_c1   = (const float*)d_in[6];
  const float* w_c2   = (const float*)d_in[7];
  const float* bn1_w  = (const float*)d_in[8];
  const float* bn1_b  = (const float*)d_in[9];
  const float* bn2_w  = (const float*)d_in[10];
  const float* bn2_b  = (const float*)d_in[11];
  const float* w_g1   = (const float*)d_in[12];
  const float* b_g1   = (const float*)d_in[13];
  const float* w_b1   = (const float*)d_in[14];
  const float* b_b1   = (const float*)d_in[15];
  const float* w_g2   = (const float*)d_in[16];
  const float* b_g2   = (const float*)d_in[17];
  const float* w_b2   = (const float*)d_in[18];
  const float* b_b2   = (const float*)d_in[19];
  const float* w_sc   = (const float*)d_in[20];
  const float* b_sc   = (const float*)d_in[21];
  float* out = (float*)d_out;
  float* ws = (float*)d_ws;

  const size_t MF = 16777216;  // floats per 64MB region
  float* A  = ws;
  float* Br = ws + MF;
  float* Cr = ws + 2 * MF;
  float* SM = ws + 3 * MF;
  float* wdn   = SM;                     // 131072
  float* mean1 = SM + 131072;
  float* rstd1 = mean1 + 512;
  float* mean2 = rstd1 + 512;
  float* rstd2 = mean2 + 256;
  float* part  = rstd2 + 256;            // 131072
  float* wsp   = part + 131072;
  u16* Wp1 = (u16*)wsp;                       // 9*256*512 u16
  u16* Wp2 = (u16*)(wsp + 655360);            // 9*256*256 u16
  u16* scs = (u16*)(wsp + 655360 + 294912);   // 4.2M u16 (bf16 shortcut)
  u16* W2p = (u16*)(wsp + 655360 + 294912 + 2097152);  // 64K u16 (img2 weights)

  u16* img1   = (u16*)A;                 // 4.2M u16
  u16* ctx1   = (u16*)A + 4194304;       // 4.2M u16
  u16* Xt1    = (u16*)A + 8388608;       // 8.4M u16 NHWC bf16
  u16* xbf    = (u16*)A + 16777216;      // 8.4M u16 (bf16 copy of x)
  u16* conv1o = (u16*)Cr;                // 16.8M u16 NCHW bf16
  u16* ctx2   = (u16*)A;                 // reuse (A dead after conv1 + shortcut)
  u16* Xt2    = (u16*)Br;                // reuse

  // ---- stage 1 ----
  prelude_kernel<<<dim3(CIN1 + 128 + 1024), dim3(256), 0, stream>>>(
      x, mean1, rstd1, xbf, wemb, wdn, w_c1, Wp1, w_c2, Wp2, w_img2, W2p);
  gemm2_mfma_kernel<<<dim3(P1 / 128, 2, NB), dim3(256), 0, stream>>>(
      w_img1, w_sc, xbf, img1, scs, CIN1, P1);
  attnctx_kernel<<<dim3(P1 / 64, NB), dim3(256), 0, stream>>>(img1, wdn, mask, ctx1, P1);
  gbact_kernel<true><<<dim3(P1 / 128, CIN1 / 128, NB), dim3(256), 0, stream>>>(
      w_g1, b_g1, w_b1, b_b1, ctx1, gcond, xbf, mean1, rstd1, bn1_w, bn1_b, Xt1, CIN1, P1);
  conv_mfma_kernel<CIN1, true, true, true><<<dim3(16, 1, NB), dim3(512), 0, stream>>>(
      Wp1, Xt1, nullptr, nullptr, conv1o, part);

  // ---- stage 2 ----
  bn_fin_kernel<<<dim3(1), dim3(256), 0, stream>>>(part, mean2, rstd2);
  attnimg_kernel<<<dim3(P2 / 64, NB), dim3(256), 0, stream>>>(
      W2p, conv1o, wdn, mask, ctx2, P2);
  gbact_kernel<true><<<dim3(P2 / 128, COUT / 128, NB), dim3(256), 0, stream>>>(
      w_g2, b_g2, w_b2, b_b2, ctx2, gcond, conv1o, mean2, rstd2, bn2_w, bn2_b, Xt2, COUT, P2);
  conv_mfma_kernel<COUT, false, false, false><<<dim3(16, 1, NB), dim3(512), 0, stream>>>(
      Wp2, Xt2, scs, b_sc, out, nullptr);
}